// Round 14
// baseline (1549.199 us; speedup 1.0000x reference)
//
#include <hip/hip_runtime.h>

typedef _Float16 f16;
typedef _Float16 f16x8 __attribute__((ext_vector_type(8)));
typedef float f32x4 __attribute__((ext_vector_type(4)));
typedef float f32x16 __attribute__((ext_vector_type(16)));

__device__ __forceinline__ f32x4 mfma16(f16x8 a, f16x8 b, f32x4 c) {
    return __builtin_amdgcn_mfma_f32_16x16x32_f16(a, b, c, 0, 0, 0);
}
__device__ __forceinline__ f32x16 mfma32(f16x8 a, f16x8 b, f32x16 c) {
    return __builtin_amdgcn_mfma_f32_32x32x16_f16(a, b, c, 0, 0, 0);
}

template<int N>
__device__ __forceinline__ void waitcnt_vm() {
    asm volatile("s_waitcnt vmcnt(%0)" :: "i"(N) : "memory");
}

// ---------------- implicit-GEMM 3x3 conv on 32x32x16 MFMA ----------------
// BX=32 cols. Wave tile: MT=2 m-tiles (rows wy*2, wy*2+1; 32 px each) x NT=2
// n-tiles (64 oc). acc = 2x2 f32x16 = 64 VGPR. Per tap per kh: 2 A ds_read_b128
// + 2 B global 16B feed 4 MFMAs -> LDS ~4.6 CU-cyc per 8.07-cyc MFMA (MFMA-bound).
// A layout: m=lane&31, k=8*(lane>>5)+j. C/D: col=lane&31,
// row=(reg&3)+8*(reg>>2)+4*(lane>>5)  [m74/m101-verified].
// Pool: horiz partner = adjacent reg, vert = mt pair -> all in-register.
// Staging: part-major global_load_lds, 2-phase dbuf, counted vmcnt (r13).
template<int IC, int OC, int WY, int WO, int NT, bool POOL>
__global__ __launch_bounds__(WY * WO * 64) void convmf32_k(
    const f16* __restrict__ in, const f16* __restrict__ wt,
    const float* __restrict__ bias, f16* __restrict__ out,
    int H, int W, int ocBlocks, long inStride, long outStride)
{
    constexpr int WAVES = WY * WO;
    constexpr int HALVES = (WAVES + 3) / 4;
    constexpr int BROWS = 2 * WY;
    constexpr int SR = BROWS + 2;
    constexpr int SC = 34;
    constexpr int NPIX = SR * SC;
    constexpr int STRD = 64 * HALVES;
    constexpr int NISS = (NPIX + STRD - 1) / STRD;
    constexpr int NPpad = NISS * STRD;
    constexpr int NC = IC / 32;
    static_assert(WAVES == 4 || WAVES == 8, "4 or 8 waves");
    __shared__ f16 lds[2 * 4 * NPpad * 8];

    const int tid  = threadIdx.x;
    const int lane = tid & 63;
    const int wv   = tid >> 6;
    const int wy   = wv / WO;
    const int wo   = wv % WO;
    const int part = wv & 3;
    const int half = wv >> 2;
    const int m    = lane & 31;
    const int hi   = lane >> 5;
    const int x0   = blockIdx.x * 32;
    const int y0   = blockIdx.y * BROWS;
    const int zb   = blockIdx.z;
    const int n    = zb / ocBlocks;
    const int oc0  = (zb - n * ocBlocks) * (32 * NT * WO) + wo * (32 * NT);
    in  += (long)n * inStride;
    out += (long)n * outStride;

    const int Wp = W + 2;
    const f16* ipBase = in + ((long)y0 * Wp + x0) * IC + part * 8;

    auto STAGE = [&](int ch, int bi) {
        const f16* ip = ipBase + ch * 32;
#pragma unroll
        for (int i = 0; i < NISS; ++i) {
            int p = i * STRD + half * 64 + lane;
            int pc = (p < NPIX) ? p : 0;
            int r = pc / SC, xcol = pc - r * SC;
            __builtin_amdgcn_global_load_lds(
                (const __attribute__((address_space(1))) void*)(ip + ((long)r * Wp + xcol) * IC),
                (__attribute__((address_space(3))) void*)&lds[((bi * 4 + part) * NPpad + i * STRD + half * 64) * 8],
                16, 0, 0);
        }
    };

    f32x16 acc[2][NT];
#pragma unroll
    for (int mt = 0; mt < 2; ++mt)
#pragma unroll
        for (int nt = 0; nt < NT; ++nt)
#pragma unroll
            for (int r = 0; r < 16; ++r) acc[mt][nt][r] = 0.f;

    STAGE(0, 0);
#pragma unroll
    for (int c = 0; c < NC; ++c) {
        const int cur = c & 1;
        if (c + 1 < NC) {
            STAGE(c + 1, cur ^ 1);
            waitcnt_vm<NISS>();
        } else {
            waitcnt_vm<0>();
        }
        __syncthreads();

        const int ic0 = c * 32;
        for (int t = 0; t < 9; ++t) {
            int dy = t / 3, dx = t - dy * 3;
#pragma unroll
            for (int kh = 0; kh < 2; ++kh) {
                f16x8 bfr[NT];
#pragma unroll
                for (int nt = 0; nt < NT; ++nt)
                    bfr[nt] = *(const f16x8*)(wt + ((long)t * OC + oc0 + nt * 32 + m) * IC
                                              + ic0 + kh * 16 + hi * 8);
                f16x8 afr[2];
#pragma unroll
                for (int mt = 0; mt < 2; ++mt) {
                    int pp = (wy * 2 + mt + dy) * SC + (m + dx);
                    afr[mt] = *(const f16x8*)&lds[((cur * 4 + kh * 2 + hi) * NPpad + pp) * 8];
                }
#pragma unroll
                for (int mt = 0; mt < 2; ++mt)
#pragma unroll
                    for (int nt = 0; nt < NT; ++nt)
                        acc[mt][nt] = mfma32(afr[mt], bfr[nt], acc[mt][nt]);
            }
        }
        __syncthreads();
    }

    if constexpr (!POOL) {
#pragma unroll
        for (int nt = 0; nt < NT; ++nt) {
            int oc = oc0 + nt * 32 + m;
            float bs = bias[oc];
#pragma unroll
            for (int mt = 0; mt < 2; ++mt) {
                int y = y0 + wy * 2 + mt;
#pragma unroll
                for (int reg = 0; reg < 16; ++reg) {
                    int row = (reg & 3) + 8 * (reg >> 2) + 4 * hi;
                    float v = fmaxf(acc[mt][nt][reg] + bs, 0.f);
                    out[((long)(y + 1) * (W + 2) + (x0 + row + 1)) * OC + oc] = (f16)v;
                }
            }
        }
    } else {
        const int Wo = W >> 1;
        const int orow = (y0 >> 1) + wy;
#pragma unroll
        for (int nt = 0; nt < NT; ++nt) {
            int oc = oc0 + nt * 32 + m;
            float bs = bias[oc];
#pragma unroll
            for (int reg = 0; reg < 16; reg += 2) {
                float v = fmaxf(fmaxf(acc[0][nt][reg], acc[0][nt][reg + 1]),
                                fmaxf(acc[1][nt][reg], acc[1][nt][reg + 1]));
                v = fmaxf(v + bs, 0.f);
                int row = (reg & 3) + 8 * (reg >> 2) + 4 * hi;   // even
                int ocol = (x0 >> 1) + (row >> 1);
                out[((long)(orow + 1) * (Wo + 2) + (ocol + 1)) * OC + oc] = (f16)v;
            }
        }
    }
}

// ---------------- conv1: IC=2, im2col in LDS, K padded to 32 (r5-proven) ----------------
__global__ __launch_bounds__(256) void convmf1_k(
    const float* __restrict__ x, int itemBase,
    const f16* __restrict__ wt1,  // [64][32] f16, k=2t+ic, zero-padded
    const float* __restrict__ bias, f16* __restrict__ out, long outStride)
{
    __shared__ f16 ldsx[10 * 66 * 2];
    __shared__ f16 ldsa[512 * 40];
    const int tid = threadIdx.x;
    const int lane = tid & 63;
    const int wv = tid >> 6;
    const int lm = lane & 15;
    const int lk = lane >> 4;
    const int x0 = blockIdx.x * 64;
    const int y0 = blockIdx.y * 8;
    const float* xb = x + (long)(itemBase + blockIdx.z) * 2 * 512 * 512;
    out += (long)blockIdx.z * outStride;

    for (int s = tid; s < 660; s += 256) {
        int r = s / 66, xc = s - r * 66;
        int gy = y0 + r - 1, gx = x0 + xc - 1;
        f16 v0 = (f16)0.f, v1 = (f16)0.f;
        if ((unsigned)gy < 512u && (unsigned)gx < 512u) {
            v0 = (f16)xb[(long)gy * 512 + gx];
            v1 = (f16)xb[262144 + (long)gy * 512 + gx];
        }
        ldsx[(r * 66 + xc) * 2]     = v0;
        ldsx[(r * 66 + xc) * 2 + 1] = v1;
    }
    __syncthreads();
    for (int s = tid; s < 2048; s += 256) {
        int pos = s >> 2, g = s & 3;
        int row = pos >> 6, col = pos & 63;
        f16x8 v;
#pragma unroll
        for (int j = 0; j < 8; ++j) {
            int k = g * 8 + j;
            f16 val = (f16)0.f;
            if (k < 18) {
                int t = k >> 1, ic = k & 1;
                int dy = t / 3, dx = t - dy * 3;
                val = ldsx[((row + dy) * 66 + col + dx) * 2 + ic];
            }
            v[j] = val;
        }
        *(f16x8*)&ldsa[pos * 40 + g * 8] = v;
    }
    __syncthreads();

    f32x4 acc[8][4];
#pragma unroll
    for (int mt = 0; mt < 8; ++mt)
#pragma unroll
        for (int nt = 0; nt < 4; ++nt)
            acc[mt][nt] = (f32x4){0.f, 0.f, 0.f, 0.f};

    f16x8 b0 = *(const f16x8*)(wt1 + (0 * 16 + lm) * 32 + lk * 8);
    f16x8 b1 = *(const f16x8*)(wt1 + (1 * 16 + lm) * 32 + lk * 8);
    f16x8 b2 = *(const f16x8*)(wt1 + (2 * 16 + lm) * 32 + lk * 8);
    f16x8 b3 = *(const f16x8*)(wt1 + (3 * 16 + lm) * 32 + lk * 8);
#pragma unroll
    for (int mt = 0; mt < 8; ++mt) {
        int pos = wv * 128 + mt * 16 + lm;
        f16x8 a = *(const f16x8*)&ldsa[pos * 40 + lk * 8];
        acc[mt][0] = mfma16(a, b0, acc[mt][0]);
        acc[mt][1] = mfma16(a, b1, acc[mt][1]);
        acc[mt][2] = mfma16(a, b2, acc[mt][2]);
        acc[mt][3] = mfma16(a, b3, acc[mt][3]);
    }
#pragma unroll
    for (int nt = 0; nt < 4; ++nt) {
        int oc = nt * 16 + lm;
        float bs = bias[oc];
#pragma unroll
        for (int mt = 0; mt < 8; ++mt) {
#pragma unroll
            for (int r = 0; r < 4; ++r) {
                int pos = wv * 128 + mt * 16 + lk * 4 + r;
                int xx = pos & 63, yy = pos >> 6;
                float v = fmaxf(acc[mt][nt][r] + bs, 0.f);
                out[((long)(y0 + yy + 1) * 514 + (x0 + xx + 1)) * 64 + oc] = (f16)v;
            }
        }
    }
}

// ---------------- fused heads (loc+conf+regr) as one 16-oc MFMA conv ----------------
template<int BX>
__global__ __launch_bounds__(256) void headconv_k(
    const f16* __restrict__ s, long sStride, const f16* __restrict__ wth,
    const float* __restrict__ lb, const float* __restrict__ cb, const float* __restrict__ rb,
    float* __restrict__ loc, float* __restrict__ conf, float* __restrict__ regr,
    int W, int posoff)
{
    constexpr int BY = (BX == 64) ? 1 : 2;
    constexpr int SR = BY + 2, SC = BX + 2;
    constexpr int LOG = (BX == 64) ? 6 : 5;
    __shared__ f16 lds[SR * SC * 40];
    const int tid = threadIdx.x;
    const int lane = tid & 63;
    const int wv = tid >> 6;
    const int lm = lane & 15;
    const int lk = lane >> 4;
    const int y0 = blockIdx.y * BY;
    const int b = blockIdx.z;
    s += (long)b * sStride;

    f32x4 acc = (f32x4){0.f, 0.f, 0.f, 0.f};
    const int Wp = W + 2;
    for (int ic0 = 0; ic0 < 256; ic0 += 32) {
        if (ic0) __syncthreads();
        const f16* ip = s + (long)y0 * Wp * 256 + ic0;
        constexpr int TASKS = SR * SC * 4;
        for (int t = tid; t < TASKS; t += 256) {
            int r = t / (SC * 4);
            int rem = t - r * (SC * 4);
            int xcol = rem >> 2, g = rem & 3;
            f16x8 v = *(const f16x8*)(ip + ((long)r * Wp + xcol) * 256 + g * 8);
            *(f16x8*)&lds[(r * SC + xcol) * 40 + g * 8] = v;
        }
        __syncthreads();
        for (int t = 0; t < 9; ++t) {
            int dy = t / 3, dx = t - dy * 3;
            f16x8 bf = *(const f16x8*)(wth + ((long)t * 16 + lm) * 256 + ic0 + lk * 8);
            int pos = wv * 16 + lm;
            int xx = pos & (BX - 1), yy = pos >> LOG;
            f16x8 a = *(const f16x8*)&lds[((yy + dy) * SC + xx + dx) * 40 + lk * 8];
            acc = mfma16(a, bf, acc);
        }
    }
#pragma unroll
    for (int r = 0; r < 4; ++r) {
        int pos = wv * 16 + lk * 4 + r;
        int xx = pos & (BX - 1), yy = pos >> LOG;
        int P = posoff + (y0 + yy) * W + xx;
        float v = acc[r];
        if (lm < 2)       loc[((long)b * 5120 + P) * 2 + lm]       = v + lb[lm];
        else if (lm < 5)  conf[((long)b * 5120 + P) * 3 + (lm - 2)] = v + cb[lm - 2];
        else if (lm == 5) regr[(long)b * 5120 + P]                  = v + rb[0];
    }
}

// ---------------- small utility kernels ----------------
__global__ __launch_bounds__(256) void cvt_wt_k(const float* __restrict__ w, f16* __restrict__ wt,
                                                int OC, int IC)
{
    int idx = blockIdx.x * 256 + threadIdx.x;
    if (idx >= OC * IC) return;
    int oc = idx / IC, ic = idx - oc * IC;
#pragma unroll
    for (int t = 0; t < 9; ++t)
        wt[((long)t * OC + oc) * IC + ic] = (f16)w[(long)idx * 9 + t];
}

__global__ __launch_bounds__(64) void cvt_wt1_k(const float* __restrict__ w, f16* __restrict__ wt1)
{
    int oc = threadIdx.x;
#pragma unroll
    for (int k = 0; k < 32; ++k) {
        f16 v = (f16)0.f;
        if (k < 18) {
            int t = k >> 1, ic = k & 1;
            v = (f16)w[((long)oc * 2 + ic) * 9 + t];
        }
        wt1[oc * 32 + k] = v;
    }
}

__global__ __launch_bounds__(256) void cvt_wth_k(const float* __restrict__ lw, const float* __restrict__ cw,
                                                 const float* __restrict__ rw, f16* __restrict__ wth)
{
    int idx = blockIdx.x * 256 + threadIdx.x;
    if (idx >= 9 * 16 * 256) return;
    int t = idx / (16 * 256);
    int r = (idx / 256) & 15;
    int ic = idx & 255;
    float v = 0.f;
    if (r < 2)      v = lw[((long)r * 256 + ic) * 9 + t];
    else if (r < 5) v = cw[((long)(r - 2) * 256 + ic) * 9 + t];
    else if (r == 5) v = rw[(long)ic * 9 + t];
    wth[((long)t * 16 + r) * 256 + ic] = (f16)v;
}

__global__ __launch_bounds__(256) void halo_k(f16* __restrict__ buf, int W, int H, int C,
                                              long stride, int items)
{
    int per = (2 * (W + 2) + 2 * H) * C;
    long total = (long)per * items;
    long idx = (long)blockIdx.x * 256 + threadIdx.x;
    if (idx >= total) return;
    int n = idx / per;
    int j = idx - (long)n * per;
    int c = j % C, p = j / C;
    int row, col;
    if (p < W + 2) { row = 0; col = p; }
    else if (p < 2 * (W + 2)) { row = H + 1; col = p - (W + 2); }
    else { int q = p - 2 * (W + 2); row = 1 + (q >> 1); col = (q & 1) ? (W + 1) : 0; }
    buf[(long)n * stride + ((long)row * (W + 2) + col) * C + c] = (f16)0.f;
}

__global__ __launch_bounds__(256) void l2n_k(const f16* __restrict__ in, const float* __restrict__ g,
                                             f16* __restrict__ out, int W, long stride, int total)
{
    int i = blockIdx.x * 256 + threadIdx.x;
    if (i >= total) return;
    int b = i / (W * W);
    int rem = i - b * W * W;
    int y = rem / W, x = rem - y * W;
    long off = (long)b * stride + ((long)(y + 1) * (W + 2) + x + 1) * 256;
    const f16* p = in + off;
    f16* q = out + off;
    float s = 0.f;
    for (int gg = 0; gg < 32; ++gg) {
        f16x8 v = *(const f16x8*)(p + gg * 8);
#pragma unroll
        for (int j = 0; j < 8; ++j) { float f = (float)v[j]; s = fmaf(f, f, s); }
    }
    float inv = 1.f / (sqrtf(s) + 1e-10f);
    for (int gg = 0; gg < 32; ++gg) {
        f16x8 v = *(const f16x8*)(p + gg * 8);
        f16x8 o;
#pragma unroll
        for (int j = 0; j < 8; ++j) o[j] = (f16)(g[gg * 8 + j] * ((float)v[j] * inv));
        *(f16x8*)(q + gg * 8) = o;
    }
}

__global__ __launch_bounds__(256) void mp_k(const f16* __restrict__ in, f16* __restrict__ out)
{
    int idx = blockIdx.x * 256 + threadIdx.x;
    if (idx >= 8 * 32 * 32 * 32) return;
    int gg = idx & 31;
    int xo = (idx >> 5) & 31;
    int yo = (idx >> 10) & 31;
    int b = idx >> 15;
    const f16* p = in + (long)b * 1115136 + ((long)(2 * yo + 1) * 66 + 2 * xo + 1) * 256 + gg * 8;
    f16x8 a0 = *(const f16x8*)p;
    f16x8 a1 = *(const f16x8*)(p + 256);
    f16x8 a2 = *(const f16x8*)(p + 66 * 256);
    f16x8 a3 = *(const f16x8*)(p + 66 * 256 + 256);
    f16x8 o;
#pragma unroll
    for (int j = 0; j < 8; ++j)
        o[j] = (f16)fmaxf(fmaxf((float)a0[j], (float)a1[j]), fmaxf((float)a2[j], (float)a3[j]));
    *(f16x8*)(out + (long)b * 295936 + ((long)(yo + 1) * 34 + xo + 1) * 256 + gg * 8) = o;
}

__global__ __launch_bounds__(256) void priors_k(float* __restrict__ out)
{
    int r = blockIdx.x * 256 + threadIdx.x;
    if (r >= 5120) return;
    float cx, cy;
    if (r < 4096) {
        int i = r >> 6, j = r & 63;
        cx = (j + 0.5f) / 64.0f; cy = (i + 0.5f) / 64.0f;
    } else {
        int rr = r - 4096;
        int i = rr >> 5, j = rr & 31;
        cx = (j + 0.5f) / 32.0f; cy = (i + 0.5f) / 32.0f;
    }
    out[2 * r] = cx;
    out[2 * r + 1] = cy;
}

// ---------------- launch ----------------
extern "C" void kernel_launch(void* const* d_in, const int* in_sizes, int n_in,
                              void* d_out, int out_size, void* d_ws, size_t ws_size,
                              hipStream_t stream)
{
    const float* x  = (const float*)d_in[0];
    const float* w1 = (const float*)d_in[1];  const float* b1 = (const float*)d_in[2];
    const float* w2 = (const float*)d_in[3];  const float* b2 = (const float*)d_in[4];
    const float* w3 = (const float*)d_in[5];  const float* b3 = (const float*)d_in[6];
    const float* w4 = (const float*)d_in[7];  const float* b4 = (const float*)d_in[8];
    const float* w5 = (const float*)d_in[9];  const float* b5 = (const float*)d_in[10];
    const float* w6 = (const float*)d_in[11]; const float* b6 = (const float*)d_in[12];
    const float* w7 = (const float*)d_in[13]; const float* b7 = (const float*)d_in[14];
    const float* w8 = (const float*)d_in[15]; const float* b8 = (const float*)d_in[16];
    const float* g1 = (const float*)d_in[17]; const float* g2 = (const float*)d_in[18];
    const float* lw1 = (const float*)d_in[19]; const float* lb1 = (const float*)d_in[20];
    const float* lw2 = (const float*)d_in[21]; const float* lb2 = (const float*)d_in[22];
    const float* cw1 = (const float*)d_in[23]; const float* cb1 = (const float*)d_in[24];
    const float* cw2 = (const float*)d_in[25]; const float* cb2 = (const float*)d_in[26];
    const float* rw1 = (const float*)d_in[27]; const float* rb1 = (const float*)d_in[28];
    const float* rw2 = (const float*)d_in[29]; const float* rb2 = (const float*)d_in[30];

    f16* wsh = (f16*)d_ws;
    // fixed region (f16 units)
    f16* wt2  = wsh + 0;         // 36864
    f16* wt3  = wsh + 36864;     // 73728
    f16* wt4  = wsh + 110592;    // 147456
    f16* wt5  = wsh + 258048;    // 294912
    f16* wt6  = wsh + 552960;    // 589824
    f16* wt7  = wsh + 1142784;   // 589824
    f16* wt8  = wsh + 1732608;   // 589824
    f16* wt1  = wsh + 2322432;   // 2048
    f16* wth1 = wsh + 2324480;   // 36864
    f16* wth2 = wsh + 2361344;   // 36864
    f16* x6p  = wsh + 2398208;   // 8*66*66*256 = 8921088
    const long PI = 11319296;    // group region base

    // per-item strides (f16 units); slot = a1 region (G*A1S) + p1 region (G*P1S)
    const long A1S = 16908544;   // 514*514*64
    const long P1S = 4260096;    // 258*258*64
    const long A3S = 8520192;    // 258*258*128 (aliases a1 region)
    const long P2S = 2163200;    // 130*130*128 (aliases p1 region)
    const long A5S = 4326400;    // 130*130*256 (aliases a1 region)
    const long PH2 = 18391040;   // phase-2 footprint (s1..s2)

    int G = 1;
    for (int g = 8; g >= 1; g >>= 1) {
        long ext = (long)g * (A1S + P1S); if (ext < PH2) ext = PH2;
        if (2.0 * (double)(PI + ext) <= (double)ws_size) { G = g; break; }
    }
    const int NGRP = 8 / G;

    f16* a1 = wsh + PI;                    // G x A1S (aliased: a3 G x A3S, a5 G x A5S)
    f16* p1 = wsh + PI + (long)G * A1S;    // G x P1S (aliased: p2 G x P2S)
    f16* a3 = a1;
    f16* p2 = p1;
    f16* a5 = a1;
    // phase-2 (after group loop, group region dead)
    f16* s1 = wsh + PI;
    f16* p4 = wsh + PI + 8921088;
    f16* a7 = wsh + PI + 11288576;
    f16* a8 = wsh + PI + 13656064;
    f16* s2 = wsh + PI + 16023552;

    float* loc  = (float*)d_out;
    float* conf = loc + 81920;
    float* regr = loc + 204800;
    float* pri  = loc + 245760;

    // weight conversions
    cvt_wt_k<<<dim3((64 * 64 + 255) / 256), 256, 0, stream>>>(w2, wt2, 64, 64);
    cvt_wt_k<<<dim3((128 * 64 + 255) / 256), 256, 0, stream>>>(w3, wt3, 128, 64);
    cvt_wt_k<<<dim3((128 * 128 + 255) / 256), 256, 0, stream>>>(w4, wt4, 128, 128);
    cvt_wt_k<<<dim3((256 * 128 + 255) / 256), 256, 0, stream>>>(w5, wt5, 256, 128);
    cvt_wt_k<<<dim3((256 * 256 + 255) / 256), 256, 0, stream>>>(w6, wt6, 256, 256);
    cvt_wt_k<<<dim3((256 * 256 + 255) / 256), 256, 0, stream>>>(w7, wt7, 256, 256);
    cvt_wt_k<<<dim3((256 * 256 + 255) / 256), 256, 0, stream>>>(w8, wt8, 256, 256);
    cvt_wt1_k<<<dim3(1), 64, 0, stream>>>(w1, wt1);
    cvt_wth_k<<<dim3(144), 256, 0, stream>>>(lw1, cw1, rw1, wth1);
    cvt_wth_k<<<dim3(144), 256, 0, stream>>>(lw2, cw2, rw2, wth2);

    // conv1..conv6, G items per dispatch; aliased halos re-zeroed in r5-proven order
    for (int grp = 0; grp < NGRP; ++grp) {
        f16* x6g = x6p + (long)grp * G * 1115136;
        halo_k<<<dim3((G * (2 * 514 + 2 * 512) * 64 + 255) / 256), 256, 0, stream>>>(a1, 512, 512, 64, A1S, G);
        halo_k<<<dim3((G * (2 * 258 + 2 * 256) * 64 + 255) / 256), 256, 0, stream>>>(p1, 256, 256, 64, P1S, G);
        convmf1_k<<<dim3(8, 64, G), 256, 0, stream>>>(x, grp * G, wt1, b1, a1, A1S);
        convmf32_k<64, 64, 4, 1, 2, true><<<dim3(16, 64, G), 256, 0, stream>>>(
            a1, wt2, b2, p1, 512, 512, 1, A1S, P1S);
        halo_k<<<dim3((G * (2 * 258 + 2 * 256) * 128 + 255) / 256), 256, 0, stream>>>(a3, 256, 256, 128, A3S, G);
        convmf32_k<64, 128, 2, 2, 2, false><<<dim3(8, 64, G), 256, 0, stream>>>(
            p1, wt3, b3, a3, 256, 256, 1, P1S, A3S);
        halo_k<<<dim3((G * (2 * 130 + 2 * 128) * 128 + 255) / 256), 256, 0, stream>>>(p2, 128, 128, 128, P2S, G);
        convmf32_k<128, 128, 2, 2, 2, true><<<dim3(8, 64, G), 256, 0, stream>>>(
            a3, wt4, b4, p2, 256, 256, 1, A3S, P2S);
        halo_k<<<dim3((G * (2 * 130 + 2 * 128) * 256 + 255) / 256), 256, 0, stream>>>(a5, 128, 128, 256, A5S, G);
        convmf32_k<128, 256, 2, 4, 2, false><<<dim3(4, 32, G), 512, 0, stream>>>(
            p2, wt5, b5, a5, 128, 128, 1, P2S, A5S);
        convmf32_k<256, 256, 2, 4, 2, true><<<dim3(4, 32, G), 512, 0, stream>>>(
            a5, wt6, b6, x6g, 128, 128, 1, A5S, 1115136);
    }

    // phase-2 halos (group region now dead)
    halo_k<<<dim3((8 * (2 * 66 + 2 * 64) * 256 + 255) / 256), 256, 0, stream>>>(s1, 64, 64, 256, 1115136, 8);
    halo_k<<<dim3((8 * (2 * 34 + 2 * 32) * 256 + 255) / 256), 256, 0, stream>>>(p4, 32, 32, 256, 295936, 8);
    halo_k<<<dim3((8 * (2 * 34 + 2 * 32) * 256 + 255) / 256), 256, 0, stream>>>(a7, 32, 32, 256, 295936, 8);
    halo_k<<<dim3((8 * (2 * 34 + 2 * 32) * 256 + 255) / 256), 256, 0, stream>>>(s2, 32, 32, 256, 295936, 8);

    l2n_k<<<dim3((32768 + 255) / 256), 256, 0, stream>>>(x6p, g1, s1, 64, 1115136, 32768);
    mp_k<<<dim3((262144 + 255) / 256), 256, 0, stream>>>(x6p, p4);
    convmf32_k<256, 256, 2, 2, 2, false><<<dim3(1, 8, 16), 256, 0, stream>>>(
        p4, wt7, b7, a7, 32, 32, 2, 295936, 295936);
    convmf32_k<256, 256, 2, 2, 2, false><<<dim3(1, 8, 16), 256, 0, stream>>>(
        a7, wt8, b8, a8, 32, 32, 2, 295936, 295936);
    l2n_k<<<dim3((8192 + 255) / 256), 256, 0, stream>>>(a8, g2, s2, 32, 295936, 8192);

    headconv_k<64><<<dim3(1, 64, 8), 256, 0, stream>>>(
        s1, 1115136, wth1, lb1, cb1, rb1, loc, conf, regr, 64, 0);
    headconv_k<32><<<dim3(1, 16, 8), 256, 0, stream>>>(
        s2, 295936, wth2, lb2, cb2, rb2, loc, conf, regr, 32, 4096);
    priors_k<<<dim3(20), 256, 0, stream>>>(pri);

    (void)in_sizes; (void)n_in; (void)out_size; (void)ws_size;
}

// Round 15
// 1418.195 us; speedup vs baseline: 1.0924x; 1.0924x over previous
//
#include <hip/hip_runtime.h>

typedef _Float16 f16;
typedef _Float16 f16x8 __attribute__((ext_vector_type(8)));
typedef float f32x4 __attribute__((ext_vector_type(4)));

__device__ __forceinline__ f32x4 mfma16(f16x8 a, f16x8 b, f32x4 c) {
    return __builtin_amdgcn_mfma_f32_16x16x32_f16(a, b, c, 0, 0, 0);
}

template<int N>
__device__ __forceinline__ void waitcnt_vm() {
    asm volatile("s_waitcnt vmcnt(%0)" :: "i"(N) : "memory");
}

// ---------------- main implicit-GEMM 3x3 conv, f16 MFMA ----------------
// TRUE 2-phase pipeline: per iter, (1) B(c) weight-frags -> regs (older vmem,
// waits on them cannot drain newer stage DMAs); (2) STAGE(c+1) via
// global_load_lds; (3) counted vmcnt(NISS) + RAW s_barrier (no compiler
// vmcnt(0) drain, unlike __syncthreads); (4) t-loop = pure LDS+MFMA.
// Part-major linear LDS (r12: 0 bank conflicts). t-loop unrolled so ball[][]
// is statically indexed (no scratch).
template<int IC, int OC, int BX, int WY, int WO, int MT, int NT, bool POOL>
__global__ __launch_bounds__(WY * WO * 64) void convmf_k(
    const f16* __restrict__ in, const f16* __restrict__ wt,
    const float* __restrict__ bias, f16* __restrict__ out,
    int H, int W, int ocBlocks, long inStride, long outStride)
{
    constexpr int WAVES = WY * WO;
    constexpr int HALVES = WAVES / 4;
    constexpr int WROWS = MT * 16 / BX;
    constexpr int BROWS = WROWS * WY;
    constexpr int SR = BROWS + 2;
    constexpr int SC = BX + 2;
    constexpr int LOG = (BX == 64) ? 6 : 5;
    constexpr int NPIX = SR * SC;
    constexpr int STRD = 64 * HALVES;
    constexpr int NISS = (NPIX + STRD - 1) / STRD;
    constexpr int NPpad = NISS * STRD;
    constexpr int NC = IC / 32;
    static_assert(WAVES == 4 || WAVES == 8, "4 or 8 waves");
    static_assert(!POOL || (BX == 64 && MT == 8), "pool path assumes BX==64, MT==8");
    __shared__ f16 lds[2 * 4 * NPpad * 8];

    const int tid  = threadIdx.x;
    const int lane = tid & 63;
    const int wv   = tid >> 6;
    const int wy   = wv / WO;
    const int wo   = wv % WO;
    const int part = wv & 3;
    const int half = wv >> 2;
    const int lm   = lane & 15;
    const int lk   = lane >> 4;
    const int x0   = blockIdx.x * BX;
    const int y0   = blockIdx.y * BROWS;
    const int zb   = blockIdx.z;
    const int n    = zb / ocBlocks;
    const int oc0  = (zb - n * ocBlocks) * (16 * NT * WO) + wo * (16 * NT);
    in  += (long)n * inStride;
    out += (long)n * outStride;

    const int Wp = W + 2;
    const f16* ipBase = in + ((long)y0 * Wp + x0) * IC + part * 8;

    auto STAGE = [&](int ch, int bi) {
        const f16* ip = ipBase + ch * 32;
#pragma unroll
        for (int i = 0; i < NISS; ++i) {
            int p = i * STRD + half * 64 + lane;
            int pc = (p < NPIX) ? p : 0;          // pad lanes: harmless in-range load
            int r = pc / SC, xcol = pc - r * SC;
            __builtin_amdgcn_global_load_lds(
                (const __attribute__((address_space(1))) void*)(ip + ((long)r * Wp + xcol) * IC),
                (__attribute__((address_space(3))) void*)&lds[((bi * 4 + part) * NPpad + i * STRD + half * 64) * 8],
                16, 0, 0);
        }
    };

    f32x4 acc[MT][NT];
#pragma unroll
    for (int mt = 0; mt < MT; ++mt)
#pragma unroll
        for (int nt = 0; nt < NT; ++nt)
            acc[mt][nt] = (f32x4){0.f, 0.f, 0.f, 0.f};

    STAGE(0, 0);
#pragma unroll
    for (int c = 0; c < NC; ++c) {
        const int cur = c & 1;
        const int ic0 = c * 32;

        // (1) B(c) -> regs, issued BEFORE next-chunk stage DMAs
        f16x8 ball[9][NT];
#pragma unroll
        for (int t = 0; t < 9; ++t)
#pragma unroll
            for (int nt = 0; nt < NT; ++nt)
                ball[t][nt] = *(const f16x8*)(wt + ((long)t * OC + oc0 + nt * 16 + lm) * IC
                                              + ic0 + lk * 8);

        // (2) prefetch next chunk; (3) counted wait + raw barrier
        if (c + 1 < NC) {
            STAGE(c + 1, cur ^ 1);
            waitcnt_vm<NISS>();    // chunk c landed; c+1 stays in flight
        } else {
            waitcnt_vm<0>();
        }
        __builtin_amdgcn_s_barrier();
        asm volatile("" ::: "memory");

        // (4) pure LDS + MFMA
#pragma unroll
        for (int t = 0; t < 9; ++t) {
            const int dy = t / 3, dx = t - dy * 3;
#pragma unroll
            for (int mt = 0; mt < MT; ++mt) {
                int pos = mt * 16 + lm;
                int xx = pos & (BX - 1);
                int yy = wy * WROWS + (pos >> LOG);
                int pp = (yy + dy) * SC + xx + dx;
                f16x8 a = *(const f16x8*)&lds[((cur * 4 + lk) * NPpad + pp) * 8];
#pragma unroll
                for (int nt = 0; nt < NT; ++nt)
                    acc[mt][nt] = mfma16(a, ball[t][nt], acc[mt][nt]);
            }
        }
        asm volatile("" ::: "memory");
        __builtin_amdgcn_s_barrier();   // buf[cur] free for restage next iter
    }

    if constexpr (!POOL) {
#pragma unroll
        for (int nt = 0; nt < NT; ++nt) {
            int oc = oc0 + nt * 16 + lm;
            float bs = bias[oc];
#pragma unroll
            for (int mt = 0; mt < MT; ++mt) {
#pragma unroll
                for (int r = 0; r < 4; ++r) {
                    int pos = mt * 16 + lk * 4 + r;
                    int xx = pos & (BX - 1);
                    int yy = wy * WROWS + (pos >> LOG);
                    float v = fmaxf(acc[mt][nt][r] + bs, 0.f);
                    out[((long)(y0 + yy + 1) * (W + 2) + (x0 + xx + 1)) * OC + oc] = (f16)v;
                }
            }
        }
    } else {
        const int Wo = W >> 1;
#pragma unroll
        for (int nt = 0; nt < NT; ++nt) {
            int oc = oc0 + nt * 16 + lm;
            float bs = bias[oc];
#pragma unroll
            for (int mt = 0; mt < 4; ++mt) {
#pragma unroll
                for (int r = 0; r < 4; r += 2) {
                    float v = fmaxf(fmaxf(acc[mt][nt][r], acc[mt][nt][r + 1]),
                                    fmaxf(acc[mt + 4][nt][r], acc[mt + 4][nt][r + 1]));
                    v = fmaxf(v + bs, 0.f);
                    int pos = mt * 16 + lk * 4 + r;
                    int xo = pos >> 1;
                    out[((long)((y0 >> 1) + wy + 1) * (Wo + 2) + ((x0 >> 1) + xo + 1)) * OC + oc] = (f16)v;
                }
            }
        }
    }
}

// ---------------- conv1: IC=2, im2col in LDS, K padded to 32 (r5-proven) ----------------
__global__ __launch_bounds__(256) void convmf1_k(
    const float* __restrict__ x, int itemBase,
    const f16* __restrict__ wt1,  // [64][32] f16, k=2t+ic, zero-padded
    const float* __restrict__ bias, f16* __restrict__ out, long outStride)
{
    __shared__ f16 ldsx[10 * 66 * 2];
    __shared__ f16 ldsa[512 * 40];
    const int tid = threadIdx.x;
    const int lane = tid & 63;
    const int wv = tid >> 6;
    const int lm = lane & 15;
    const int lk = lane >> 4;
    const int x0 = blockIdx.x * 64;
    const int y0 = blockIdx.y * 8;
    const float* xb = x + (long)(itemBase + blockIdx.z) * 2 * 512 * 512;
    out += (long)blockIdx.z * outStride;

    for (int s = tid; s < 660; s += 256) {
        int r = s / 66, xc = s - r * 66;
        int gy = y0 + r - 1, gx = x0 + xc - 1;
        f16 v0 = (f16)0.f, v1 = (f16)0.f;
        if ((unsigned)gy < 512u && (unsigned)gx < 512u) {
            v0 = (f16)xb[(long)gy * 512 + gx];
            v1 = (f16)xb[262144 + (long)gy * 512 + gx];
        }
        ldsx[(r * 66 + xc) * 2]     = v0;
        ldsx[(r * 66 + xc) * 2 + 1] = v1;
    }
    __syncthreads();
    for (int s = tid; s < 2048; s += 256) {
        int pos = s >> 2, g = s & 3;
        int row = pos >> 6, col = pos & 63;
        f16x8 v;
#pragma unroll
        for (int j = 0; j < 8; ++j) {
            int k = g * 8 + j;
            f16 val = (f16)0.f;
            if (k < 18) {
                int t = k >> 1, ic = k & 1;
                int dy = t / 3, dx = t - dy * 3;
                val = ldsx[((row + dy) * 66 + col + dx) * 2 + ic];
            }
            v[j] = val;
        }
        *(f16x8*)&ldsa[pos * 40 + g * 8] = v;
    }
    __syncthreads();

    f32x4 acc[8][4];
#pragma unroll
    for (int mt = 0; mt < 8; ++mt)
#pragma unroll
        for (int nt = 0; nt < 4; ++nt)
            acc[mt][nt] = (f32x4){0.f, 0.f, 0.f, 0.f};

    f16x8 b0 = *(const f16x8*)(wt1 + (0 * 16 + lm) * 32 + lk * 8);
    f16x8 b1 = *(const f16x8*)(wt1 + (1 * 16 + lm) * 32 + lk * 8);
    f16x8 b2 = *(const f16x8*)(wt1 + (2 * 16 + lm) * 32 + lk * 8);
    f16x8 b3 = *(const f16x8*)(wt1 + (3 * 16 + lm) * 32 + lk * 8);
#pragma unroll
    for (int mt = 0; mt < 8; ++mt) {
        int pos = wv * 128 + mt * 16 + lm;
        f16x8 a = *(const f16x8*)&ldsa[pos * 40 + lk * 8];
        acc[mt][0] = mfma16(a, b0, acc[mt][0]);
        acc[mt][1] = mfma16(a, b1, acc[mt][1]);
        acc[mt][2] = mfma16(a, b2, acc[mt][2]);
        acc[mt][3] = mfma16(a, b3, acc[mt][3]);
    }
#pragma unroll
    for (int nt = 0; nt < 4; ++nt) {
        int oc = nt * 16 + lm;
        float bs = bias[oc];
#pragma unroll
        for (int mt = 0; mt < 8; ++mt) {
#pragma unroll
            for (int r = 0; r < 4; ++r) {
                int pos = wv * 128 + mt * 16 + lk * 4 + r;
                int xx = pos & 63, yy = pos >> 6;
                float v = fmaxf(acc[mt][nt][r] + bs, 0.f);
                out[((long)(y0 + yy + 1) * 514 + (x0 + xx + 1)) * 64 + oc] = (f16)v;
            }
        }
    }
}

// ---------------- fused heads (loc+conf+regr) as one 16-oc MFMA conv ----------------
template<int BX>
__global__ __launch_bounds__(256) void headconv_k(
    const f16* __restrict__ s, long sStride, const f16* __restrict__ wth,
    const float* __restrict__ lb, const float* __restrict__ cb, const float* __restrict__ rb,
    float* __restrict__ loc, float* __restrict__ conf, float* __restrict__ regr,
    int W, int posoff)
{
    constexpr int BY = (BX == 64) ? 1 : 2;
    constexpr int SR = BY + 2, SC = BX + 2;
    constexpr int LOG = (BX == 64) ? 6 : 5;
    __shared__ f16 lds[SR * SC * 40];
    const int tid = threadIdx.x;
    const int lane = tid & 63;
    const int wv = tid >> 6;
    const int lm = lane & 15;
    const int lk = lane >> 4;
    const int y0 = blockIdx.y * BY;
    const int b = blockIdx.z;
    s += (long)b * sStride;

    f32x4 acc = (f32x4){0.f, 0.f, 0.f, 0.f};
    const int Wp = W + 2;
    for (int ic0 = 0; ic0 < 256; ic0 += 32) {
        if (ic0) __syncthreads();
        const f16* ip = s + (long)y0 * Wp * 256 + ic0;
        constexpr int TASKS = SR * SC * 4;
        for (int t = tid; t < TASKS; t += 256) {
            int r = t / (SC * 4);
            int rem = t - r * (SC * 4);
            int xcol = rem >> 2, g = rem & 3;
            f16x8 v = *(const f16x8*)(ip + ((long)r * Wp + xcol) * 256 + g * 8);
            *(f16x8*)&lds[(r * SC + xcol) * 40 + g * 8] = v;
        }
        __syncthreads();
        for (int t = 0; t < 9; ++t) {
            int dy = t / 3, dx = t - dy * 3;
            f16x8 bf = *(const f16x8*)(wth + ((long)t * 16 + lm) * 256 + ic0 + lk * 8);
            int pos = wv * 16 + lm;
            int xx = pos & (BX - 1), yy = pos >> LOG;
            f16x8 a = *(const f16x8*)&lds[((yy + dy) * SC + xx + dx) * 40 + lk * 8];
            acc = mfma16(a, bf, acc);
        }
    }
#pragma unroll
    for (int r = 0; r < 4; ++r) {
        int pos = wv * 16 + lk * 4 + r;
        int xx = pos & (BX - 1), yy = pos >> LOG;
        int P = posoff + (y0 + yy) * W + xx;
        float v = acc[r];
        if (lm < 2)       loc[((long)b * 5120 + P) * 2 + lm]       = v + lb[lm];
        else if (lm < 5)  conf[((long)b * 5120 + P) * 3 + (lm - 2)] = v + cb[lm - 2];
        else if (lm == 5) regr[(long)b * 5120 + P]                  = v + rb[0];
    }
}

// ---------------- small utility kernels ----------------
__global__ __launch_bounds__(256) void cvt_wt_k(const float* __restrict__ w, f16* __restrict__ wt,
                                                int OC, int IC)
{
    int idx = blockIdx.x * 256 + threadIdx.x;
    if (idx >= OC * IC) return;
    int oc = idx / IC, ic = idx - oc * IC;
#pragma unroll
    for (int t = 0; t < 9; ++t)
        wt[((long)t * OC + oc) * IC + ic] = (f16)w[(long)idx * 9 + t];
}

__global__ __launch_bounds__(64) void cvt_wt1_k(const float* __restrict__ w, f16* __restrict__ wt1)
{
    int oc = threadIdx.x;
#pragma unroll
    for (int k = 0; k < 32; ++k) {
        f16 v = (f16)0.f;
        if (k < 18) {
            int t = k >> 1, ic = k & 1;
            v = (f16)w[((long)oc * 2 + ic) * 9 + t];
        }
        wt1[oc * 32 + k] = v;
    }
}

__global__ __launch_bounds__(256) void cvt_wth_k(const float* __restrict__ lw, const float* __restrict__ cw,
                                                 const float* __restrict__ rw, f16* __restrict__ wth)
{
    int idx = blockIdx.x * 256 + threadIdx.x;
    if (idx >= 9 * 16 * 256) return;
    int t = idx / (16 * 256);
    int r = (idx / 256) & 15;
    int ic = idx & 255;
    float v = 0.f;
    if (r < 2)      v = lw[((long)r * 256 + ic) * 9 + t];
    else if (r < 5) v = cw[((long)(r - 2) * 256 + ic) * 9 + t];
    else if (r == 5) v = rw[(long)ic * 9 + t];
    wth[((long)t * 16 + r) * 256 + ic] = (f16)v;
}

__global__ __launch_bounds__(256) void halo_k(f16* __restrict__ buf, int W, int H, int C,
                                              long stride, int items)
{
    int per = (2 * (W + 2) + 2 * H) * C;
    long total = (long)per * items;
    long idx = (long)blockIdx.x * 256 + threadIdx.x;
    if (idx >= total) return;
    int n = idx / per;
    int j = idx - (long)n * per;
    int c = j % C, p = j / C;
    int row, col;
    if (p < W + 2) { row = 0; col = p; }
    else if (p < 2 * (W + 2)) { row = H + 1; col = p - (W + 2); }
    else { int q = p - 2 * (W + 2); row = 1 + (q >> 1); col = (q & 1) ? (W + 1) : 0; }
    buf[(long)n * stride + ((long)row * (W + 2) + col) * C + c] = (f16)0.f;
}

__global__ __launch_bounds__(256) void l2n_k(const f16* __restrict__ in, const float* __restrict__ g,
                                             f16* __restrict__ out, int W, long stride, int total)
{
    int i = blockIdx.x * 256 + threadIdx.x;
    if (i >= total) return;
    int b = i / (W * W);
    int rem = i - b * W * W;
    int y = rem / W, x = rem - y * W;
    long off = (long)b * stride + ((long)(y + 1) * (W + 2) + x + 1) * 256;
    const f16* p = in + off;
    f16* q = out + off;
    float s = 0.f;
    for (int gg = 0; gg < 32; ++gg) {
        f16x8 v = *(const f16x8*)(p + gg * 8);
#pragma unroll
        for (int j = 0; j < 8; ++j) { float f = (float)v[j]; s = fmaf(f, f, s); }
    }
    float inv = 1.f / (sqrtf(s) + 1e-10f);
    for (int gg = 0; gg < 32; ++gg) {
        f16x8 v = *(const f16x8*)(p + gg * 8);
        f16x8 o;
#pragma unroll
        for (int j = 0; j < 8; ++j) o[j] = (f16)(g[gg * 8 + j] * ((float)v[j] * inv));
        *(f16x8*)(q + gg * 8) = o;
    }
}

__global__ __launch_bounds__(256) void mp_k(const f16* __restrict__ in, f16* __restrict__ out)
{
    int idx = blockIdx.x * 256 + threadIdx.x;
    if (idx >= 8 * 32 * 32 * 32) return;
    int gg = idx & 31;
    int xo = (idx >> 5) & 31;
    int yo = (idx >> 10) & 31;
    int b = idx >> 15;
    const f16* p = in + (long)b * 1115136 + ((long)(2 * yo + 1) * 66 + 2 * xo + 1) * 256 + gg * 8;
    f16x8 a0 = *(const f16x8*)p;
    f16x8 a1 = *(const f16x8*)(p + 256);
    f16x8 a2 = *(const f16x8*)(p + 66 * 256);
    f16x8 a3 = *(const f16x8*)(p + 66 * 256 + 256);
    f16x8 o;
#pragma unroll
    for (int j = 0; j < 8; ++j)
        o[j] = (f16)fmaxf(fmaxf((float)a0[j], (float)a1[j]), fmaxf((float)a2[j], (float)a3[j]));
    *(f16x8*)(out + (long)b * 295936 + ((long)(yo + 1) * 34 + xo + 1) * 256 + gg * 8) = o;
}

__global__ __launch_bounds__(256) void priors_k(float* __restrict__ out)
{
    int r = blockIdx.x * 256 + threadIdx.x;
    if (r >= 5120) return;
    float cx, cy;
    if (r < 4096) {
        int i = r >> 6, j = r & 63;
        cx = (j + 0.5f) / 64.0f; cy = (i + 0.5f) / 64.0f;
    } else {
        int rr = r - 4096;
        int i = rr >> 5, j = rr & 31;
        cx = (j + 0.5f) / 32.0f; cy = (i + 0.5f) / 32.0f;
    }
    out[2 * r] = cx;
    out[2 * r + 1] = cy;
}

// ---------------- launch ----------------
extern "C" void kernel_launch(void* const* d_in, const int* in_sizes, int n_in,
                              void* d_out, int out_size, void* d_ws, size_t ws_size,
                              hipStream_t stream)
{
    const float* x  = (const float*)d_in[0];
    const float* w1 = (const float*)d_in[1];  const float* b1 = (const float*)d_in[2];
    const float* w2 = (const float*)d_in[3];  const float* b2 = (const float*)d_in[4];
    const float* w3 = (const float*)d_in[5];  const float* b3 = (const float*)d_in[6];
    const float* w4 = (const float*)d_in[7];  const float* b4 = (const float*)d_in[8];
    const float* w5 = (const float*)d_in[9];  const float* b5 = (const float*)d_in[10];
    const float* w6 = (const float*)d_in[11]; const float* b6 = (const float*)d_in[12];
    const float* w7 = (const float*)d_in[13]; const float* b7 = (const float*)d_in[14];
    const float* w8 = (const float*)d_in[15]; const float* b8 = (const float*)d_in[16];
    const float* g1 = (const float*)d_in[17]; const float* g2 = (const float*)d_in[18];
    const float* lw1 = (const float*)d_in[19]; const float* lb1 = (const float*)d_in[20];
    const float* lw2 = (const float*)d_in[21]; const float* lb2 = (const float*)d_in[22];
    const float* cw1 = (const float*)d_in[23]; const float* cb1 = (const float*)d_in[24];
    const float* cw2 = (const float*)d_in[25]; const float* cb2 = (const float*)d_in[26];
    const float* rw1 = (const float*)d_in[27]; const float* rb1 = (const float*)d_in[28];
    const float* rw2 = (const float*)d_in[29]; const float* rb2 = (const float*)d_in[30];

    f16* wsh = (f16*)d_ws;
    // fixed region (f16 units)
    f16* wt2  = wsh + 0;         // 36864
    f16* wt3  = wsh + 36864;     // 73728
    f16* wt4  = wsh + 110592;    // 147456
    f16* wt5  = wsh + 258048;    // 294912
    f16* wt6  = wsh + 552960;    // 589824
    f16* wt7  = wsh + 1142784;   // 589824
    f16* wt8  = wsh + 1732608;   // 589824
    f16* wt1  = wsh + 2322432;   // 2048
    f16* wth1 = wsh + 2324480;   // 36864
    f16* wth2 = wsh + 2361344;   // 36864
    f16* x6p  = wsh + 2398208;   // 8*66*66*256 = 8921088
    const long PI = 11319296;    // group region base

    // per-item strides (f16 units); slot = a1 region (G*A1S) + p1 region (G*P1S)
    const long A1S = 16908544;   // 514*514*64
    const long P1S = 4260096;    // 258*258*64
    const long A3S = 8520192;    // 258*258*128 (aliases a1 region)
    const long P2S = 2163200;    // 130*130*128 (aliases p1 region)
    const long A5S = 4326400;    // 130*130*256 (aliases a1 region)
    const long PH2 = 18391040;   // phase-2 footprint (s1..s2)

    int G = 1;
    for (int g = 8; g >= 1; g >>= 1) {
        long ext = (long)g * (A1S + P1S); if (ext < PH2) ext = PH2;
        if (2.0 * (double)(PI + ext) <= (double)ws_size) { G = g; break; }
    }
    const int NGRP = 8 / G;

    f16* a1 = wsh + PI;                    // G x A1S (aliased: a3 G x A3S, a5 G x A5S)
    f16* p1 = wsh + PI + (long)G * A1S;    // G x P1S (aliased: p2 G x P2S)
    f16* a3 = a1;
    f16* p2 = p1;
    f16* a5 = a1;
    // phase-2 (after group loop, group region dead)
    f16* s1 = wsh + PI;
    f16* p4 = wsh + PI + 8921088;
    f16* a7 = wsh + PI + 11288576;
    f16* a8 = wsh + PI + 13656064;
    f16* s2 = wsh + PI + 16023552;

    float* loc  = (float*)d_out;
    float* conf = loc + 81920;
    float* regr = loc + 204800;
    float* pri  = loc + 245760;

    // weight conversions
    cvt_wt_k<<<dim3((64 * 64 + 255) / 256), 256, 0, stream>>>(w2, wt2, 64, 64);
    cvt_wt_k<<<dim3((128 * 64 + 255) / 256), 256, 0, stream>>>(w3, wt3, 128, 64);
    cvt_wt_k<<<dim3((128 * 128 + 255) / 256), 256, 0, stream>>>(w4, wt4, 128, 128);
    cvt_wt_k<<<dim3((256 * 128 + 255) / 256), 256, 0, stream>>>(w5, wt5, 256, 128);
    cvt_wt_k<<<dim3((256 * 256 + 255) / 256), 256, 0, stream>>>(w6, wt6, 256, 256);
    cvt_wt_k<<<dim3((256 * 256 + 255) / 256), 256, 0, stream>>>(w7, wt7, 256, 256);
    cvt_wt_k<<<dim3((256 * 256 + 255) / 256), 256, 0, stream>>>(w8, wt8, 256, 256);
    cvt_wt1_k<<<dim3(1), 64, 0, stream>>>(w1, wt1);
    cvt_wth_k<<<dim3(144), 256, 0, stream>>>(lw1, cw1, rw1, wth1);
    cvt_wth_k<<<dim3(144), 256, 0, stream>>>(lw2, cw2, rw2, wth2);

    // conv1..conv6, G items per dispatch; aliased halos re-zeroed in r5-proven order
    for (int grp = 0; grp < NGRP; ++grp) {
        f16* x6g = x6p + (long)grp * G * 1115136;
        halo_k<<<dim3((G * (2 * 514 + 2 * 512) * 64 + 255) / 256), 256, 0, stream>>>(a1, 512, 512, 64, A1S, G);
        halo_k<<<dim3((G * (2 * 258 + 2 * 256) * 64 + 255) / 256), 256, 0, stream>>>(p1, 256, 256, 64, P1S, G);
        convmf1_k<<<dim3(8, 64, G), 256, 0, stream>>>(x, grp * G, wt1, b1, a1, A1S);
        convmf_k<64, 64, 64, 2, 4, 8, 1, true><<<dim3(8, 128, G), 512, 0, stream>>>(
            a1, wt2, b2, p1, 512, 512, 1, A1S, P1S);
        halo_k<<<dim3((G * (2 * 258 + 2 * 256) * 128 + 255) / 256), 256, 0, stream>>>(a3, 256, 256, 128, A3S, G);
        convmf_k<64, 128, 64, 2, 4, 8, 1, false><<<dim3(4, 64, 2 * G), 512, 0, stream>>>(
            p1, wt3, b3, a3, 256, 256, 2, P1S, A3S);
        halo_k<<<dim3((G * (2 * 130 + 2 * 128) * 128 + 255) / 256), 256, 0, stream>>>(p2, 128, 128, 128, P2S, G);
        convmf_k<128, 128, 64, 2, 4, 8, 1, true><<<dim3(4, 64, 2 * G), 512, 0, stream>>>(
            a3, wt4, b4, p2, 256, 256, 2, A3S, P2S);
        halo_k<<<dim3((G * (2 * 130 + 2 * 128) * 256 + 255) / 256), 256, 0, stream>>>(a5, 128, 128, 256, A5S, G);
        convmf_k<128, 256, 64, 2, 4, 8, 1, false><<<dim3(2, 32, 4 * G), 512, 0, stream>>>(
            p2, wt5, b5, a5, 128, 128, 4, P2S, A5S);
        convmf_k<256, 256, 64, 2, 4, 8, 1, true><<<dim3(2, 32, 4 * G), 512, 0, stream>>>(
            a5, wt6, b6, x6g, 128, 128, 4, A5S, 1115136);
    }

    // phase-2 halos (group region now dead)
    halo_k<<<dim3((8 * (2 * 66 + 2 * 64) * 256 + 255) / 256), 256, 0, stream>>>(s1, 64, 64, 256, 1115136, 8);
    halo_k<<<dim3((8 * (2 * 34 + 2 * 32) * 256 + 255) / 256), 256, 0, stream>>>(p4, 32, 32, 256, 295936, 8);
    halo_k<<<dim3((8 * (2 * 34 + 2 * 32) * 256 + 255) / 256), 256, 0, stream>>>(a7, 32, 32, 256, 295936, 8);
    halo_k<<<dim3((8 * (2 * 34 + 2 * 32) * 256 + 255) / 256), 256, 0, stream>>>(s2, 32, 32, 256, 295936, 8);

    l2n_k<<<dim3((32768 + 255) / 256), 256, 0, stream>>>(x6p, g1, s1, 64, 1115136, 32768);
    mp_k<<<dim3((262144 + 255) / 256), 256, 0, stream>>>(x6p, p4);
    convmf_k<256, 256, 32, 2, 2, 4, 2, false><<<dim3(1, 8, 32), 256, 0, stream>>>(
        p4, wt7, b7, a7, 32, 32, 4, 295936, 295936);
    convmf_k<256, 256, 32, 2, 2, 4, 2, false><<<dim3(1, 8, 32), 256, 0, stream>>>(
        a7, wt8, b8, a8, 32, 32, 4, 295936, 295936);
    l2n_k<<<dim3((8192 + 255) / 256), 256, 0, stream>>>(a8, g2, s2, 32, 295936, 8192);

    headconv_k<64><<<dim3(1, 64, 8), 256, 0, stream>>>(
        s1, 1115136, wth1, lb1, cb1, rb1, loc, conf, regr, 64, 0);
    headconv_k<32><<<dim3(1, 16, 8), 256, 0, stream>>>(
        s2, 295936, wth2, lb2, cb2, rb2, loc, conf, regr, 32, 4096);
    priors_k<<<dim3(20), 256, 0, stream>>>(pri);

    (void)in_sizes; (void)n_in; (void)out_size; (void)ws_size;
}

// Round 16
// 1317.044 us; speedup vs baseline: 1.1763x; 1.0768x over previous
//
#include <hip/hip_runtime.h>

typedef _Float16 f16;
typedef _Float16 f16x8 __attribute__((ext_vector_type(8)));
typedef float f32x4 __attribute__((ext_vector_type(4)));

__device__ __forceinline__ f32x4 mfma16(f16x8 a, f16x8 b, f32x4 c) {
    return __builtin_amdgcn_mfma_f32_16x16x32_f16(a, b, c, 0, 0, 0);
}

template<int N>
__device__ __forceinline__ void waitcnt_vm() {
    asm volatile("s_waitcnt vmcnt(%0)" :: "i"(N) : "memory");
}

// ---------------- main implicit-GEMM 3x3 conv, f16 MFMA ----------------
// Y-LOOPED deep pipeline: each block owns YL y-tiles; steps = YL*NC.
// Per step s=(yt,c): (1) B(c)->regs (older vmem than stage DMAs, so B-waits
// can't drain them); (2) STAGE(s+1 -> buf[(s+1)&1]); (3) vmcnt(NISS) + RAW
// s_barrier (no compiler vmcnt(0) drain); (4) pure LDS+MFMA from buf[s&1].
// Epilogue per yt (overlaps next tile's stage latency), acc reset.
// Part-major linear LDS (r12-proven, 0 bank conflicts), 4 waves.
template<int IC, int OC, int BX, int WY, int WO, int MT, int NT, int YL, bool POOL>
__global__ __launch_bounds__(256) void convmf_k(
    const f16* __restrict__ in, const f16* __restrict__ wt,
    const float* __restrict__ bias, f16* __restrict__ out,
    int H, int W, int ocBlocks, long inStride, long outStride)
{
    constexpr int WROWS = MT * 16 / BX;
    constexpr int BROWS = WROWS * WY;
    constexpr int SR = BROWS + 2;
    constexpr int SC = BX + 2;
    constexpr int LOG = (BX == 64) ? 6 : 5;
    constexpr int NPIX = SR * SC;
    constexpr int NISS = (NPIX + 63) / 64;   // DMA issues per wave per step
    constexpr int NPpad = NISS * 64;
    constexpr int NC = IC / 32;              // K-chunks (power of 2)
    constexpr int NSTEPS = YL * NC;
    static_assert(WY * WO == 4, "4 waves");
    static_assert(!POOL || (BX == 64 && MT == 8), "pool path assumes BX==64, MT==8");
    __shared__ f16 lds[2 * 4 * NPpad * 8];

    const int tid  = threadIdx.x;
    const int lane = tid & 63;
    const int wv   = tid >> 6;
    const int wy   = wv / WO;
    const int wo   = wv % WO;
    const int part = wv & 3;
    const int lm   = lane & 15;
    const int lk   = lane >> 4;
    const int x0   = blockIdx.x * BX;
    const int zb   = blockIdx.z;
    const int n    = zb / ocBlocks;
    const int oc0  = (zb - n * ocBlocks) * (16 * NT * WO) + wo * (16 * NT);
    in  += (long)n * inStride;
    out += (long)n * outStride;

    const int Wp = W + 2;

    // stage step s1 = (yt, chunk) into buf[s1&1]
    auto STAGE = [&](int s1) {
        const int yt2 = s1 / NC;
        const int c2  = s1 & (NC - 1);
        const int bi  = s1 & 1;
        const f16* ip = in + ((long)(blockIdx.y * YL + yt2) * BROWS * Wp + x0) * IC
                        + part * 8 + c2 * 32;
#pragma unroll
        for (int i = 0; i < NISS; ++i) {
            int p = i * 64 + lane;
            int pc = (p < NPIX) ? p : 0;          // pad lanes: harmless in-range load
            int r = pc / SC, xcol = pc - r * SC;
            __builtin_amdgcn_global_load_lds(
                (const __attribute__((address_space(1))) void*)(ip + ((long)r * Wp + xcol) * IC),
                (__attribute__((address_space(3))) void*)&lds[((bi * 4 + part) * NPpad + i * 64) * 8],
                16, 0, 0);
        }
    };

    f32x4 acc[MT][NT];
#pragma unroll
    for (int mt = 0; mt < MT; ++mt)
#pragma unroll
        for (int nt = 0; nt < NT; ++nt)
            acc[mt][nt] = (f32x4){0.f, 0.f, 0.f, 0.f};

    STAGE(0);
    for (int yt = 0; yt < YL; ++yt) {
        const int y0 = (blockIdx.y * YL + yt) * BROWS;
        for (int c = 0; c < NC; ++c) {
            const int s = yt * NC + c;
            const int cur = s & 1;
            const int ic0 = c * 32;

            // (1) B(c) -> regs, BEFORE next stage DMAs
            f16x8 ball[9][NT];
#pragma unroll
            for (int t = 0; t < 9; ++t)
#pragma unroll
                for (int nt = 0; nt < NT; ++nt)
                    ball[t][nt] = *(const f16x8*)(wt + ((long)t * OC + oc0 + nt * 16 + lm) * IC
                                                  + ic0 + lk * 8);

            // (2) prefetch next step; (3) counted wait + raw barrier
            if (s + 1 < NSTEPS) {
                STAGE(s + 1);
                waitcnt_vm<NISS>();   // step s landed; s+1 stays in flight
            } else {
                waitcnt_vm<0>();
            }
            __builtin_amdgcn_s_barrier();
            asm volatile("" ::: "memory");

            // (4) pure LDS + MFMA
#pragma unroll
            for (int t = 0; t < 9; ++t) {
                const int dy = t / 3, dx = t - dy * 3;
#pragma unroll
                for (int mt = 0; mt < MT; ++mt) {
                    int pos = mt * 16 + lm;
                    int xx = pos & (BX - 1);
                    int yy = wy * WROWS + (pos >> LOG);
                    int pp = (yy + dy) * SC + xx + dx;
                    f16x8 a = *(const f16x8*)&lds[((cur * 4 + lk) * NPpad + pp) * 8];
#pragma unroll
                    for (int nt = 0; nt < NT; ++nt)
                        acc[mt][nt] = mfma16(a, ball[t][nt], acc[mt][nt]);
                }
            }
            asm volatile("" ::: "memory");
            __builtin_amdgcn_s_barrier();   // buf[cur] free for restage at step s+1
        }

        // per-tile epilogue (overlaps next tile's in-flight stage), then reset acc
        if constexpr (!POOL) {
#pragma unroll
            for (int nt = 0; nt < NT; ++nt) {
                int oc = oc0 + nt * 16 + lm;
                float bs = bias[oc];
#pragma unroll
                for (int mt = 0; mt < MT; ++mt) {
#pragma unroll
                    for (int r = 0; r < 4; ++r) {
                        int pos = mt * 16 + lk * 4 + r;
                        int xx = pos & (BX - 1);
                        int yy = wy * WROWS + (pos >> LOG);
                        float v = fmaxf(acc[mt][nt][r] + bs, 0.f);
                        out[((long)(y0 + yy + 1) * (W + 2) + (x0 + xx + 1)) * OC + oc] = (f16)v;
                    }
                }
            }
        } else {
            const int Wo = W >> 1;
#pragma unroll
            for (int nt = 0; nt < NT; ++nt) {
                int oc = oc0 + nt * 16 + lm;
                float bs = bias[oc];
#pragma unroll
                for (int mt = 0; mt < 4; ++mt) {
#pragma unroll
                    for (int r = 0; r < 4; r += 2) {
                        float v = fmaxf(fmaxf(acc[mt][nt][r], acc[mt][nt][r + 1]),
                                        fmaxf(acc[mt + 4][nt][r], acc[mt + 4][nt][r + 1]));
                        v = fmaxf(v + bs, 0.f);
                        int pos = mt * 16 + lk * 4 + r;
                        int xo = pos >> 1;
                        out[((long)((y0 >> 1) + wy + 1) * (Wo + 2) + ((x0 >> 1) + xo + 1)) * OC + oc] = (f16)v;
                    }
                }
            }
        }
#pragma unroll
        for (int mt = 0; mt < MT; ++mt)
#pragma unroll
            for (int nt = 0; nt < NT; ++nt)
                acc[mt][nt] = (f32x4){0.f, 0.f, 0.f, 0.f};
    }
}

// ---------------- conv1: IC=2, im2col in LDS, K padded to 32 (r5-proven) ----------------
__global__ __launch_bounds__(256) void convmf1_k(
    const float* __restrict__ x, int itemBase,
    const f16* __restrict__ wt1,  // [64][32] f16, k=2t+ic, zero-padded
    const float* __restrict__ bias, f16* __restrict__ out, long outStride)
{
    __shared__ f16 ldsx[10 * 66 * 2];
    __shared__ f16 ldsa[512 * 40];
    const int tid = threadIdx.x;
    const int lane = tid & 63;
    const int wv = tid >> 6;
    const int lm = lane & 15;
    const int lk = lane >> 4;
    const int x0 = blockIdx.x * 64;
    const int y0 = blockIdx.y * 8;
    const float* xb = x + (long)(itemBase + blockIdx.z) * 2 * 512 * 512;
    out += (long)blockIdx.z * outStride;

    for (int s = tid; s < 660; s += 256) {
        int r = s / 66, xc = s - r * 66;
        int gy = y0 + r - 1, gx = x0 + xc - 1;
        f16 v0 = (f16)0.f, v1 = (f16)0.f;
        if ((unsigned)gy < 512u && (unsigned)gx < 512u) {
            v0 = (f16)xb[(long)gy * 512 + gx];
            v1 = (f16)xb[262144 + (long)gy * 512 + gx];
        }
        ldsx[(r * 66 + xc) * 2]     = v0;
        ldsx[(r * 66 + xc) * 2 + 1] = v1;
    }
    __syncthreads();
    for (int s = tid; s < 2048; s += 256) {
        int pos = s >> 2, g = s & 3;
        int row = pos >> 6, col = pos & 63;
        f16x8 v;
#pragma unroll
        for (int j = 0; j < 8; ++j) {
            int k = g * 8 + j;
            f16 val = (f16)0.f;
            if (k < 18) {
                int t = k >> 1, ic = k & 1;
                int dy = t / 3, dx = t - dy * 3;
                val = ldsx[((row + dy) * 66 + col + dx) * 2 + ic];
            }
            v[j] = val;
        }
        *(f16x8*)&ldsa[pos * 40 + g * 8] = v;
    }
    __syncthreads();

    f32x4 acc[8][4];
#pragma unroll
    for (int mt = 0; mt < 8; ++mt)
#pragma unroll
        for (int nt = 0; nt < 4; ++nt)
            acc[mt][nt] = (f32x4){0.f, 0.f, 0.f, 0.f};

    f16x8 b0 = *(const f16x8*)(wt1 + (0 * 16 + lm) * 32 + lk * 8);
    f16x8 b1 = *(const f16x8*)(wt1 + (1 * 16 + lm) * 32 + lk * 8);
    f16x8 b2 = *(const f16x8*)(wt1 + (2 * 16 + lm) * 32 + lk * 8);
    f16x8 b3 = *(const f16x8*)(wt1 + (3 * 16 + lm) * 32 + lk * 8);
#pragma unroll
    for (int mt = 0; mt < 8; ++mt) {
        int pos = wv * 128 + mt * 16 + lm;
        f16x8 a = *(const f16x8*)&ldsa[pos * 40 + lk * 8];
        acc[mt][0] = mfma16(a, b0, acc[mt][0]);
        acc[mt][1] = mfma16(a, b1, acc[mt][1]);
        acc[mt][2] = mfma16(a, b2, acc[mt][2]);
        acc[mt][3] = mfma16(a, b3, acc[mt][3]);
    }
#pragma unroll
    for (int nt = 0; nt < 4; ++nt) {
        int oc = nt * 16 + lm;
        float bs = bias[oc];
#pragma unroll
        for (int mt = 0; mt < 8; ++mt) {
#pragma unroll
            for (int r = 0; r < 4; ++r) {
                int pos = wv * 128 + mt * 16 + lk * 4 + r;
                int xx = pos & 63, yy = pos >> 6;
                float v = fmaxf(acc[mt][nt][r] + bs, 0.f);
                out[((long)(y0 + yy + 1) * 514 + (x0 + xx + 1)) * 64 + oc] = (f16)v;
            }
        }
    }
}

// ---------------- fused heads (loc+conf+regr) as one 16-oc MFMA conv ----------------
template<int BX>
__global__ __launch_bounds__(256) void headconv_k(
    const f16* __restrict__ s, long sStride, const f16* __restrict__ wth,
    const float* __restrict__ lb, const float* __restrict__ cb, const float* __restrict__ rb,
    float* __restrict__ loc, float* __restrict__ conf, float* __restrict__ regr,
    int W, int posoff)
{
    constexpr int BY = (BX == 64) ? 1 : 2;
    constexpr int SR = BY + 2, SC = BX + 2;
    constexpr int LOG = (BX == 64) ? 6 : 5;
    __shared__ f16 lds[SR * SC * 40];
    const int tid = threadIdx.x;
    const int lane = tid & 63;
    const int wv = tid >> 6;
    const int lm = lane & 15;
    const int lk = lane >> 4;
    const int y0 = blockIdx.y * BY;
    const int b = blockIdx.z;
    s += (long)b * sStride;

    f32x4 acc = (f32x4){0.f, 0.f, 0.f, 0.f};
    const int Wp = W + 2;
    for (int ic0 = 0; ic0 < 256; ic0 += 32) {
        if (ic0) __syncthreads();
        const f16* ip = s + (long)y0 * Wp * 256 + ic0;
        constexpr int TASKS = SR * SC * 4;
        for (int t = tid; t < TASKS; t += 256) {
            int r = t / (SC * 4);
            int rem = t - r * (SC * 4);
            int xcol = rem >> 2, g = rem & 3;
            f16x8 v = *(const f16x8*)(ip + ((long)r * Wp + xcol) * 256 + g * 8);
            *(f16x8*)&lds[(r * SC + xcol) * 40 + g * 8] = v;
        }
        __syncthreads();
        for (int t = 0; t < 9; ++t) {
            int dy = t / 3, dx = t - dy * 3;
            f16x8 bf = *(const f16x8*)(wth + ((long)t * 16 + lm) * 256 + ic0 + lk * 8);
            int pos = wv * 16 + lm;
            int xx = pos & (BX - 1), yy = pos >> LOG;
            f16x8 a = *(const f16x8*)&lds[((yy + dy) * SC + xx + dx) * 40 + lk * 8];
            acc = mfma16(a, bf, acc);
        }
    }
#pragma unroll
    for (int r = 0; r < 4; ++r) {
        int pos = wv * 16 + lk * 4 + r;
        int xx = pos & (BX - 1), yy = pos >> LOG;
        int P = posoff + (y0 + yy) * W + xx;
        float v = acc[r];
        if (lm < 2)       loc[((long)b * 5120 + P) * 2 + lm]       = v + lb[lm];
        else if (lm < 5)  conf[((long)b * 5120 + P) * 3 + (lm - 2)] = v + cb[lm - 2];
        else if (lm == 5) regr[(long)b * 5120 + P]                  = v + rb[0];
    }
}

// ---------------- small utility kernels ----------------
__global__ __launch_bounds__(256) void cvt_wt_k(const float* __restrict__ w, f16* __restrict__ wt,
                                                int OC, int IC)
{
    int idx = blockIdx.x * 256 + threadIdx.x;
    if (idx >= OC * IC) return;
    int oc = idx / IC, ic = idx - oc * IC;
#pragma unroll
    for (int t = 0; t < 9; ++t)
        wt[((long)t * OC + oc) * IC + ic] = (f16)w[(long)idx * 9 + t];
}

__global__ __launch_bounds__(64) void cvt_wt1_k(const float* __restrict__ w, f16* __restrict__ wt1)
{
    int oc = threadIdx.x;
#pragma unroll
    for (int k = 0; k < 32; ++k) {
        f16 v = (f16)0.f;
        if (k < 18) {
            int t = k >> 1, ic = k & 1;
            v = (f16)w[((long)oc * 2 + ic) * 9 + t];
        }
        wt1[oc * 32 + k] = v;
    }
}

__global__ __launch_bounds__(256) void cvt_wth_k(const float* __restrict__ lw, const float* __restrict__ cw,
                                                 const float* __restrict__ rw, f16* __restrict__ wth)
{
    int idx = blockIdx.x * 256 + threadIdx.x;
    if (idx >= 9 * 16 * 256) return;
    int t = idx / (16 * 256);
    int r = (idx / 256) & 15;
    int ic = idx & 255;
    float v = 0.f;
    if (r < 2)      v = lw[((long)r * 256 + ic) * 9 + t];
    else if (r < 5) v = cw[((long)(r - 2) * 256 + ic) * 9 + t];
    else if (r == 5) v = rw[(long)ic * 9 + t];
    wth[((long)t * 16 + r) * 256 + ic] = (f16)v;
}

__global__ __launch_bounds__(256) void halo_k(f16* __restrict__ buf, int W, int H, int C,
                                              long stride, int items)
{
    int per = (2 * (W + 2) + 2 * H) * C;
    long total = (long)per * items;
    long idx = (long)blockIdx.x * 256 + threadIdx.x;
    if (idx >= total) return;
    int n = idx / per;
    int j = idx - (long)n * per;
    int c = j % C, p = j / C;
    int row, col;
    if (p < W + 2) { row = 0; col = p; }
    else if (p < 2 * (W + 2)) { row = H + 1; col = p - (W + 2); }
    else { int q = p - 2 * (W + 2); row = 1 + (q >> 1); col = (q & 1) ? (W + 1) : 0; }
    buf[(long)n * stride + ((long)row * (W + 2) + col) * C + c] = (f16)0.f;
}

__global__ __launch_bounds__(256) void l2n_k(const f16* __restrict__ in, const float* __restrict__ g,
                                             f16* __restrict__ out, int W, long stride, int total)
{
    int i = blockIdx.x * 256 + threadIdx.x;
    if (i >= total) return;
    int b = i / (W * W);
    int rem = i - b * W * W;
    int y = rem / W, x = rem - y * W;
    long off = (long)b * stride + ((long)(y + 1) * (W + 2) + x + 1) * 256;
    const f16* p = in + off;
    f16* q = out + off;
    float s = 0.f;
    for (int gg = 0; gg < 32; ++gg) {
        f16x8 v = *(const f16x8*)(p + gg * 8);
#pragma unroll
        for (int j = 0; j < 8; ++j) { float f = (float)v[j]; s = fmaf(f, f, s); }
    }
    float inv = 1.f / (sqrtf(s) + 1e-10f);
    for (int gg = 0; gg < 32; ++gg) {
        f16x8 v = *(const f16x8*)(p + gg * 8);
        f16x8 o;
#pragma unroll
        for (int j = 0; j < 8; ++j) o[j] = (f16)(g[gg * 8 + j] * ((float)v[j] * inv));
        *(f16x8*)(q + gg * 8) = o;
    }
}

__global__ __launch_bounds__(256) void mp_k(const f16* __restrict__ in, f16* __restrict__ out)
{
    int idx = blockIdx.x * 256 + threadIdx.x;
    if (idx >= 8 * 32 * 32 * 32) return;
    int gg = idx & 31;
    int xo = (idx >> 5) & 31;
    int yo = (idx >> 10) & 31;
    int b = idx >> 15;
    const f16* p = in + (long)b * 1115136 + ((long)(2 * yo + 1) * 66 + 2 * xo + 1) * 256 + gg * 8;
    f16x8 a0 = *(const f16x8*)p;
    f16x8 a1 = *(const f16x8*)(p + 256);
    f16x8 a2 = *(const f16x8*)(p + 66 * 256);
    f16x8 a3 = *(const f16x8*)(p + 66 * 256 + 256);
    f16x8 o;
#pragma unroll
    for (int j = 0; j < 8; ++j)
        o[j] = (f16)fmaxf(fmaxf((float)a0[j], (float)a1[j]), fmaxf((float)a2[j], (float)a3[j]));
    *(f16x8*)(out + (long)b * 295936 + ((long)(yo + 1) * 34 + xo + 1) * 256 + gg * 8) = o;
}

__global__ __launch_bounds__(256) void priors_k(float* __restrict__ out)
{
    int r = blockIdx.x * 256 + threadIdx.x;
    if (r >= 5120) return;
    float cx, cy;
    if (r < 4096) {
        int i = r >> 6, j = r & 63;
        cx = (j + 0.5f) / 64.0f; cy = (i + 0.5f) / 64.0f;
    } else {
        int rr = r - 4096;
        int i = rr >> 5, j = rr & 31;
        cx = (j + 0.5f) / 32.0f; cy = (i + 0.5f) / 32.0f;
    }
    out[2 * r] = cx;
    out[2 * r + 1] = cy;
}

// ---------------- launch ----------------
extern "C" void kernel_launch(void* const* d_in, const int* in_sizes, int n_in,
                              void* d_out, int out_size, void* d_ws, size_t ws_size,
                              hipStream_t stream)
{
    const float* x  = (const float*)d_in[0];
    const float* w1 = (const float*)d_in[1];  const float* b1 = (const float*)d_in[2];
    const float* w2 = (const float*)d_in[3];  const float* b2 = (const float*)d_in[4];
    const float* w3 = (const float*)d_in[5];  const float* b3 = (const float*)d_in[6];
    const float* w4 = (const float*)d_in[7];  const float* b4 = (const float*)d_in[8];
    const float* w5 = (const float*)d_in[9];  const float* b5 = (const float*)d_in[10];
    const float* w6 = (const float*)d_in[11]; const float* b6 = (const float*)d_in[12];
    const float* w7 = (const float*)d_in[13]; const float* b7 = (const float*)d_in[14];
    const float* w8 = (const float*)d_in[15]; const float* b8 = (const float*)d_in[16];
    const float* g1 = (const float*)d_in[17]; const float* g2 = (const float*)d_in[18];
    const float* lw1 = (const float*)d_in[19]; const float* lb1 = (const float*)d_in[20];
    const float* lw2 = (const float*)d_in[21]; const float* lb2 = (const float*)d_in[22];
    const float* cw1 = (const float*)d_in[23]; const float* cb1 = (const float*)d_in[24];
    const float* cw2 = (const float*)d_in[25]; const float* cb2 = (const float*)d_in[26];
    const float* rw1 = (const float*)d_in[27]; const float* rb1 = (const float*)d_in[28];
    const float* rw2 = (const float*)d_in[29]; const float* rb2 = (const float*)d_in[30];

    f16* wsh = (f16*)d_ws;
    // fixed region (f16 units)
    f16* wt2  = wsh + 0;         // 36864
    f16* wt3  = wsh + 36864;     // 73728
    f16* wt4  = wsh + 110592;    // 147456
    f16* wt5  = wsh + 258048;    // 294912
    f16* wt6  = wsh + 552960;    // 589824
    f16* wt7  = wsh + 1142784;   // 589824
    f16* wt8  = wsh + 1732608;   // 589824
    f16* wt1  = wsh + 2322432;   // 2048
    f16* wth1 = wsh + 2324480;   // 36864
    f16* wth2 = wsh + 2361344;   // 36864
    f16* x6p  = wsh + 2398208;   // 8*66*66*256 = 8921088
    const long PI = 11319296;    // group region base

    // per-item strides (f16 units); slot = a1 region (G*A1S) + p1 region (G*P1S)
    const long A1S = 16908544;   // 514*514*64
    const long P1S = 4260096;    // 258*258*64
    const long A3S = 8520192;    // 258*258*128 (aliases a1 region)
    const long P2S = 2163200;    // 130*130*128 (aliases p1 region)
    const long A5S = 4326400;    // 130*130*256 (aliases a1 region)
    const long PH2 = 18391040;   // phase-2 footprint (s1..s2)

    int G = 1;
    for (int g = 8; g >= 1; g >>= 1) {
        long ext = (long)g * (A1S + P1S); if (ext < PH2) ext = PH2;
        if (2.0 * (double)(PI + ext) <= (double)ws_size) { G = g; break; }
    }
    const int NGRP = 8 / G;

    f16* a1 = wsh + PI;                    // G x A1S (aliased: a3 G x A3S, a5 G x A5S)
    f16* p1 = wsh + PI + (long)G * A1S;    // G x P1S (aliased: p2 G x P2S)
    f16* a3 = a1;
    f16* p2 = p1;
    f16* a5 = a1;
    // phase-2 (after group loop, group region dead)
    f16* s1 = wsh + PI;
    f16* p4 = wsh + PI + 8921088;
    f16* a7 = wsh + PI + 11288576;
    f16* a8 = wsh + PI + 13656064;
    f16* s2 = wsh + PI + 16023552;

    float* loc  = (float*)d_out;
    float* conf = loc + 81920;
    float* regr = loc + 204800;
    float* pri  = loc + 245760;

    // weight conversions
    cvt_wt_k<<<dim3((64 * 64 + 255) / 256), 256, 0, stream>>>(w2, wt2, 64, 64);
    cvt_wt_k<<<dim3((128 * 64 + 255) / 256), 256, 0, stream>>>(w3, wt3, 128, 64);
    cvt_wt_k<<<dim3((128 * 128 + 255) / 256), 256, 0, stream>>>(w4, wt4, 128, 128);
    cvt_wt_k<<<dim3((256 * 128 + 255) / 256), 256, 0, stream>>>(w5, wt5, 256, 128);
    cvt_wt_k<<<dim3((256 * 256 + 255) / 256), 256, 0, stream>>>(w6, wt6, 256, 256);
    cvt_wt_k<<<dim3((256 * 256 + 255) / 256), 256, 0, stream>>>(w7, wt7, 256, 256);
    cvt_wt_k<<<dim3((256 * 256 + 255) / 256), 256, 0, stream>>>(w8, wt8, 256, 256);
    cvt_wt1_k<<<dim3(1), 64, 0, stream>>>(w1, wt1);
    cvt_wth_k<<<dim3(144), 256, 0, stream>>>(lw1, cw1, rw1, wth1);
    cvt_wth_k<<<dim3(144), 256, 0, stream>>>(lw2, cw2, rw2, wth2);

    // conv1..conv6, G items per dispatch; aliased halos re-zeroed in r5-proven order
    for (int grp = 0; grp < NGRP; ++grp) {
        f16* x6g = x6p + (long)grp * G * 1115136;
        halo_k<<<dim3((G * (2 * 514 + 2 * 512) * 64 + 255) / 256), 256, 0, stream>>>(a1, 512, 512, 64, A1S, G);
        halo_k<<<dim3((G * (2 * 258 + 2 * 256) * 64 + 255) / 256), 256, 0, stream>>>(p1, 256, 256, 64, P1S, G);
        convmf1_k<<<dim3(8, 64, G), 256, 0, stream>>>(x, grp * G, wt1, b1, a1, A1S);
        convmf_k<64, 64, 64, 2, 2, 8, 2, 4, true><<<dim3(8, 32, G), 256, 0, stream>>>(
            a1, wt2, b2, p1, 512, 512, 1, A1S, P1S);
        halo_k<<<dim3((G * (2 * 258 + 2 * 256) * 128 + 255) / 256), 256, 0, stream>>>(a3, 256, 256, 128, A3S, G);
        convmf_k<64, 128, 64, 2, 2, 8, 2, 2, false><<<dim3(4, 32, 2 * G), 256, 0, stream>>>(
            p1, wt3, b3, a3, 256, 256, 2, P1S, A3S);
        halo_k<<<dim3((G * (2 * 130 + 2 * 128) * 128 + 255) / 256), 256, 0, stream>>>(p2, 128, 128, 128, P2S, G);
        convmf_k<128, 128, 64, 2, 2, 8, 2, 2, true><<<dim3(4, 32, 2 * G), 256, 0, stream>>>(
            a3, wt4, b4, p2, 256, 256, 2, A3S, P2S);
        halo_k<<<dim3((G * (2 * 130 + 2 * 128) * 256 + 255) / 256), 256, 0, stream>>>(a5, 128, 128, 256, A5S, G);
        convmf_k<128, 256, 64, 2, 2, 8, 2, 1, false><<<dim3(2, 32, 4 * G), 256, 0, stream>>>(
            p2, wt5, b5, a5, 128, 128, 4, P2S, A5S);
        convmf_k<256, 256, 64, 2, 2, 8, 2, 1, true><<<dim3(2, 32, 4 * G), 256, 0, stream>>>(
            a5, wt6, b6, x6g, 128, 128, 4, A5S, 1115136);
    }

    // phase-2 halos (group region now dead)
    halo_k<<<dim3((8 * (2 * 66 + 2 * 64) * 256 + 255) / 256), 256, 0, stream>>>(s1, 64, 64, 256, 1115136, 8);
    halo_k<<<dim3((8 * (2 * 34 + 2 * 32) * 256 + 255) / 256), 256, 0, stream>>>(p4, 32, 32, 256, 295936, 8);
    halo_k<<<dim3((8 * (2 * 34 + 2 * 32) * 256 + 255) / 256), 256, 0, stream>>>(a7, 32, 32, 256, 295936, 8);
    halo_k<<<dim3((8 * (2 * 34 + 2 * 32) * 256 + 255) / 256), 256, 0, stream>>>(s2, 32, 32, 256, 295936, 8);

    l2n_k<<<dim3((32768 + 255) / 256), 256, 0, stream>>>(x6p, g1, s1, 64, 1115136, 32768);
    mp_k<<<dim3((262144 + 255) / 256), 256, 0, stream>>>(x6p, p4);
    convmf_k<256, 256, 32, 2, 2, 4, 2, 1, false><<<dim3(1, 8, 32), 256, 0, stream>>>(
        p4, wt7, b7, a7, 32, 32, 4, 295936, 295936);
    convmf_k<256, 256, 32, 2, 2, 4, 2, 1, false><<<dim3(1, 8, 32), 256, 0, stream>>>(
        a7, wt8, b8, a8, 32, 32, 4, 295936, 295936);
    l2n_k<<<dim3((8192 + 255) / 256), 256, 0, stream>>>(a8, g2, s2, 32, 295936, 8192);

    headconv_k<64><<<dim3(1, 64, 8), 256, 0, stream>>>(
        s1, 1115136, wth1, lb1, cb1, rb1, loc, conf, regr, 64, 0);
    headconv_k<32><<<dim3(1, 16, 8), 256, 0, stream>>>(
        s2, 295936, wth2, lb2, cb2, rb2, loc, conf, regr, 32, 4096);
    priors_k<<<dim3(20), 256, 0, stream>>>(pri);

    (void)in_sizes; (void)n_in; (void)out_size; (void)ws_size;
}

// Round 17
// 1178.649 us; speedup vs baseline: 1.3144x; 1.1174x over previous
//
#include <hip/hip_runtime.h>

typedef _Float16 f16;
typedef _Float16 f16x8 __attribute__((ext_vector_type(8)));
typedef float f32x4 __attribute__((ext_vector_type(4)));

__device__ __forceinline__ f32x4 mfma16(f16x8 a, f16x8 b, f32x4 c) {
    return __builtin_amdgcn_mfma_f32_16x16x32_f16(a, b, c, 0, 0, 0);
}

// ---------------- main implicit-GEMM 3x3 conv, f16 MFMA ----------------
// Wave tile: MT m-tiles (MT*16 pos) x NT n-tiles (NT*16 oc). Block: WY x WO waves.
// DEFAULT launch bounds (r8 lesson: a min-waves clamp spills acc to scratch).
// r10-proven configuration: best measured total (1177 us).
template<int IC, int OC, int BX, int WY, int WO, int MT, int NT, bool POOL>
__global__ __launch_bounds__(256) void convmf_k(
    const f16* __restrict__ in, const f16* __restrict__ wt,
    const float* __restrict__ bias, f16* __restrict__ out,
    int H, int W, int ocBlocks, long inStride, long outStride)
{
    constexpr int WROWS = MT * 16 / BX;
    constexpr int BROWS = WROWS * WY;
    constexpr int SR = BROWS + 2;
    constexpr int SC = BX + 2;
    constexpr int LOG = (BX == 64) ? 6 : 5;
    static_assert(!POOL || (BX == 64 && MT == 8), "pool path assumes BX==64, MT==8");
    __shared__ f16 lds[SR * SC * 40];

    const int tid  = threadIdx.x;
    const int lane = tid & 63;
    const int wv   = tid >> 6;
    const int wy   = wv / WO;
    const int wo   = wv % WO;
    const int lm   = lane & 15;
    const int lk   = lane >> 4;
    const int x0   = blockIdx.x * BX;
    const int y0   = blockIdx.y * BROWS;
    const int zb   = blockIdx.z;
    const int n    = zb / ocBlocks;
    const int oc0  = (zb - n * ocBlocks) * (16 * NT * WO) + wo * (16 * NT);
    in  += (long)n * inStride;
    out += (long)n * outStride;

    f32x4 acc[MT][NT];
#pragma unroll
    for (int mt = 0; mt < MT; ++mt)
#pragma unroll
        for (int nt = 0; nt < NT; ++nt)
            acc[mt][nt] = (f32x4){0.f, 0.f, 0.f, 0.f};

    const int Wp = W + 2;
    for (int ic0 = 0; ic0 < IC; ic0 += 32) {
        if (ic0) __syncthreads();
        const f16* ip = in + ((long)y0 * Wp + x0) * IC + ic0;
        constexpr int TASKS = SR * SC * 4;
        for (int s = tid; s < TASKS; s += 256) {
            int r    = s / (SC * 4);
            int rem  = s - r * (SC * 4);
            int xcol = rem >> 2;
            int g    = rem & 3;
            f16x8 v = *(const f16x8*)(ip + ((long)r * Wp + xcol) * IC + g * 8);
            *(f16x8*)&lds[(r * SC + xcol) * 40 + g * 8] = v;
        }
        __syncthreads();

        for (int t = 0; t < 9; ++t) {
            int dy = t / 3, dx = t - dy * 3;
            const f16* wp = wt + ((long)t * OC + oc0) * IC + ic0 + lk * 8;
            f16x8 bfr[NT];
#pragma unroll
            for (int nt = 0; nt < NT; ++nt)
                bfr[nt] = *(const f16x8*)(wp + (nt * 16 + lm) * IC);
#pragma unroll
            for (int mt = 0; mt < MT; ++mt) {
                int pos = mt * 16 + lm;
                int xx = pos & (BX - 1);
                int yy = wy * WROWS + (pos >> LOG);
                f16x8 a = *(const f16x8*)&lds[((yy + dy) * SC + xx + dx) * 40 + lk * 8];
#pragma unroll
                for (int nt = 0; nt < NT; ++nt)
                    acc[mt][nt] = mfma16(a, bfr[nt], acc[mt][nt]);
            }
        }
    }

    if constexpr (!POOL) {
#pragma unroll
        for (int nt = 0; nt < NT; ++nt) {
            int oc = oc0 + nt * 16 + lm;
            float bs = bias[oc];
#pragma unroll
            for (int mt = 0; mt < MT; ++mt) {
#pragma unroll
                for (int r = 0; r < 4; ++r) {
                    int pos = mt * 16 + lk * 4 + r;
                    int xx = pos & (BX - 1);
                    int yy = wy * WROWS + (pos >> LOG);
                    float v = fmaxf(acc[mt][nt][r] + bs, 0.f);
                    out[((long)(y0 + yy + 1) * (W + 2) + (x0 + xx + 1)) * OC + oc] = (f16)v;
                }
            }
        }
    } else {
        const int Wo = W >> 1;
#pragma unroll
        for (int nt = 0; nt < NT; ++nt) {
            int oc = oc0 + nt * 16 + lm;
            float bs = bias[oc];
#pragma unroll
            for (int mt = 0; mt < 4; ++mt) {
#pragma unroll
                for (int r = 0; r < 4; r += 2) {
                    float v = fmaxf(fmaxf(acc[mt][nt][r], acc[mt][nt][r + 1]),
                                    fmaxf(acc[mt + 4][nt][r], acc[mt + 4][nt][r + 1]));
                    v = fmaxf(v + bs, 0.f);
                    int pos = mt * 16 + lk * 4 + r;
                    int xo = pos >> 1;
                    out[((long)((y0 >> 1) + wy + 1) * (Wo + 2) + ((x0 >> 1) + xo + 1)) * OC + oc] = (f16)v;
                }
            }
        }
    }
}

// ---------------- conv1: IC=2, im2col in LDS, K padded to 32 (r5-proven) ----------------
__global__ __launch_bounds__(256) void convmf1_k(
    const float* __restrict__ x, int itemBase,
    const f16* __restrict__ wt1,  // [64][32] f16, k=2t+ic, zero-padded
    const float* __restrict__ bias, f16* __restrict__ out, long outStride)
{
    __shared__ f16 ldsx[10 * 66 * 2];
    __shared__ f16 ldsa[512 * 40];
    const int tid = threadIdx.x;
    const int lane = tid & 63;
    const int wv = tid >> 6;
    const int lm = lane & 15;
    const int lk = lane >> 4;
    const int x0 = blockIdx.x * 64;
    const int y0 = blockIdx.y * 8;
    const float* xb = x + (long)(itemBase + blockIdx.z) * 2 * 512 * 512;
    out += (long)blockIdx.z * outStride;

    for (int s = tid; s < 660; s += 256) {
        int r = s / 66, xc = s - r * 66;
        int gy = y0 + r - 1, gx = x0 + xc - 1;
        f16 v0 = (f16)0.f, v1 = (f16)0.f;
        if ((unsigned)gy < 512u && (unsigned)gx < 512u) {
            v0 = (f16)xb[(long)gy * 512 + gx];
            v1 = (f16)xb[262144 + (long)gy * 512 + gx];
        }
        ldsx[(r * 66 + xc) * 2]     = v0;
        ldsx[(r * 66 + xc) * 2 + 1] = v1;
    }
    __syncthreads();
    for (int s = tid; s < 2048; s += 256) {
        int pos = s >> 2, g = s & 3;
        int row = pos >> 6, col = pos & 63;
        f16x8 v;
#pragma unroll
        for (int j = 0; j < 8; ++j) {
            int k = g * 8 + j;
            f16 val = (f16)0.f;
            if (k < 18) {
                int t = k >> 1, ic = k & 1;
                int dy = t / 3, dx = t - dy * 3;
                val = ldsx[((row + dy) * 66 + col + dx) * 2 + ic];
            }
            v[j] = val;
        }
        *(f16x8*)&ldsa[pos * 40 + g * 8] = v;
    }
    __syncthreads();

    f32x4 acc[8][4];
#pragma unroll
    for (int mt = 0; mt < 8; ++mt)
#pragma unroll
        for (int nt = 0; nt < 4; ++nt)
            acc[mt][nt] = (f32x4){0.f, 0.f, 0.f, 0.f};

    f16x8 b0 = *(const f16x8*)(wt1 + (0 * 16 + lm) * 32 + lk * 8);
    f16x8 b1 = *(const f16x8*)(wt1 + (1 * 16 + lm) * 32 + lk * 8);
    f16x8 b2 = *(const f16x8*)(wt1 + (2 * 16 + lm) * 32 + lk * 8);
    f16x8 b3 = *(const f16x8*)(wt1 + (3 * 16 + lm) * 32 + lk * 8);
#pragma unroll
    for (int mt = 0; mt < 8; ++mt) {
        int pos = wv * 128 + mt * 16 + lm;
        f16x8 a = *(const f16x8*)&ldsa[pos * 40 + lk * 8];
        acc[mt][0] = mfma16(a, b0, acc[mt][0]);
        acc[mt][1] = mfma16(a, b1, acc[mt][1]);
        acc[mt][2] = mfma16(a, b2, acc[mt][2]);
        acc[mt][3] = mfma16(a, b3, acc[mt][3]);
    }
#pragma unroll
    for (int nt = 0; nt < 4; ++nt) {
        int oc = nt * 16 + lm;
        float bs = bias[oc];
#pragma unroll
        for (int mt = 0; mt < 8; ++mt) {
#pragma unroll
            for (int r = 0; r < 4; ++r) {
                int pos = wv * 128 + mt * 16 + lk * 4 + r;
                int xx = pos & 63, yy = pos >> 6;
                float v = fmaxf(acc[mt][nt][r] + bs, 0.f);
                out[((long)(y0 + yy + 1) * 514 + (x0 + xx + 1)) * 64 + oc] = (f16)v;
            }
        }
    }
}

// ---------------- fused heads (loc+conf+regr) as one 16-oc MFMA conv ----------------
template<int BX>
__global__ __launch_bounds__(256) void headconv_k(
    const f16* __restrict__ s, long sStride, const f16* __restrict__ wth,
    const float* __restrict__ lb, const float* __restrict__ cb, const float* __restrict__ rb,
    float* __restrict__ loc, float* __restrict__ conf, float* __restrict__ regr,
    int W, int posoff)
{
    constexpr int BY = (BX == 64) ? 1 : 2;
    constexpr int SR = BY + 2, SC = BX + 2;
    constexpr int LOG = (BX == 64) ? 6 : 5;
    __shared__ f16 lds[SR * SC * 40];
    const int tid = threadIdx.x;
    const int lane = tid & 63;
    const int wv = tid >> 6;
    const int lm = lane & 15;
    const int lk = lane >> 4;
    const int y0 = blockIdx.y * BY;
    const int b = blockIdx.z;
    s += (long)b * sStride;

    f32x4 acc = (f32x4){0.f, 0.f, 0.f, 0.f};
    const int Wp = W + 2;
    for (int ic0 = 0; ic0 < 256; ic0 += 32) {
        if (ic0) __syncthreads();
        const f16* ip = s + (long)y0 * Wp * 256 + ic0;
        constexpr int TASKS = SR * SC * 4;
        for (int t = tid; t < TASKS; t += 256) {
            int r = t / (SC * 4);
            int rem = t - r * (SC * 4);
            int xcol = rem >> 2, g = rem & 3;
            f16x8 v = *(const f16x8*)(ip + ((long)r * Wp + xcol) * 256 + g * 8);
            *(f16x8*)&lds[(r * SC + xcol) * 40 + g * 8] = v;
        }
        __syncthreads();
        for (int t = 0; t < 9; ++t) {
            int dy = t / 3, dx = t - dy * 3;
            f16x8 bf = *(const f16x8*)(wth + ((long)t * 16 + lm) * 256 + ic0 + lk * 8);
            int pos = wv * 16 + lm;
            int xx = pos & (BX - 1), yy = pos >> LOG;
            f16x8 a = *(const f16x8*)&lds[((yy + dy) * SC + xx + dx) * 40 + lk * 8];
            acc = mfma16(a, bf, acc);
        }
    }
#pragma unroll
    for (int r = 0; r < 4; ++r) {
        int pos = wv * 16 + lk * 4 + r;
        int xx = pos & (BX - 1), yy = pos >> LOG;
        int P = posoff + (y0 + yy) * W + xx;
        float v = acc[r];
        if (lm < 2)       loc[((long)b * 5120 + P) * 2 + lm]       = v + lb[lm];
        else if (lm < 5)  conf[((long)b * 5120 + P) * 3 + (lm - 2)] = v + cb[lm - 2];
        else if (lm == 5) regr[(long)b * 5120 + P]                  = v + rb[0];
    }
}

// ---------------- small utility kernels ----------------
__global__ __launch_bounds__(256) void cvt_wt_k(const float* __restrict__ w, f16* __restrict__ wt,
                                                int OC, int IC)
{
    int idx = blockIdx.x * 256 + threadIdx.x;
    if (idx >= OC * IC) return;
    int oc = idx / IC, ic = idx - oc * IC;
#pragma unroll
    for (int t = 0; t < 9; ++t)
        wt[((long)t * OC + oc) * IC + ic] = (f16)w[(long)idx * 9 + t];
}

__global__ __launch_bounds__(64) void cvt_wt1_k(const float* __restrict__ w, f16* __restrict__ wt1)
{
    int oc = threadIdx.x;
#pragma unroll
    for (int k = 0; k < 32; ++k) {
        f16 v = (f16)0.f;
        if (k < 18) {
            int t = k >> 1, ic = k & 1;
            v = (f16)w[((long)oc * 2 + ic) * 9 + t];
        }
        wt1[oc * 32 + k] = v;
    }
}

__global__ __launch_bounds__(256) void cvt_wth_k(const float* __restrict__ lw, const float* __restrict__ cw,
                                                 const float* __restrict__ rw, f16* __restrict__ wth)
{
    int idx = blockIdx.x * 256 + threadIdx.x;
    if (idx >= 9 * 16 * 256) return;
    int t = idx / (16 * 256);
    int r = (idx / 256) & 15;
    int ic = idx & 255;
    float v = 0.f;
    if (r < 2)      v = lw[((long)r * 256 + ic) * 9 + t];
    else if (r < 5) v = cw[((long)(r - 2) * 256 + ic) * 9 + t];
    else if (r == 5) v = rw[(long)ic * 9 + t];
    wth[((long)t * 16 + r) * 256 + ic] = (f16)v;
}

__global__ __launch_bounds__(256) void halo_k(f16* __restrict__ buf, int W, int H, int C,
                                              long stride, int items)
{
    int per = (2 * (W + 2) + 2 * H) * C;
    long total = (long)per * items;
    long idx = (long)blockIdx.x * 256 + threadIdx.x;
    if (idx >= total) return;
    int n = idx / per;
    int j = idx - (long)n * per;
    int c = j % C, p = j / C;
    int row, col;
    if (p < W + 2) { row = 0; col = p; }
    else if (p < 2 * (W + 2)) { row = H + 1; col = p - (W + 2); }
    else { int q = p - 2 * (W + 2); row = 1 + (q >> 1); col = (q & 1) ? (W + 1) : 0; }
    buf[(long)n * stride + ((long)row * (W + 2) + col) * C + c] = (f16)0.f;
}

__global__ __launch_bounds__(256) void l2n_k(const f16* __restrict__ in, const float* __restrict__ g,
                                             f16* __restrict__ out, int W, long stride, int total)
{
    int i = blockIdx.x * 256 + threadIdx.x;
    if (i >= total) return;
    int b = i / (W * W);
    int rem = i - b * W * W;
    int y = rem / W, x = rem - y * W;
    long off = (long)b * stride + ((long)(y + 1) * (W + 2) + x + 1) * 256;
    const f16* p = in + off;
    f16* q = out + off;
    float s = 0.f;
    for (int gg = 0; gg < 32; ++gg) {
        f16x8 v = *(const f16x8*)(p + gg * 8);
#pragma unroll
        for (int j = 0; j < 8; ++j) { float f = (float)v[j]; s = fmaf(f, f, s); }
    }
    float inv = 1.f / (sqrtf(s) + 1e-10f);
    for (int gg = 0; gg < 32; ++gg) {
        f16x8 v = *(const f16x8*)(p + gg * 8);
        f16x8 o;
#pragma unroll
        for (int j = 0; j < 8; ++j) o[j] = (f16)(g[gg * 8 + j] * ((float)v[j] * inv));
        *(f16x8*)(q + gg * 8) = o;
    }
}

__global__ __launch_bounds__(256) void mp_k(const f16* __restrict__ in, f16* __restrict__ out)
{
    int idx = blockIdx.x * 256 + threadIdx.x;
    if (idx >= 8 * 32 * 32 * 32) return;
    int gg = idx & 31;
    int xo = (idx >> 5) & 31;
    int yo = (idx >> 10) & 31;
    int b = idx >> 15;
    const f16* p = in + (long)b * 1115136 + ((long)(2 * yo + 1) * 66 + 2 * xo + 1) * 256 + gg * 8;
    f16x8 a0 = *(const f16x8*)p;
    f16x8 a1 = *(const f16x8*)(p + 256);
    f16x8 a2 = *(const f16x8*)(p + 66 * 256);
    f16x8 a3 = *(const f16x8*)(p + 66 * 256 + 256);
    f16x8 o;
#pragma unroll
    for (int j = 0; j < 8; ++j)
        o[j] = (f16)fmaxf(fmaxf((float)a0[j], (float)a1[j]), fmaxf((float)a2[j], (float)a3[j]));
    *(f16x8*)(out + (long)b * 295936 + ((long)(yo + 1) * 34 + xo + 1) * 256 + gg * 8) = o;
}

__global__ __launch_bounds__(256) void priors_k(float* __restrict__ out)
{
    int r = blockIdx.x * 256 + threadIdx.x;
    if (r >= 5120) return;
    float cx, cy;
    if (r < 4096) {
        int i = r >> 6, j = r & 63;
        cx = (j + 0.5f) / 64.0f; cy = (i + 0.5f) / 64.0f;
    } else {
        int rr = r - 4096;
        int i = rr >> 5, j = rr & 31;
        cx = (j + 0.5f) / 32.0f; cy = (i + 0.5f) / 32.0f;
    }
    out[2 * r] = cx;
    out[2 * r + 1] = cy;
}

// ---------------- launch ----------------
extern "C" void kernel_launch(void* const* d_in, const int* in_sizes, int n_in,
                              void* d_out, int out_size, void* d_ws, size_t ws_size,
                              hipStream_t stream)
{
    const float* x  = (const float*)d_in[0];
    const float* w1 = (const float*)d_in[1];  const float* b1 = (const float*)d_in[2];
    const float* w2 = (const float*)d_in[3];  const float* b2 = (const float*)d_in[4];
    const float* w3 = (const float*)d_in[5];  const float* b3 = (const float*)d_in[6];
    const float* w4 = (const float*)d_in[7];  const float* b4 = (const float*)d_in[8];
    const float* w5 = (const float*)d_in[9];  const float* b5 = (const float*)d_in[10];
    const float* w6 = (const float*)d_in[11]; const float* b6 = (const float*)d_in[12];
    const float* w7 = (const float*)d_in[13]; const float* b7 = (const float*)d_in[14];
    const float* w8 = (const float*)d_in[15]; const float* b8 = (const float*)d_in[16];
    const float* g1 = (const float*)d_in[17]; const float* g2 = (const float*)d_in[18];
    const float* lw1 = (const float*)d_in[19]; const float* lb1 = (const float*)d_in[20];
    const float* lw2 = (const float*)d_in[21]; const float* lb2 = (const float*)d_in[22];
    const float* cw1 = (const float*)d_in[23]; const float* cb1 = (const float*)d_in[24];
    const float* cw2 = (const float*)d_in[25]; const float* cb2 = (const float*)d_in[26];
    const float* rw1 = (const float*)d_in[27]; const float* rb1 = (const float*)d_in[28];
    const float* rw2 = (const float*)d_in[29]; const float* rb2 = (const float*)d_in[30];

    f16* wsh = (f16*)d_ws;
    // fixed region (f16 units)
    f16* wt2  = wsh + 0;         // 36864
    f16* wt3  = wsh + 36864;     // 73728
    f16* wt4  = wsh + 110592;    // 147456
    f16* wt5  = wsh + 258048;    // 294912
    f16* wt6  = wsh + 552960;    // 589824
    f16* wt7  = wsh + 1142784;   // 589824
    f16* wt8  = wsh + 1732608;   // 589824
    f16* wt1  = wsh + 2322432;   // 2048
    f16* wth1 = wsh + 2324480;   // 36864
    f16* wth2 = wsh + 2361344;   // 36864
    f16* x6p  = wsh + 2398208;   // 8*66*66*256 = 8921088
    const long PI = 11319296;    // group region base

    // per-item strides (f16 units); slot = a1 region (G*A1S) + p1 region (G*P1S)
    const long A1S = 16908544;   // 514*514*64
    const long P1S = 4260096;    // 258*258*64
    const long A3S = 8520192;    // 258*258*128 (aliases a1 region)
    const long P2S = 2163200;    // 130*130*128 (aliases p1 region)
    const long A5S = 4326400;    // 130*130*256 (aliases a1 region)
    const long PH2 = 18391040;   // phase-2 footprint (s1..s2)

    int G = 1;
    for (int g = 8; g >= 1; g >>= 1) {
        long ext = (long)g * (A1S + P1S); if (ext < PH2) ext = PH2;
        if (2.0 * (double)(PI + ext) <= (double)ws_size) { G = g; break; }
    }
    const int NGRP = 8 / G;

    f16* a1 = wsh + PI;                    // G x A1S (aliased: a3 G x A3S, a5 G x A5S)
    f16* p1 = wsh + PI + (long)G * A1S;    // G x P1S (aliased: p2 G x P2S)
    f16* a3 = a1;
    f16* p2 = p1;
    f16* a5 = a1;
    // phase-2 (after group loop, group region dead)
    f16* s1 = wsh + PI;
    f16* p4 = wsh + PI + 8921088;
    f16* a7 = wsh + PI + 11288576;
    f16* a8 = wsh + PI + 13656064;
    f16* s2 = wsh + PI + 16023552;

    float* loc  = (float*)d_out;
    float* conf = loc + 81920;
    float* regr = loc + 204800;
    float* pri  = loc + 245760;

    // weight conversions
    cvt_wt_k<<<dim3((64 * 64 + 255) / 256), 256, 0, stream>>>(w2, wt2, 64, 64);
    cvt_wt_k<<<dim3((128 * 64 + 255) / 256), 256, 0, stream>>>(w3, wt3, 128, 64);
    cvt_wt_k<<<dim3((128 * 128 + 255) / 256), 256, 0, stream>>>(w4, wt4, 128, 128);
    cvt_wt_k<<<dim3((256 * 128 + 255) / 256), 256, 0, stream>>>(w5, wt5, 256, 128);
    cvt_wt_k<<<dim3((256 * 256 + 255) / 256), 256, 0, stream>>>(w6, wt6, 256, 256);
    cvt_wt_k<<<dim3((256 * 256 + 255) / 256), 256, 0, stream>>>(w7, wt7, 256, 256);
    cvt_wt_k<<<dim3((256 * 256 + 255) / 256), 256, 0, stream>>>(w8, wt8, 256, 256);
    cvt_wt1_k<<<dim3(1), 64, 0, stream>>>(w1, wt1);
    cvt_wth_k<<<dim3(144), 256, 0, stream>>>(lw1, cw1, rw1, wth1);
    cvt_wth_k<<<dim3(144), 256, 0, stream>>>(lw2, cw2, rw2, wth2);

    // conv1..conv6, G items per dispatch; aliased halos re-zeroed in r5-proven order
    for (int grp = 0; grp < NGRP; ++grp) {
        f16* x6g = x6p + (long)grp * G * 1115136;
        halo_k<<<dim3((G * (2 * 514 + 2 * 512) * 64 + 255) / 256), 256, 0, stream>>>(a1, 512, 512, 64, A1S, G);
        halo_k<<<dim3((G * (2 * 258 + 2 * 256) * 64 + 255) / 256), 256, 0, stream>>>(p1, 256, 256, 64, P1S, G);
        convmf1_k<<<dim3(8, 64, G), 256, 0, stream>>>(x, grp * G, wt1, b1, a1, A1S);
        convmf_k<64, 64, 64, 2, 2, 8, 2, true><<<dim3(8, 128, G), 256, 0, stream>>>(
            a1, wt2, b2, p1, 512, 512, 1, A1S, P1S);
        halo_k<<<dim3((G * (2 * 258 + 2 * 256) * 128 + 255) / 256), 256, 0, stream>>>(a3, 256, 256, 128, A3S, G);
        convmf_k<64, 128, 64, 2, 2, 8, 2, false><<<dim3(4, 64, 2 * G), 256, 0, stream>>>(
            p1, wt3, b3, a3, 256, 256, 2, P1S, A3S);
        halo_k<<<dim3((G * (2 * 130 + 2 * 128) * 128 + 255) / 256), 256, 0, stream>>>(p2, 128, 128, 128, P2S, G);
        convmf_k<128, 128, 64, 2, 2, 8, 2, true><<<dim3(4, 64, 2 * G), 256, 0, stream>>>(
            a3, wt4, b4, p2, 256, 256, 2, A3S, P2S);
        halo_k<<<dim3((G * (2 * 130 + 2 * 128) * 256 + 255) / 256), 256, 0, stream>>>(a5, 128, 128, 256, A5S, G);
        convmf_k<128, 256, 64, 2, 2, 8, 2, false><<<dim3(2, 32, 4 * G), 256, 0, stream>>>(
            p2, wt5, b5, a5, 128, 128, 4, P2S, A5S);
        convmf_k<256, 256, 64, 2, 2, 8, 2, true><<<dim3(2, 32, 4 * G), 256, 0, stream>>>(
            a5, wt6, b6, x6g, 128, 128, 4, A5S, 1115136);
    }

    // phase-2 halos (group region now dead)
    halo_k<<<dim3((8 * (2 * 66 + 2 * 64) * 256 + 255) / 256), 256, 0, stream>>>(s1, 64, 64, 256, 1115136, 8);
    halo_k<<<dim3((8 * (2 * 34 + 2 * 32) * 256 + 255) / 256), 256, 0, stream>>>(p4, 32, 32, 256, 295936, 8);
    halo_k<<<dim3((8 * (2 * 34 + 2 * 32) * 256 + 255) / 256), 256, 0, stream>>>(a7, 32, 32, 256, 295936, 8);
    halo_k<<<dim3((8 * (2 * 34 + 2 * 32) * 256 + 255) / 256), 256, 0, stream>>>(s2, 32, 32, 256, 295936, 8);

    l2n_k<<<dim3((32768 + 255) / 256), 256, 0, stream>>>(x6p, g1, s1, 64, 1115136, 32768);
    mp_k<<<dim3((262144 + 255) / 256), 256, 0, stream>>>(x6p, p4);
    convmf_k<256, 256, 32, 2, 2, 4, 4, false><<<dim3(1, 8, 16), 256, 0, stream>>>(
        p4, wt7, b7, a7, 32, 32, 2, 295936, 295936);
    convmf_k<256, 256, 32, 2, 2, 4, 4, false><<<dim3(1, 8, 16), 256, 0, stream>>>(
        a7, wt8, b8, a8, 32, 32, 2, 295936, 295936);
    l2n_k<<<dim3((8192 + 255) / 256), 256, 0, stream>>>(a8, g2, s2, 32, 295936, 8192);

    headconv_k<64><<<dim3(1, 64, 8), 256, 0, stream>>>(
        s1, 1115136, wth1, lb1, cb1, rb1, loc, conf, regr, 64, 0);
    headconv_k<32><<<dim3(1, 16, 8), 256, 0, stream>>>(
        s2, 295936, wth2, lb2, cb2, rb2, loc, conf, regr, 32, 4096);
    priors_k<<<dim3(20), 256, 0, stream>>>(pri);

    (void)in_sizes; (void)n_in; (void)out_size; (void)ws_size;
}

// Round 18
// 1156.373 us; speedup vs baseline: 1.3397x; 1.0193x over previous
//
#include <hip/hip_runtime.h>

typedef _Float16 f16;
typedef _Float16 f16x8 __attribute__((ext_vector_type(8)));
typedef float f32x4 __attribute__((ext_vector_type(4)));

__device__ __forceinline__ f32x4 mfma16(f16x8 a, f16x8 b, f32x4 c) {
    return __builtin_amdgcn_mfma_f32_16x16x32_f16(a, b, c, 0, 0, 0);
}

// ---------------- main implicit-GEMM 3x3 conv, f16 MFMA (r10-proven, untouched) ----------------
template<int IC, int OC, int BX, int WY, int WO, int MT, int NT, bool POOL>
__global__ __launch_bounds__(256) void convmf_k(
    const f16* __restrict__ in, const f16* __restrict__ wt,
    const float* __restrict__ bias, f16* __restrict__ out,
    int H, int W, int ocBlocks, long inStride, long outStride)
{
    constexpr int WROWS = MT * 16 / BX;
    constexpr int BROWS = WROWS * WY;
    constexpr int SR = BROWS + 2;
    constexpr int SC = BX + 2;
    constexpr int LOG = (BX == 64) ? 6 : 5;
    static_assert(!POOL || (BX == 64 && MT == 8), "pool path assumes BX==64, MT==8");
    __shared__ f16 lds[SR * SC * 40];

    const int tid  = threadIdx.x;
    const int lane = tid & 63;
    const int wv   = tid >> 6;
    const int wy   = wv / WO;
    const int wo   = wv % WO;
    const int lm   = lane & 15;
    const int lk   = lane >> 4;
    const int x0   = blockIdx.x * BX;
    const int y0   = blockIdx.y * BROWS;
    const int zb   = blockIdx.z;
    const int n    = zb / ocBlocks;
    const int oc0  = (zb - n * ocBlocks) * (16 * NT * WO) + wo * (16 * NT);
    in  += (long)n * inStride;
    out += (long)n * outStride;

    f32x4 acc[MT][NT];
#pragma unroll
    for (int mt = 0; mt < MT; ++mt)
#pragma unroll
        for (int nt = 0; nt < NT; ++nt)
            acc[mt][nt] = (f32x4){0.f, 0.f, 0.f, 0.f};

    const int Wp = W + 2;
    for (int ic0 = 0; ic0 < IC; ic0 += 32) {
        if (ic0) __syncthreads();
        const f16* ip = in + ((long)y0 * Wp + x0) * IC + ic0;
        constexpr int TASKS = SR * SC * 4;
        for (int s = tid; s < TASKS; s += 256) {
            int r    = s / (SC * 4);
            int rem  = s - r * (SC * 4);
            int xcol = rem >> 2;
            int g    = rem & 3;
            f16x8 v = *(const f16x8*)(ip + ((long)r * Wp + xcol) * IC + g * 8);
            *(f16x8*)&lds[(r * SC + xcol) * 40 + g * 8] = v;
        }
        __syncthreads();

        for (int t = 0; t < 9; ++t) {
            int dy = t / 3, dx = t - dy * 3;
            const f16* wp = wt + ((long)t * OC + oc0) * IC + ic0 + lk * 8;
            f16x8 bfr[NT];
#pragma unroll
            for (int nt = 0; nt < NT; ++nt)
                bfr[nt] = *(const f16x8*)(wp + (nt * 16 + lm) * IC);
#pragma unroll
            for (int mt = 0; mt < MT; ++mt) {
                int pos = mt * 16 + lm;
                int xx = pos & (BX - 1);
                int yy = wy * WROWS + (pos >> LOG);
                f16x8 a = *(const f16x8*)&lds[((yy + dy) * SC + xx + dx) * 40 + lk * 8];
#pragma unroll
                for (int nt = 0; nt < NT; ++nt)
                    acc[mt][nt] = mfma16(a, bfr[nt], acc[mt][nt]);
            }
        }
    }

    if constexpr (!POOL) {
#pragma unroll
        for (int nt = 0; nt < NT; ++nt) {
            int oc = oc0 + nt * 16 + lm;
            float bs = bias[oc];
#pragma unroll
            for (int mt = 0; mt < MT; ++mt) {
#pragma unroll
                for (int r = 0; r < 4; ++r) {
                    int pos = mt * 16 + lk * 4 + r;
                    int xx = pos & (BX - 1);
                    int yy = wy * WROWS + (pos >> LOG);
                    float v = fmaxf(acc[mt][nt][r] + bs, 0.f);
                    out[((long)(y0 + yy + 1) * (W + 2) + (x0 + xx + 1)) * OC + oc] = (f16)v;
                }
            }
        }
    } else {
        const int Wo = W >> 1;
#pragma unroll
        for (int nt = 0; nt < NT; ++nt) {
            int oc = oc0 + nt * 16 + lm;
            float bs = bias[oc];
#pragma unroll
            for (int mt = 0; mt < 4; ++mt) {
#pragma unroll
                for (int r = 0; r < 4; r += 2) {
                    float v = fmaxf(fmaxf(acc[mt][nt][r], acc[mt][nt][r + 1]),
                                    fmaxf(acc[mt + 4][nt][r], acc[mt + 4][nt][r + 1]));
                    v = fmaxf(v + bs, 0.f);
                    int pos = mt * 16 + lk * 4 + r;
                    int xo = pos >> 1;
                    out[((long)((y0 >> 1) + wy + 1) * (Wo + 2) + ((x0 >> 1) + xo + 1)) * OC + oc] = (f16)v;
                }
            }
        }
    }
}

// ---------------- conv1: IC=2, im2col in LDS, K padded to 32 (r5-proven) ----------------
__global__ __launch_bounds__(256) void convmf1_k(
    const float* __restrict__ x, int itemBase,
    const f16* __restrict__ wt1,  // [64][32] f16, k=2t+ic, zero-padded
    const float* __restrict__ bias, f16* __restrict__ out, long outStride)
{
    __shared__ f16 ldsx[10 * 66 * 2];
    __shared__ f16 ldsa[512 * 40];
    const int tid = threadIdx.x;
    const int lane = tid & 63;
    const int wv = tid >> 6;
    const int lm = lane & 15;
    const int lk = lane >> 4;
    const int x0 = blockIdx.x * 64;
    const int y0 = blockIdx.y * 8;
    const float* xb = x + (long)(itemBase + blockIdx.z) * 2 * 512 * 512;
    out += (long)blockIdx.z * outStride;

    for (int s = tid; s < 660; s += 256) {
        int r = s / 66, xc = s - r * 66;
        int gy = y0 + r - 1, gx = x0 + xc - 1;
        f16 v0 = (f16)0.f, v1 = (f16)0.f;
        if ((unsigned)gy < 512u && (unsigned)gx < 512u) {
            v0 = (f16)xb[(long)gy * 512 + gx];
            v1 = (f16)xb[262144 + (long)gy * 512 + gx];
        }
        ldsx[(r * 66 + xc) * 2]     = v0;
        ldsx[(r * 66 + xc) * 2 + 1] = v1;
    }
    __syncthreads();
    for (int s = tid; s < 2048; s += 256) {
        int pos = s >> 2, g = s & 3;
        int row = pos >> 6, col = pos & 63;
        f16x8 v;
#pragma unroll
        for (int j = 0; j < 8; ++j) {
            int k = g * 8 + j;
            f16 val = (f16)0.f;
            if (k < 18) {
                int t = k >> 1, ic = k & 1;
                int dy = t / 3, dx = t - dy * 3;
                val = ldsx[((row + dy) * 66 + col + dx) * 2 + ic];
            }
            v[j] = val;
        }
        *(f16x8*)&ldsa[pos * 40 + g * 8] = v;
    }
    __syncthreads();

    f32x4 acc[8][4];
#pragma unroll
    for (int mt = 0; mt < 8; ++mt)
#pragma unroll
        for (int nt = 0; nt < 4; ++nt)
            acc[mt][nt] = (f32x4){0.f, 0.f, 0.f, 0.f};

    f16x8 b0 = *(const f16x8*)(wt1 + (0 * 16 + lm) * 32 + lk * 8);
    f16x8 b1 = *(const f16x8*)(wt1 + (1 * 16 + lm) * 32 + lk * 8);
    f16x8 b2 = *(const f16x8*)(wt1 + (2 * 16 + lm) * 32 + lk * 8);
    f16x8 b3 = *(const f16x8*)(wt1 + (3 * 16 + lm) * 32 + lk * 8);
#pragma unroll
    for (int mt = 0; mt < 8; ++mt) {
        int pos = wv * 128 + mt * 16 + lm;
        f16x8 a = *(const f16x8*)&ldsa[pos * 40 + lk * 8];
        acc[mt][0] = mfma16(a, b0, acc[mt][0]);
        acc[mt][1] = mfma16(a, b1, acc[mt][1]);
        acc[mt][2] = mfma16(a, b2, acc[mt][2]);
        acc[mt][3] = mfma16(a, b3, acc[mt][3]);
    }
#pragma unroll
    for (int nt = 0; nt < 4; ++nt) {
        int oc = nt * 16 + lm;
        float bs = bias[oc];
#pragma unroll
        for (int mt = 0; mt < 8; ++mt) {
#pragma unroll
            for (int r = 0; r < 4; ++r) {
                int pos = wv * 128 + mt * 16 + lk * 4 + r;
                int xx = pos & 63, yy = pos >> 6;
                float v = fmaxf(acc[mt][nt][r] + bs, 0.f);
                out[((long)(y0 + yy + 1) * 514 + (x0 + xx + 1)) * 64 + oc] = (f16)v;
            }
        }
    }
}

// ---------------- fused heads (loc+conf+regr) as one 16-oc MFMA conv ----------------
template<int BX>
__global__ __launch_bounds__(256) void headconv_k(
    const f16* __restrict__ s, long sStride, const f16* __restrict__ wth,
    const float* __restrict__ lb, const float* __restrict__ cb, const float* __restrict__ rb,
    float* __restrict__ loc, float* __restrict__ conf, float* __restrict__ regr,
    int W, int posoff)
{
    constexpr int BY = (BX == 64) ? 1 : 2;
    constexpr int SR = BY + 2, SC = BX + 2;
    constexpr int LOG = (BX == 64) ? 6 : 5;
    __shared__ f16 lds[SR * SC * 40];
    const int tid = threadIdx.x;
    const int lane = tid & 63;
    const int wv = tid >> 6;
    const int lm = lane & 15;
    const int lk = lane >> 4;
    const int y0 = blockIdx.y * BY;
    const int b = blockIdx.z;
    s += (long)b * sStride;

    f32x4 acc = (f32x4){0.f, 0.f, 0.f, 0.f};
    const int Wp = W + 2;
    for (int ic0 = 0; ic0 < 256; ic0 += 32) {
        if (ic0) __syncthreads();
        const f16* ip = s + (long)y0 * Wp * 256 + ic0;
        constexpr int TASKS = SR * SC * 4;
        for (int t = tid; t < TASKS; t += 256) {
            int r = t / (SC * 4);
            int rem = t - r * (SC * 4);
            int xcol = rem >> 2, g = rem & 3;
            f16x8 v = *(const f16x8*)(ip + ((long)r * Wp + xcol) * 256 + g * 8);
            *(f16x8*)&lds[(r * SC + xcol) * 40 + g * 8] = v;
        }
        __syncthreads();
        for (int t = 0; t < 9; ++t) {
            int dy = t / 3, dx = t - dy * 3;
            f16x8 bf = *(const f16x8*)(wth + ((long)t * 16 + lm) * 256 + ic0 + lk * 8);
            int pos = wv * 16 + lm;
            int xx = pos & (BX - 1), yy = pos >> LOG;
            f16x8 a = *(const f16x8*)&lds[((yy + dy) * SC + xx + dx) * 40 + lk * 8];
            acc = mfma16(a, bf, acc);
        }
    }
#pragma unroll
    for (int r = 0; r < 4; ++r) {
        int pos = wv * 16 + lk * 4 + r;
        int xx = pos & (BX - 1), yy = pos >> LOG;
        int P = posoff + (y0 + yy) * W + xx;
        float v = acc[r];
        if (lm < 2)       loc[((long)b * 5120 + P) * 2 + lm]       = v + lb[lm];
        else if (lm < 5)  conf[((long)b * 5120 + P) * 3 + (lm - 2)] = v + cb[lm - 2];
        else if (lm == 5) regr[(long)b * 5120 + P]                  = v + rb[0];
    }
}

// ---------------- merged weight conversions (10 dispatches -> 1) ----------------
__global__ __launch_bounds__(256) void cvt_all_k(
    const float* __restrict__ w1, const float* __restrict__ w2, const float* __restrict__ w3,
    const float* __restrict__ w4, const float* __restrict__ w5, const float* __restrict__ w6,
    const float* __restrict__ w7, const float* __restrict__ w8,
    const float* __restrict__ lw1, const float* __restrict__ cw1, const float* __restrict__ rw1,
    const float* __restrict__ lw2, const float* __restrict__ cw2, const float* __restrict__ rw2,
    f16* __restrict__ wsh)
{
    int idx = blockIdx.x * 256 + threadIdx.x;
    f16* wt2  = wsh + 0;
    f16* wt3  = wsh + 36864;
    f16* wt4  = wsh + 110592;
    f16* wt5  = wsh + 258048;
    f16* wt6  = wsh + 552960;
    f16* wt7  = wsh + 1142784;
    f16* wt8  = wsh + 1732608;
    f16* wt1  = wsh + 2322432;
    f16* wth1 = wsh + 2324480;
    f16* wth2 = wsh + 2361344;

    auto cw = [](const float* w, f16* wt, int OC, int IC, int i) {
        int oc = i / IC, ic = i - oc * IC;
#pragma unroll
        for (int t = 0; t < 9; ++t)
            wt[((long)t * OC + oc) * IC + ic] = (f16)w[(long)i * 9 + t];
    };
    auto ch = [](const float* lw, const float* cwp, const float* rw, f16* wth, int i) {
        int t = i / 4096;
        int r = (i >> 8) & 15;
        int ic = i & 255;
        float v = 0.f;
        if (r < 2)       v = lw[((long)r * 256 + ic) * 9 + t];
        else if (r < 5)  v = cwp[((long)(r - 2) * 256 + ic) * 9 + t];
        else if (r == 5) v = rw[(long)ic * 9 + t];
        wth[((long)t * 16 + r) * 256 + ic] = (f16)v;
    };

    if (idx < 4096)        cw(w2, wt2, 64, 64, idx);
    else if (idx < 12288)  cw(w3, wt3, 128, 64, idx - 4096);
    else if (idx < 28672)  cw(w4, wt4, 128, 128, idx - 12288);
    else if (idx < 61440)  cw(w5, wt5, 256, 128, idx - 28672);
    else if (idx < 126976) cw(w6, wt6, 256, 256, idx - 61440);
    else if (idx < 192512) cw(w7, wt7, 256, 256, idx - 126976);
    else if (idx < 258048) cw(w8, wt8, 256, 256, idx - 192512);
    else if (idx < 258112) {
        int oc = idx - 258048;
#pragma unroll
        for (int k = 0; k < 32; ++k) {
            f16 v = (f16)0.f;
            if (k < 18) {
                int t = k >> 1, ic = k & 1;
                v = (f16)w1[((long)oc * 2 + ic) * 9 + t];
            }
            wt1[oc * 32 + k] = v;
        }
    }
    else if (idx < 294976) ch(lw1, cw1, rw1, wth1, idx - 258112);
    else if (idx < 331840) ch(lw2, cw2, rw2, wth2, idx - 294976);
}

// ---------------- small utility kernels ----------------
__global__ __launch_bounds__(256) void halo_k(f16* __restrict__ buf, int W, int H, int C,
                                              long stride, int items)
{
    int per = (2 * (W + 2) + 2 * H) * C;
    long total = (long)per * items;
    long idx = (long)blockIdx.x * 256 + threadIdx.x;
    if (idx >= total) return;
    int n = idx / per;
    int j = idx - (long)n * per;
    int c = j % C, p = j / C;
    int row, col;
    if (p < W + 2) { row = 0; col = p; }
    else if (p < 2 * (W + 2)) { row = H + 1; col = p - (W + 2); }
    else { int q = p - 2 * (W + 2); row = 1 + (q >> 1); col = (q & 1) ? (W + 1) : 0; }
    buf[(long)n * stride + ((long)row * (W + 2) + col) * C + c] = (f16)0.f;
}

__global__ __launch_bounds__(256) void l2n_k(const f16* __restrict__ in, const float* __restrict__ g,
                                             f16* __restrict__ out, int W, long stride, int total)
{
    int i = blockIdx.x * 256 + threadIdx.x;
    if (i >= total) return;
    int b = i / (W * W);
    int rem = i - b * W * W;
    int y = rem / W, x = rem - y * W;
    long off = (long)b * stride + ((long)(y + 1) * (W + 2) + x + 1) * 256;
    const f16* p = in + off;
    f16* q = out + off;
    float s = 0.f;
    for (int gg = 0; gg < 32; ++gg) {
        f16x8 v = *(const f16x8*)(p + gg * 8);
#pragma unroll
        for (int j = 0; j < 8; ++j) { float f = (float)v[j]; s = fmaf(f, f, s); }
    }
    float inv = 1.f / (sqrtf(s) + 1e-10f);
    for (int gg = 0; gg < 32; ++gg) {
        f16x8 v = *(const f16x8*)(p + gg * 8);
        f16x8 o;
#pragma unroll
        for (int j = 0; j < 8; ++j) o[j] = (f16)(g[gg * 8 + j] * ((float)v[j] * inv));
        *(f16x8*)(q + gg * 8) = o;
    }
}

__global__ __launch_bounds__(256) void mp_k(const f16* __restrict__ in, f16* __restrict__ out)
{
    int idx = blockIdx.x * 256 + threadIdx.x;
    if (idx >= 8 * 32 * 32 * 32) return;
    int gg = idx & 31;
    int xo = (idx >> 5) & 31;
    int yo = (idx >> 10) & 31;
    int b = idx >> 15;
    const f16* p = in + (long)b * 1115136 + ((long)(2 * yo + 1) * 66 + 2 * xo + 1) * 256 + gg * 8;
    f16x8 a0 = *(const f16x8*)p;
    f16x8 a1 = *(const f16x8*)(p + 256);
    f16x8 a2 = *(const f16x8*)(p + 66 * 256);
    f16x8 a3 = *(const f16x8*)(p + 66 * 256 + 256);
    f16x8 o;
#pragma unroll
    for (int j = 0; j < 8; ++j)
        o[j] = (f16)fmaxf(fmaxf((float)a0[j], (float)a1[j]), fmaxf((float)a2[j], (float)a3[j]));
    *(f16x8*)(out + (long)b * 295936 + ((long)(yo + 1) * 34 + xo + 1) * 256 + gg * 8) = o;
}

__global__ __launch_bounds__(256) void priors_k(float* __restrict__ out)
{
    int r = blockIdx.x * 256 + threadIdx.x;
    if (r >= 5120) return;
    float cx, cy;
    if (r < 4096) {
        int i = r >> 6, j = r & 63;
        cx = (j + 0.5f) / 64.0f; cy = (i + 0.5f) / 64.0f;
    } else {
        int rr = r - 4096;
        int i = rr >> 5, j = rr & 31;
        cx = (j + 0.5f) / 32.0f; cy = (i + 0.5f) / 32.0f;
    }
    out[2 * r] = cx;
    out[2 * r + 1] = cy;
}

// ---------------- launch ----------------
extern "C" void kernel_launch(void* const* d_in, const int* in_sizes, int n_in,
                              void* d_out, int out_size, void* d_ws, size_t ws_size,
                              hipStream_t stream)
{
    const float* x  = (const float*)d_in[0];
    const float* w1 = (const float*)d_in[1];  const float* b1 = (const float*)d_in[2];
    const float* w2 = (const float*)d_in[3];  const float* b2 = (const float*)d_in[4];
    const float* w3 = (const float*)d_in[5];  const float* b3 = (const float*)d_in[6];
    const float* w4 = (const float*)d_in[7];  const float* b4 = (const float*)d_in[8];
    const float* w5 = (const float*)d_in[9];  const float* b5 = (const float*)d_in[10];
    const float* w6 = (const float*)d_in[11]; const float* b6 = (const float*)d_in[12];
    const float* w7 = (const float*)d_in[13]; const float* b7 = (const float*)d_in[14];
    const float* w8 = (const float*)d_in[15]; const float* b8 = (const float*)d_in[16];
    const float* g1 = (const float*)d_in[17]; const float* g2 = (const float*)d_in[18];
    const float* lw1 = (const float*)d_in[19]; const float* lb1 = (const float*)d_in[20];
    const float* lw2 = (const float*)d_in[21]; const float* lb2 = (const float*)d_in[22];
    const float* cw1 = (const float*)d_in[23]; const float* cb1 = (const float*)d_in[24];
    const float* cw2 = (const float*)d_in[25]; const float* cb2 = (const float*)d_in[26];
    const float* rw1 = (const float*)d_in[27]; const float* rb1 = (const float*)d_in[28];
    const float* rw2 = (const float*)d_in[29]; const float* rb2 = (const float*)d_in[30];

    f16* wsh = (f16*)d_ws;
    // fixed region (f16 units): weights [0, 2398208), then x6p
    f16* wt2  = wsh + 0;
    f16* wt3  = wsh + 36864;
    f16* wt4  = wsh + 110592;
    f16* wt5  = wsh + 258048;
    f16* wt6  = wsh + 552960;
    f16* wt7  = wsh + 1142784;
    f16* wt8  = wsh + 1732608;
    f16* wt1  = wsh + 2322432;
    f16* wth1 = wsh + 2324480;
    f16* wth2 = wsh + 2361344;
    f16* x6p  = wsh + 2398208;   // 8*66*66*256 = 8921088
    const long PI = 11319296;    // group region base

    // per-item buffer sizes (f16 units)
    const long A1S = 16908544;   // 514*514*64
    const long P1S = 4260096;    // 258*258*64
    const long A3S = 8520192;    // 258*258*128
    const long P2S = 2163200;    // 130*130*128
    const long A5S = 4326400;    // 130*130*256
    const long NAS = A1S + P1S + A3S + P2S + A5S;   // non-aliased slot: 36178432
    const long ALS = A1S + P1S;                     // aliased slot: 21168640
    const long PH2 = 18391040;   // phase-2 footprint (s1..s2)

    // layout ladder: prefer larger G; prefer non-aliased (halos hoisted out of loop)
    int G = 1; bool NA = false;
    {
        const int gs[4] = {8, 4, 2, 1};
        bool done = false;
        for (int gi = 0; gi < 4 && !done; ++gi) {
            for (int na = 1; na >= 0 && !done; --na) {
                long ext = (long)gs[gi] * (na ? NAS : ALS);
                if (ext < PH2) ext = PH2;
                if (2.0 * (double)(PI + ext) <= (double)ws_size) {
                    G = gs[gi]; NA = (na == 1); done = true;
                }
            }
        }
    }
    const int NGRP = 8 / G;

    f16* base = wsh + PI;
    f16 *a1, *p1, *a3, *p2, *a5;
    if (NA) {
        a1 = base;
        p1 = base + (long)G * A1S;
        a3 = p1 + (long)G * P1S;
        p2 = a3 + (long)G * A3S;
        a5 = p2 + (long)G * P2S;
    } else {
        a1 = base;
        p1 = base + (long)G * A1S;
        a3 = a1; p2 = p1; a5 = a1;
    }
    // phase-2 (after group loop, group region dead); p4,a7,a8,s2 are 4 contiguous
    // equal-stride [8,34,34,256] buffers -> halos zeroable as one items=32 pass
    f16* s1 = base;
    f16* p4 = base + 8921088;
    f16* a7 = base + 11288576;
    f16* a8 = base + 13656064;
    f16* s2 = base + 16023552;

    float* loc  = (float*)d_out;
    float* conf = loc + 81920;
    float* regr = loc + 204800;
    float* pri  = loc + 245760;

    // all weight conversions in one dispatch (331840 work items)
    cvt_all_k<<<dim3((331840 + 255) / 256), 256, 0, stream>>>(
        w1, w2, w3, w4, w5, w6, w7, w8, lw1, cw1, rw1, lw2, cw2, rw2, wsh);

    if (NA) {
        // non-aliased: zero every halo once; zeros persist (convs write interior only)
        halo_k<<<dim3((G * (2 * 514 + 2 * 512) * 64 + 255) / 256), 256, 0, stream>>>(a1, 512, 512, 64, A1S, G);
        halo_k<<<dim3((G * (2 * 258 + 2 * 256) * 64 + 255) / 256), 256, 0, stream>>>(p1, 256, 256, 64, P1S, G);
        halo_k<<<dim3((G * (2 * 258 + 2 * 256) * 128 + 255) / 256), 256, 0, stream>>>(a3, 256, 256, 128, A3S, G);
        halo_k<<<dim3((G * (2 * 130 + 2 * 128) * 128 + 255) / 256), 256, 0, stream>>>(p2, 128, 128, 128, P2S, G);
        halo_k<<<dim3((G * (2 * 130 + 2 * 128) * 256 + 255) / 256), 256, 0, stream>>>(a5, 128, 128, 256, A5S, G);
    }

    // conv1..conv6, G items per dispatch (r10-proven launches)
    for (int grp = 0; grp < NGRP; ++grp) {
        f16* x6g = x6p + (long)grp * G * 1115136;
        if (!NA) {
            halo_k<<<dim3((G * (2 * 514 + 2 * 512) * 64 + 255) / 256), 256, 0, stream>>>(a1, 512, 512, 64, A1S, G);
            halo_k<<<dim3((G * (2 * 258 + 2 * 256) * 64 + 255) / 256), 256, 0, stream>>>(p1, 256, 256, 64, P1S, G);
        }
        convmf1_k<<<dim3(8, 64, G), 256, 0, stream>>>(x, grp * G, wt1, b1, a1, A1S);
        convmf_k<64, 64, 64, 2, 2, 8, 2, true><<<dim3(8, 128, G), 256, 0, stream>>>(
            a1, wt2, b2, p1, 512, 512, 1, A1S, P1S);
        if (!NA)
            halo_k<<<dim3((G * (2 * 258 + 2 * 256) * 128 + 255) / 256), 256, 0, stream>>>(a3, 256, 256, 128, A3S, G);
        convmf_k<64, 128, 64, 2, 2, 8, 2, false><<<dim3(4, 64, 2 * G), 256, 0, stream>>>(
            p1, wt3, b3, a3, 256, 256, 2, P1S, A3S);
        if (!NA)
            halo_k<<<dim3((G * (2 * 130 + 2 * 128) * 128 + 255) / 256), 256, 0, stream>>>(p2, 128, 128, 128, P2S, G);
        convmf_k<128, 128, 64, 2, 2, 8, 2, true><<<dim3(4, 64, 2 * G), 256, 0, stream>>>(
            a3, wt4, b4, p2, 256, 256, 2, A3S, P2S);
        if (!NA)
            halo_k<<<dim3((G * (2 * 130 + 2 * 128) * 256 + 255) / 256), 256, 0, stream>>>(a5, 128, 128, 256, A5S, G);
        convmf_k<128, 256, 64, 2, 2, 8, 2, false><<<dim3(2, 32, 4 * G), 256, 0, stream>>>(
            p2, wt5, b5, a5, 128, 128, 4, P2S, A5S);
        convmf_k<256, 256, 64, 2, 2, 8, 2, true><<<dim3(2, 32, 4 * G), 256, 0, stream>>>(
            a5, wt6, b6, x6g, 128, 128, 4, A5S, 1115136);
    }

    // phase-2 halos: s1, then p4+a7+a8+s2 in one items=32 pass (a8's halo unused, harmless)
    halo_k<<<dim3((8 * (2 * 66 + 2 * 64) * 256 + 255) / 256), 256, 0, stream>>>(s1, 64, 64, 256, 1115136, 8);
    halo_k<<<dim3((32 * (2 * 34 + 2 * 32) * 256 + 255) / 256), 256, 0, stream>>>(p4, 32, 32, 256, 295936, 32);

    l2n_k<<<dim3((32768 + 255) / 256), 256, 0, stream>>>(x6p, g1, s1, 64, 1115136, 32768);
    mp_k<<<dim3((262144 + 255) / 256), 256, 0, stream>>>(x6p, p4);
    convmf_k<256, 256, 32, 2, 2, 4, 4, false><<<dim3(1, 8, 16), 256, 0, stream>>>(
        p4, wt7, b7, a7, 32, 32, 2, 295936, 295936);
    convmf_k<256, 256, 32, 2, 2, 4, 4, false><<<dim3(1, 8, 16), 256, 0, stream>>>(
        a7, wt8, b8, a8, 32, 32, 2, 295936, 295936);
    l2n_k<<<dim3((8192 + 255) / 256), 256, 0, stream>>>(a8, g2, s2, 32, 295936, 8192);

    headconv_k<64><<<dim3(1, 64, 8), 256, 0, stream>>>(
        s1, 1115136, wth1, lb1, cb1, rb1, loc, conf, regr, 64, 0);
    headconv_k<32><<<dim3(1, 16, 8), 256, 0, stream>>>(
        s2, 295936, wth2, lb2, cb2, rb2, loc, conf, regr, 32, 4096);
    priors_k<<<dim3(20), 256, 0, stream>>>(pri);

    (void)in_sizes; (void)n_in; (void)out_size; (void)ws_size;
}

// Round 19
// 1131.031 us; speedup vs baseline: 1.3697x; 1.0224x over previous
//
#include <hip/hip_runtime.h>

typedef _Float16 f16;
typedef _Float16 f16x8 __attribute__((ext_vector_type(8)));
typedef float f32x4 __attribute__((ext_vector_type(4)));

__device__ __forceinline__ f32x4 mfma16(f16x8 a, f16x8 b, f32x4 c) {
    return __builtin_amdgcn_mfma_f32_16x16x32_f16(a, b, c, 0, 0, 0);
}

// ---------------- main implicit-GEMM 3x3 conv, f16 MFMA (r10-proven core) ----------------
// Epilogue SELF-ZEROES the output halo (edge blocks only, own oc-slice):
// producer re-zeros inside its own dispatch -> always after aliased-region
// corruption and before the consumer. Replaces all in-loop halo_k dispatches.
template<int IC, int OC, int BX, int WY, int WO, int MT, int NT, bool POOL>
__global__ __launch_bounds__(256) void convmf_k(
    const f16* __restrict__ in, const f16* __restrict__ wt,
    const float* __restrict__ bias, f16* __restrict__ out,
    int H, int W, int ocBlocks, long inStride, long outStride)
{
    constexpr int WROWS = MT * 16 / BX;
    constexpr int BROWS = WROWS * WY;
    constexpr int SR = BROWS + 2;
    constexpr int SC = BX + 2;
    constexpr int LOG = (BX == 64) ? 6 : 5;
    constexpr int OCB = 16 * NT * WO;     // channels covered per block
    static_assert(!POOL || (BX == 64 && MT == 8), "pool path assumes BX==64, MT==8");
    __shared__ f16 lds[SR * SC * 40];

    const int tid  = threadIdx.x;
    const int lane = tid & 63;
    const int wv   = tid >> 6;
    const int wy   = wv / WO;
    const int wo   = wv % WO;
    const int lm   = lane & 15;
    const int lk   = lane >> 4;
    const int x0   = blockIdx.x * BX;
    const int y0   = blockIdx.y * BROWS;
    const int zb   = blockIdx.z;
    const int n    = zb / ocBlocks;
    const int ocbase = (zb - n * ocBlocks) * OCB;
    const int oc0  = ocbase + wo * (16 * NT);
    in  += (long)n * inStride;
    out += (long)n * outStride;

    f32x4 acc[MT][NT];
#pragma unroll
    for (int mt = 0; mt < MT; ++mt)
#pragma unroll
        for (int nt = 0; nt < NT; ++nt)
            acc[mt][nt] = (f32x4){0.f, 0.f, 0.f, 0.f};

    const int Wp = W + 2;
    for (int ic0 = 0; ic0 < IC; ic0 += 32) {
        if (ic0) __syncthreads();
        const f16* ip = in + ((long)y0 * Wp + x0) * IC + ic0;
        constexpr int TASKS = SR * SC * 4;
        for (int s = tid; s < TASKS; s += 256) {
            int r    = s / (SC * 4);
            int rem  = s - r * (SC * 4);
            int xcol = rem >> 2;
            int g    = rem & 3;
            f16x8 v = *(const f16x8*)(ip + ((long)r * Wp + xcol) * IC + g * 8);
            *(f16x8*)&lds[(r * SC + xcol) * 40 + g * 8] = v;
        }
        __syncthreads();

        for (int t = 0; t < 9; ++t) {
            int dy = t / 3, dx = t - dy * 3;
            const f16* wp = wt + ((long)t * OC + oc0) * IC + ic0 + lk * 8;
            f16x8 bfr[NT];
#pragma unroll
            for (int nt = 0; nt < NT; ++nt)
                bfr[nt] = *(const f16x8*)(wp + (nt * 16 + lm) * IC);
#pragma unroll
            for (int mt = 0; mt < MT; ++mt) {
                int pos = mt * 16 + lm;
                int xx = pos & (BX - 1);
                int yy = wy * WROWS + (pos >> LOG);
                f16x8 a = *(const f16x8*)&lds[((yy + dy) * SC + xx + dx) * 40 + lk * 8];
#pragma unroll
                for (int nt = 0; nt < NT; ++nt)
                    acc[mt][nt] = mfma16(a, bfr[nt], acc[mt][nt]);
            }
        }
    }

    f16x8 z8;
#pragma unroll
    for (int j = 0; j < 8; ++j) z8[j] = (f16)0.f;

    if constexpr (!POOL) {
#pragma unroll
        for (int nt = 0; nt < NT; ++nt) {
            int oc = oc0 + nt * 16 + lm;
            float bs = bias[oc];
#pragma unroll
            for (int mt = 0; mt < MT; ++mt) {
#pragma unroll
                for (int r = 0; r < 4; ++r) {
                    int pos = mt * 16 + lk * 4 + r;
                    int xx = pos & (BX - 1);
                    int yy = wy * WROWS + (pos >> LOG);
                    float v = fmaxf(acc[mt][nt][r] + bs, 0.f);
                    out[((long)(y0 + yy + 1) * (W + 2) + (x0 + xx + 1)) * OC + oc] = (f16)v;
                }
            }
        }
        // ---- self-zero output halo (edge blocks, own oc-slice) ----
        if (y0 == 0 || y0 + BROWS == H) {
            int c0 = (x0 == 0) ? 0 : x0 + 1;
            int c1 = (x0 + BX == W) ? (W + 1) : (x0 + BX);
            int ncol = c1 - c0 + 1;
            int total = ncol * (OCB / 8);
            for (int pass = 0; pass < 2; ++pass) {
                int row = (pass == 0) ? 0 : H + 1;
                if ((pass == 0 && y0 == 0) || (pass == 1 && y0 + BROWS == H)) {
                    for (int s = tid; s < total; s += 256) {
                        int col = c0 + s / (OCB / 8);
                        int gg = s - (col - c0) * (OCB / 8);
                        *(f16x8*)&out[((long)row * (W + 2) + col) * OC + ocbase + gg * 8] = z8;
                    }
                }
            }
        }
        if (x0 == 0 || x0 + BX == W) {
            int total = BROWS * (OCB / 8);
            for (int pass = 0; pass < 2; ++pass) {
                int col = (pass == 0) ? 0 : W + 1;
                if ((pass == 0 && x0 == 0) || (pass == 1 && x0 + BX == W)) {
                    for (int s = tid; s < total; s += 256) {
                        int row = y0 + 1 + s / (OCB / 8);
                        int gg = s - (row - y0 - 1) * (OCB / 8);
                        *(f16x8*)&out[((long)row * (W + 2) + col) * OC + ocbase + gg * 8] = z8;
                    }
                }
            }
        }
    } else {
        const int Wo = W >> 1;
        const int Ho = H >> 1;
#pragma unroll
        for (int nt = 0; nt < NT; ++nt) {
            int oc = oc0 + nt * 16 + lm;
            float bs = bias[oc];
#pragma unroll
            for (int mt = 0; mt < 4; ++mt) {
#pragma unroll
                for (int r = 0; r < 4; r += 2) {
                    float v = fmaxf(fmaxf(acc[mt][nt][r], acc[mt][nt][r + 1]),
                                    fmaxf(acc[mt + 4][nt][r], acc[mt + 4][nt][r + 1]));
                    v = fmaxf(v + bs, 0.f);
                    int pos = mt * 16 + lk * 4 + r;
                    int xo = pos >> 1;
                    out[((long)((y0 >> 1) + wy + 1) * (Wo + 2) + ((x0 >> 1) + xo + 1)) * OC + oc] = (f16)v;
                }
            }
        }
        // ---- self-zero pooled output halo ----
        const int px0 = x0 >> 1;
        const int py0 = y0 >> 1;
        if (y0 == 0 || y0 + BROWS == H) {
            int c0 = (x0 == 0) ? 0 : px0 + 1;
            int c1 = (x0 + BX == W) ? (Wo + 1) : (px0 + BX / 2);
            int ncol = c1 - c0 + 1;
            int total = ncol * (OCB / 8);
            for (int pass = 0; pass < 2; ++pass) {
                int row = (pass == 0) ? 0 : Ho + 1;
                if ((pass == 0 && y0 == 0) || (pass == 1 && y0 + BROWS == H)) {
                    for (int s = tid; s < total; s += 256) {
                        int col = c0 + s / (OCB / 8);
                        int gg = s - (col - c0) * (OCB / 8);
                        *(f16x8*)&out[((long)row * (Wo + 2) + col) * OC + ocbase + gg * 8] = z8;
                    }
                }
            }
        }
        if (x0 == 0 || x0 + BX == W) {
            constexpr int PROWS = BROWS / 2;
            int total = PROWS * (OCB / 8);
            for (int pass = 0; pass < 2; ++pass) {
                int col = (pass == 0) ? 0 : Wo + 1;
                if ((pass == 0 && x0 == 0) || (pass == 1 && x0 + BX == W)) {
                    for (int s = tid; s < total; s += 256) {
                        int row = py0 + 1 + s / (OCB / 8);
                        int gg = s - (row - py0 - 1) * (OCB / 8);
                        *(f16x8*)&out[((long)row * (Wo + 2) + col) * OC + ocbase + gg * 8] = z8;
                    }
                }
            }
        }
    }
}

// ---------------- conv1: IC=2, im2col in LDS, K padded to 32 (r5-proven) ----------------
// Self-zeroes a1's halo ([514][514][64]) on edge blocks.
__global__ __launch_bounds__(256) void convmf1_k(
    const float* __restrict__ x, int itemBase,
    const f16* __restrict__ wt1,  // [64][32] f16, k=2t+ic, zero-padded
    const float* __restrict__ bias, f16* __restrict__ out, long outStride)
{
    __shared__ f16 ldsx[10 * 66 * 2];
    __shared__ f16 ldsa[512 * 40];
    const int tid = threadIdx.x;
    const int lane = tid & 63;
    const int wv = tid >> 6;
    const int lm = lane & 15;
    const int lk = lane >> 4;
    const int x0 = blockIdx.x * 64;
    const int y0 = blockIdx.y * 8;
    const float* xb = x + (long)(itemBase + blockIdx.z) * 2 * 512 * 512;
    out += (long)blockIdx.z * outStride;

    for (int s = tid; s < 660; s += 256) {
        int r = s / 66, xc = s - r * 66;
        int gy = y0 + r - 1, gx = x0 + xc - 1;
        f16 v0 = (f16)0.f, v1 = (f16)0.f;
        if ((unsigned)gy < 512u && (unsigned)gx < 512u) {
            v0 = (f16)xb[(long)gy * 512 + gx];
            v1 = (f16)xb[262144 + (long)gy * 512 + gx];
        }
        ldsx[(r * 66 + xc) * 2]     = v0;
        ldsx[(r * 66 + xc) * 2 + 1] = v1;
    }
    __syncthreads();
    for (int s = tid; s < 2048; s += 256) {
        int pos = s >> 2, g = s & 3;
        int row = pos >> 6, col = pos & 63;
        f16x8 v;
#pragma unroll
        for (int j = 0; j < 8; ++j) {
            int k = g * 8 + j;
            f16 val = (f16)0.f;
            if (k < 18) {
                int t = k >> 1, ic = k & 1;
                int dy = t / 3, dx = t - dy * 3;
                val = ldsx[((row + dy) * 66 + col + dx) * 2 + ic];
            }
            v[j] = val;
        }
        *(f16x8*)&ldsa[pos * 40 + g * 8] = v;
    }
    __syncthreads();

    f32x4 acc[8][4];
#pragma unroll
    for (int mt = 0; mt < 8; ++mt)
#pragma unroll
        for (int nt = 0; nt < 4; ++nt)
            acc[mt][nt] = (f32x4){0.f, 0.f, 0.f, 0.f};

    f16x8 b0 = *(const f16x8*)(wt1 + (0 * 16 + lm) * 32 + lk * 8);
    f16x8 b1 = *(const f16x8*)(wt1 + (1 * 16 + lm) * 32 + lk * 8);
    f16x8 b2 = *(const f16x8*)(wt1 + (2 * 16 + lm) * 32 + lk * 8);
    f16x8 b3 = *(const f16x8*)(wt1 + (3 * 16 + lm) * 32 + lk * 8);
#pragma unroll
    for (int mt = 0; mt < 8; ++mt) {
        int pos = wv * 128 + mt * 16 + lm;
        f16x8 a = *(const f16x8*)&ldsa[pos * 40 + lk * 8];
        acc[mt][0] = mfma16(a, b0, acc[mt][0]);
        acc[mt][1] = mfma16(a, b1, acc[mt][1]);
        acc[mt][2] = mfma16(a, b2, acc[mt][2]);
        acc[mt][3] = mfma16(a, b3, acc[mt][3]);
    }
#pragma unroll
    for (int nt = 0; nt < 4; ++nt) {
        int oc = nt * 16 + lm;
        float bs = bias[oc];
#pragma unroll
        for (int mt = 0; mt < 8; ++mt) {
#pragma unroll
            for (int r = 0; r < 4; ++r) {
                int pos = wv * 128 + mt * 16 + lk * 4 + r;
                int xx = pos & 63, yy = pos >> 6;
                float v = fmaxf(acc[mt][nt][r] + bs, 0.f);
                out[((long)(y0 + yy + 1) * 514 + (x0 + xx + 1)) * 64 + oc] = (f16)v;
            }
        }
    }

    // self-zero a1 halo: rows 0/513, cols 0/513 (64 ch, all owned by this block)
    f16x8 z8;
#pragma unroll
    for (int j = 0; j < 8; ++j) z8[j] = (f16)0.f;
    if (y0 == 0 || y0 + 8 == 512) {
        int c0 = (x0 == 0) ? 0 : x0 + 1;
        int c1 = (x0 + 64 == 512) ? 513 : (x0 + 64);
        int ncol = c1 - c0 + 1;
        int total = ncol * 8;                       // 64 ch / 8
        for (int pass = 0; pass < 2; ++pass) {
            int row = (pass == 0) ? 0 : 513;
            if ((pass == 0 && y0 == 0) || (pass == 1 && y0 + 8 == 512)) {
                for (int s = tid; s < total; s += 256) {
                    int col = c0 + (s >> 3);
                    int gg = s & 7;
                    *(f16x8*)&out[((long)row * 514 + col) * 64 + gg * 8] = z8;
                }
            }
        }
    }
    if (x0 == 0 || x0 + 64 == 512) {
        int total = 8 * 8;                          // BROWS=8 x 8 groups
        for (int pass = 0; pass < 2; ++pass) {
            int col = (pass == 0) ? 0 : 513;
            if ((pass == 0 && x0 == 0) || (pass == 1 && x0 + 64 == 512)) {
                for (int s = tid; s < total; s += 256) {
                    int row = y0 + 1 + (s >> 3);
                    int gg = s & 7;
                    *(f16x8*)&out[((long)row * 514 + col) * 64 + gg * 8] = z8;
                }
            }
        }
    }
}

// ---------------- fused heads (loc+conf+regr) as one 16-oc MFMA conv ----------------
template<int BX>
__global__ __launch_bounds__(256) void headconv_k(
    const f16* __restrict__ s, long sStride, const f16* __restrict__ wth,
    const float* __restrict__ lb, const float* __restrict__ cb, const float* __restrict__ rb,
    float* __restrict__ loc, float* __restrict__ conf, float* __restrict__ regr,
    int W, int posoff)
{
    constexpr int BY = (BX == 64) ? 1 : 2;
    constexpr int SR = BY + 2, SC = BX + 2;
    constexpr int LOG = (BX == 64) ? 6 : 5;
    __shared__ f16 lds[SR * SC * 40];
    const int tid = threadIdx.x;
    const int lane = tid & 63;
    const int wv = tid >> 6;
    const int lm = lane & 15;
    const int lk = lane >> 4;
    const int y0 = blockIdx.y * BY;
    const int b = blockIdx.z;
    s += (long)b * sStride;

    f32x4 acc = (f32x4){0.f, 0.f, 0.f, 0.f};
    const int Wp = W + 2;
    for (int ic0 = 0; ic0 < 256; ic0 += 32) {
        if (ic0) __syncthreads();
        const f16* ip = s + (long)y0 * Wp * 256 + ic0;
        constexpr int TASKS = SR * SC * 4;
        for (int t = tid; t < TASKS; t += 256) {
            int r = t / (SC * 4);
            int rem = t - r * (SC * 4);
            int xcol = rem >> 2, g = rem & 3;
            f16x8 v = *(const f16x8*)(ip + ((long)r * Wp + xcol) * 256 + g * 8);
            *(f16x8*)&lds[(r * SC + xcol) * 40 + g * 8] = v;
        }
        __syncthreads();
        for (int t = 0; t < 9; ++t) {
            int dy = t / 3, dx = t - dy * 3;
            f16x8 bf = *(const f16x8*)(wth + ((long)t * 16 + lm) * 256 + ic0 + lk * 8);
            int pos = wv * 16 + lm;
            int xx = pos & (BX - 1), yy = pos >> LOG;
            f16x8 a = *(const f16x8*)&lds[((yy + dy) * SC + xx + dx) * 40 + lk * 8];
            acc = mfma16(a, bf, acc);
        }
    }
#pragma unroll
    for (int r = 0; r < 4; ++r) {
        int pos = wv * 16 + lk * 4 + r;
        int xx = pos & (BX - 1), yy = pos >> LOG;
        int P = posoff + (y0 + yy) * W + xx;
        float v = acc[r];
        if (lm < 2)       loc[((long)b * 5120 + P) * 2 + lm]       = v + lb[lm];
        else if (lm < 5)  conf[((long)b * 5120 + P) * 3 + (lm - 2)] = v + cb[lm - 2];
        else if (lm == 5) regr[(long)b * 5120 + P]                  = v + rb[0];
    }
}

// ---------------- merged weight conversions (one dispatch) ----------------
__global__ __launch_bounds__(256) void cvt_all_k(
    const float* __restrict__ w1, const float* __restrict__ w2, const float* __restrict__ w3,
    const float* __restrict__ w4, const float* __restrict__ w5, const float* __restrict__ w6,
    const float* __restrict__ w7, const float* __restrict__ w8,
    const float* __restrict__ lw1, const float* __restrict__ cw1, const float* __restrict__ rw1,
    const float* __restrict__ lw2, const float* __restrict__ cw2, const float* __restrict__ rw2,
    f16* __restrict__ wsh)
{
    int idx = blockIdx.x * 256 + threadIdx.x;
    f16* wt2  = wsh + 0;
    f16* wt3  = wsh + 36864;
    f16* wt4  = wsh + 110592;
    f16* wt5  = wsh + 258048;
    f16* wt6  = wsh + 552960;
    f16* wt7  = wsh + 1142784;
    f16* wt8  = wsh + 1732608;
    f16* wt1  = wsh + 2322432;
    f16* wth1 = wsh + 2324480;
    f16* wth2 = wsh + 2361344;

    auto cw = [](const float* w, f16* wt, int OC, int IC, int i) {
        int oc = i / IC, ic = i - oc * IC;
#pragma unroll
        for (int t = 0; t < 9; ++t)
            wt[((long)t * OC + oc) * IC + ic] = (f16)w[(long)i * 9 + t];
    };
    auto ch = [](const float* lw, const float* cwp, const float* rw, f16* wth, int i) {
        int t = i / 4096;
        int r = (i >> 8) & 15;
        int ic = i & 255;
        float v = 0.f;
        if (r < 2)       v = lw[((long)r * 256 + ic) * 9 + t];
        else if (r < 5)  v = cwp[((long)(r - 2) * 256 + ic) * 9 + t];
        else if (r == 5) v = rw[(long)ic * 9 + t];
        wth[((long)t * 16 + r) * 256 + ic] = (f16)v;
    };

    if (idx < 4096)        cw(w2, wt2, 64, 64, idx);
    else if (idx < 12288)  cw(w3, wt3, 128, 64, idx - 4096);
    else if (idx < 28672)  cw(w4, wt4, 128, 128, idx - 12288);
    else if (idx < 61440)  cw(w5, wt5, 256, 128, idx - 28672);
    else if (idx < 126976) cw(w6, wt6, 256, 256, idx - 61440);
    else if (idx < 192512) cw(w7, wt7, 256, 256, idx - 126976);
    else if (idx < 258048) cw(w8, wt8, 256, 256, idx - 192512);
    else if (idx < 258112) {
        int oc = idx - 258048;
#pragma unroll
        for (int k = 0; k < 32; ++k) {
            f16 v = (f16)0.f;
            if (k < 18) {
                int t = k >> 1, ic = k & 1;
                v = (f16)w1[((long)oc * 2 + ic) * 9 + t];
            }
            wt1[oc * 32 + k] = v;
        }
    }
    else if (idx < 294976) ch(lw1, cw1, rw1, wth1, idx - 258112);
    else if (idx < 331840) ch(lw2, cw2, rw2, wth2, idx - 294976);
}

// ---------------- small utility kernels ----------------
__global__ __launch_bounds__(256) void halo_k(f16* __restrict__ buf, int W, int H, int C,
                                              long stride, int items)
{
    int per = (2 * (W + 2) + 2 * H) * C;
    long total = (long)per * items;
    long idx = (long)blockIdx.x * 256 + threadIdx.x;
    if (idx >= total) return;
    int n = idx / per;
    int j = idx - (long)n * per;
    int c = j % C, p = j / C;
    int row, col;
    if (p < W + 2) { row = 0; col = p; }
    else if (p < 2 * (W + 2)) { row = H + 1; col = p - (W + 2); }
    else { int q = p - 2 * (W + 2); row = 1 + (q >> 1); col = (q & 1) ? (W + 1) : 0; }
    buf[(long)n * stride + ((long)row * (W + 2) + col) * C + c] = (f16)0.f;
}

__global__ __launch_bounds__(256) void l2n_k(const f16* __restrict__ in, const float* __restrict__ g,
                                             f16* __restrict__ out, int W, long stride, int total)
{
    int i = blockIdx.x * 256 + threadIdx.x;
    if (i >= total) return;
    int b = i / (W * W);
    int rem = i - b * W * W;
    int y = rem / W, x = rem - y * W;
    long off = (long)b * stride + ((long)(y + 1) * (W + 2) + x + 1) * 256;
    const f16* p = in + off;
    f16* q = out + off;
    float s = 0.f;
    for (int gg = 0; gg < 32; ++gg) {
        f16x8 v = *(const f16x8*)(p + gg * 8);
#pragma unroll
        for (int j = 0; j < 8; ++j) { float f = (float)v[j]; s = fmaf(f, f, s); }
    }
    float inv = 1.f / (sqrtf(s) + 1e-10f);
    for (int gg = 0; gg < 32; ++gg) {
        f16x8 v = *(const f16x8*)(p + gg * 8);
        f16x8 o;
#pragma unroll
        for (int j = 0; j < 8; ++j) o[j] = (f16)(g[gg * 8 + j] * ((float)v[j] * inv));
        *(f16x8*)(q + gg * 8) = o;
    }
}

__global__ __launch_bounds__(256) void mp_k(const f16* __restrict__ in, f16* __restrict__ out)
{
    int idx = blockIdx.x * 256 + threadIdx.x;
    if (idx >= 8 * 32 * 32 * 32) return;
    int gg = idx & 31;
    int xo = (idx >> 5) & 31;
    int yo = (idx >> 10) & 31;
    int b = idx >> 15;
    const f16* p = in + (long)b * 1115136 + ((long)(2 * yo + 1) * 66 + 2 * xo + 1) * 256 + gg * 8;
    f16x8 a0 = *(const f16x8*)p;
    f16x8 a1 = *(const f16x8*)(p + 256);
    f16x8 a2 = *(const f16x8*)(p + 66 * 256);
    f16x8 a3 = *(const f16x8*)(p + 66 * 256 + 256);
    f16x8 o;
#pragma unroll
    for (int j = 0; j < 8; ++j)
        o[j] = (f16)fmaxf(fmaxf((float)a0[j], (float)a1[j]), fmaxf((float)a2[j], (float)a3[j]));
    *(f16x8*)(out + (long)b * 295936 + ((long)(yo + 1) * 34 + xo + 1) * 256 + gg * 8) = o;
}

__global__ __launch_bounds__(256) void priors_k(float* __restrict__ out)
{
    int r = blockIdx.x * 256 + threadIdx.x;
    if (r >= 5120) return;
    float cx, cy;
    if (r < 4096) {
        int i = r >> 6, j = r & 63;
        cx = (j + 0.5f) / 64.0f; cy = (i + 0.5f) / 64.0f;
    } else {
        int rr = r - 4096;
        int i = rr >> 5, j = rr & 31;
        cx = (j + 0.5f) / 32.0f; cy = (i + 0.5f) / 32.0f;
    }
    out[2 * r] = cx;
    out[2 * r + 1] = cy;
}

// ---------------- launch ----------------
extern "C" void kernel_launch(void* const* d_in, const int* in_sizes, int n_in,
                              void* d_out, int out_size, void* d_ws, size_t ws_size,
                              hipStream_t stream)
{
    const float* x  = (const float*)d_in[0];
    const float* w1 = (const float*)d_in[1];  const float* b1 = (const float*)d_in[2];
    const float* w2 = (const float*)d_in[3];  const float* b2 = (const float*)d_in[4];
    const float* w3 = (const float*)d_in[5];  const float* b3 = (const float*)d_in[6];
    const float* w4 = (const float*)d_in[7];  const float* b4 = (const float*)d_in[8];
    const float* w5 = (const float*)d_in[9];  const float* b5 = (const float*)d_in[10];
    const float* w6 = (const float*)d_in[11]; const float* b6 = (const float*)d_in[12];
    const float* w7 = (const float*)d_in[13]; const float* b7 = (const float*)d_in[14];
    const float* w8 = (const float*)d_in[15]; const float* b8 = (const float*)d_in[16];
    const float* g1 = (const float*)d_in[17]; const float* g2 = (const float*)d_in[18];
    const float* lw1 = (const float*)d_in[19]; const float* lb1 = (const float*)d_in[20];
    const float* lw2 = (const float*)d_in[21]; const float* lb2 = (const float*)d_in[22];
    const float* cw1 = (const float*)d_in[23]; const float* cb1 = (const float*)d_in[24];
    const float* cw2 = (const float*)d_in[25]; const float* cb2 = (const float*)d_in[26];
    const float* rw1 = (const float*)d_in[27]; const float* rb1 = (const float*)d_in[28];
    const float* rw2 = (const float*)d_in[29]; const float* rb2 = (const float*)d_in[30];

    f16* wsh = (f16*)d_ws;
    f16* wt2  = wsh + 0;
    f16* wt3  = wsh + 36864;
    f16* wt4  = wsh + 110592;
    f16* wt5  = wsh + 258048;
    f16* wt6  = wsh + 552960;
    f16* wt7  = wsh + 1142784;
    f16* wt8  = wsh + 1732608;
    f16* wt1  = wsh + 2322432;
    f16* wth1 = wsh + 2324480;
    f16* wth2 = wsh + 2361344;
    f16* x6p  = wsh + 2398208;   // 8*66*66*256 = 8921088
    const long PI = 11319296;    // group region base

    const long A1S = 16908544;   // 514*514*64
    const long P1S = 4260096;    // 258*258*64
    const long A3S = 8520192;    // 258*258*128 (aliases a1 region)
    const long P2S = 2163200;    // 130*130*128 (aliases p1 region)
    const long A5S = 4326400;    // 130*130*256 (aliases a1 region)
    const long PH2 = 18391040;   // phase-2 footprint (s1..s2)

    int G = 1;
    for (int g = 8; g >= 1; g >>= 1) {
        long ext = (long)g * (A1S + P1S); if (ext < PH2) ext = PH2;
        if (2.0 * (double)(PI + ext) <= (double)ws_size) { G = g; break; }
    }
    const int NGRP = 8 / G;

    f16* a1 = wsh + PI;                    // G x A1S (aliased: a3, a5)
    f16* p1 = wsh + PI + (long)G * A1S;    // G x P1S (aliased: p2)
    f16* a3 = a1;
    f16* p2 = p1;
    f16* a5 = a1;
    // phase-2 (after group loop, group region dead)
    f16* s1 = wsh + PI;
    f16* p4 = wsh + PI + 8921088;
    f16* a7 = wsh + PI + 11288576;
    f16* a8 = wsh + PI + 13656064;
    f16* s2 = wsh + PI + 16023552;

    float* loc  = (float*)d_out;
    float* conf = loc + 81920;
    float* regr = loc + 204800;
    float* pri  = loc + 245760;

    cvt_all_k<<<dim3((331840 + 255) / 256), 256, 0, stream>>>(
        w1, w2, w3, w4, w5, w6, w7, w8, lw1, cw1, rw1, lw2, cw2, rw2, wsh);

    // conv1..conv6, G items per dispatch; every conv self-zeroes its output halo
    for (int grp = 0; grp < NGRP; ++grp) {
        f16* x6g = x6p + (long)grp * G * 1115136;
        convmf1_k<<<dim3(8, 64, G), 256, 0, stream>>>(x, grp * G, wt1, b1, a1, A1S);
        convmf_k<64, 64, 64, 2, 2, 8, 2, true><<<dim3(8, 128, G), 256, 0, stream>>>(
            a1, wt2, b2, p1, 512, 512, 1, A1S, P1S);
        convmf_k<64, 128, 64, 2, 2, 8, 2, false><<<dim3(4, 64, 2 * G), 256, 0, stream>>>(
            p1, wt3, b3, a3, 256, 256, 2, P1S, A3S);
        convmf_k<128, 128, 64, 2, 2, 8, 2, true><<<dim3(4, 64, 2 * G), 256, 0, stream>>>(
            a3, wt4, b4, p2, 256, 256, 2, A3S, P2S);
        convmf_k<128, 256, 64, 2, 2, 8, 2, false><<<dim3(2, 32, 4 * G), 256, 0, stream>>>(
            p2, wt5, b5, a5, 128, 128, 4, P2S, A5S);
        convmf_k<256, 256, 64, 2, 2, 8, 2, true><<<dim3(2, 32, 4 * G), 256, 0, stream>>>(
            a5, wt6, b6, x6g, 128, 128, 4, A5S, 1115136);
    }

    // phase-2 halos: s1, then p4+a7+a8+s2 as one items=32 pass (redundant zeros benign)
    halo_k<<<dim3((8 * (2 * 66 + 2 * 64) * 256 + 255) / 256), 256, 0, stream>>>(s1, 64, 64, 256, 1115136, 8);
    halo_k<<<dim3((32 * (2 * 34 + 2 * 32) * 256 + 255) / 256), 256, 0, stream>>>(p4, 32, 32, 256, 295936, 32);

    l2n_k<<<dim3((32768 + 255) / 256), 256, 0, stream>>>(x6p, g1, s1, 64, 1115136, 32768);
    mp_k<<<dim3((262144 + 255) / 256), 256, 0, stream>>>(x6p, p4);
    convmf_k<256, 256, 32, 2, 2, 4, 4, false><<<dim3(1, 8, 16), 256, 0, stream>>>(
        p4, wt7, b7, a7, 32, 32, 2, 295936, 295936);
    convmf_k<256, 256, 32, 2, 2, 4, 4, false><<<dim3(1, 8, 16), 256, 0, stream>>>(
        a7, wt8, b8, a8, 32, 32, 2, 295936, 295936);
    l2n_k<<<dim3((8192 + 255) / 256), 256, 0, stream>>>(a8, g2, s2, 32, 295936, 8192);

    headconv_k<64><<<dim3(1, 64, 8), 256, 0, stream>>>(
        s1, 1115136, wth1, lb1, cb1, rb1, loc, conf, regr, 64, 0);
    headconv_k<32><<<dim3(1, 16, 8), 256, 0, stream>>>(
        s2, 295936, wth2, lb2, cb2, rb2, loc, conf, regr, 32, 4096);
    priors_k<<<dim3(20), 256, 0, stream>>>(pri);

    (void)in_sizes; (void)n_in; (void)out_size; (void)ws_size;
}

// Round 20
// 1107.093 us; speedup vs baseline: 1.3993x; 1.0216x over previous
//
#include <hip/hip_runtime.h>

typedef _Float16 f16;
typedef _Float16 f16x8 __attribute__((ext_vector_type(8)));
typedef float f32x4 __attribute__((ext_vector_type(4)));

__device__ __forceinline__ f32x4 mfma16(f16x8 a, f16x8 b, f32x4 c) {
    return __builtin_amdgcn_mfma_f32_16x16x32_f16(a, b, c, 0, 0, 0);
}

// ---------------- main implicit-GEMM 3x3 conv, f16 MFMA (r10-proven core) ----------------
// Epilogue SELF-ZEROES the output halo (edge blocks only, own oc-slice).
template<int IC, int OC, int BX, int WY, int WO, int MT, int NT, bool POOL>
__global__ __launch_bounds__(256) void convmf_k(
    const f16* __restrict__ in, const f16* __restrict__ wt,
    const float* __restrict__ bias, f16* __restrict__ out,
    int H, int W, int ocBlocks, long inStride, long outStride)
{
    constexpr int WROWS = MT * 16 / BX;
    constexpr int BROWS = WROWS * WY;
    constexpr int SR = BROWS + 2;
    constexpr int SC = BX + 2;
    constexpr int LOG = (BX == 64) ? 6 : 5;
    constexpr int OCB = 16 * NT * WO;     // channels covered per block
    static_assert(!POOL || (BX == 64 && MT == 8), "pool path assumes BX==64, MT==8");
    __shared__ f16 lds[SR * SC * 40];

    const int tid  = threadIdx.x;
    const int lane = tid & 63;
    const int wv   = tid >> 6;
    const int wy   = wv / WO;
    const int wo   = wv % WO;
    const int lm   = lane & 15;
    const int lk   = lane >> 4;
    const int x0   = blockIdx.x * BX;
    const int y0   = blockIdx.y * BROWS;
    const int zb   = blockIdx.z;
    const int n    = zb / ocBlocks;
    const int ocbase = (zb - n * ocBlocks) * OCB;
    const int oc0  = ocbase + wo * (16 * NT);
    in  += (long)n * inStride;
    out += (long)n * outStride;

    f32x4 acc[MT][NT];
#pragma unroll
    for (int mt = 0; mt < MT; ++mt)
#pragma unroll
        for (int nt = 0; nt < NT; ++nt)
            acc[mt][nt] = (f32x4){0.f, 0.f, 0.f, 0.f};

    const int Wp = W + 2;
    for (int ic0 = 0; ic0 < IC; ic0 += 32) {
        if (ic0) __syncthreads();
        const f16* ip = in + ((long)y0 * Wp + x0) * IC + ic0;
        constexpr int TASKS = SR * SC * 4;
        for (int s = tid; s < TASKS; s += 256) {
            int r    = s / (SC * 4);
            int rem  = s - r * (SC * 4);
            int xcol = rem >> 2;
            int g    = rem & 3;
            f16x8 v = *(const f16x8*)(ip + ((long)r * Wp + xcol) * IC + g * 8);
            *(f16x8*)&lds[(r * SC + xcol) * 40 + g * 8] = v;
        }
        __syncthreads();

        for (int t = 0; t < 9; ++t) {
            int dy = t / 3, dx = t - dy * 3;
            const f16* wp = wt + ((long)t * OC + oc0) * IC + ic0 + lk * 8;
            f16x8 bfr[NT];
#pragma unroll
            for (int nt = 0; nt < NT; ++nt)
                bfr[nt] = *(const f16x8*)(wp + (nt * 16 + lm) * IC);
#pragma unroll
            for (int mt = 0; mt < MT; ++mt) {
                int pos = mt * 16 + lm;
                int xx = pos & (BX - 1);
                int yy = wy * WROWS + (pos >> LOG);
                f16x8 a = *(const f16x8*)&lds[((yy + dy) * SC + xx + dx) * 40 + lk * 8];
#pragma unroll
                for (int nt = 0; nt < NT; ++nt)
                    acc[mt][nt] = mfma16(a, bfr[nt], acc[mt][nt]);
            }
        }
    }

    f16x8 z8;
#pragma unroll
    for (int j = 0; j < 8; ++j) z8[j] = (f16)0.f;

    if constexpr (!POOL) {
#pragma unroll
        for (int nt = 0; nt < NT; ++nt) {
            int oc = oc0 + nt * 16 + lm;
            float bs = bias[oc];
#pragma unroll
            for (int mt = 0; mt < MT; ++mt) {
#pragma unroll
                for (int r = 0; r < 4; ++r) {
                    int pos = mt * 16 + lk * 4 + r;
                    int xx = pos & (BX - 1);
                    int yy = wy * WROWS + (pos >> LOG);
                    float v = fmaxf(acc[mt][nt][r] + bs, 0.f);
                    out[((long)(y0 + yy + 1) * (W + 2) + (x0 + xx + 1)) * OC + oc] = (f16)v;
                }
            }
        }
        if (y0 == 0 || y0 + BROWS == H) {
            int c0 = (x0 == 0) ? 0 : x0 + 1;
            int c1 = (x0 + BX == W) ? (W + 1) : (x0 + BX);
            int ncol = c1 - c0 + 1;
            int total = ncol * (OCB / 8);
            for (int pass = 0; pass < 2; ++pass) {
                int row = (pass == 0) ? 0 : H + 1;
                if ((pass == 0 && y0 == 0) || (pass == 1 && y0 + BROWS == H)) {
                    for (int s = tid; s < total; s += 256) {
                        int col = c0 + s / (OCB / 8);
                        int gg = s - (col - c0) * (OCB / 8);
                        *(f16x8*)&out[((long)row * (W + 2) + col) * OC + ocbase + gg * 8] = z8;
                    }
                }
            }
        }
        if (x0 == 0 || x0 + BX == W) {
            int total = BROWS * (OCB / 8);
            for (int pass = 0; pass < 2; ++pass) {
                int col = (pass == 0) ? 0 : W + 1;
                if ((pass == 0 && x0 == 0) || (pass == 1 && x0 + BX == W)) {
                    for (int s = tid; s < total; s += 256) {
                        int row = y0 + 1 + s / (OCB / 8);
                        int gg = s - (row - y0 - 1) * (OCB / 8);
                        *(f16x8*)&out[((long)row * (W + 2) + col) * OC + ocbase + gg * 8] = z8;
                    }
                }
            }
        }
    } else {
        const int Wo = W >> 1;
        const int Ho = H >> 1;
#pragma unroll
        for (int nt = 0; nt < NT; ++nt) {
            int oc = oc0 + nt * 16 + lm;
            float bs = bias[oc];
#pragma unroll
            for (int mt = 0; mt < 4; ++mt) {
#pragma unroll
                for (int r = 0; r < 4; r += 2) {
                    float v = fmaxf(fmaxf(acc[mt][nt][r], acc[mt][nt][r + 1]),
                                    fmaxf(acc[mt + 4][nt][r], acc[mt + 4][nt][r + 1]));
                    v = fmaxf(v + bs, 0.f);
                    int pos = mt * 16 + lk * 4 + r;
                    int xo = pos >> 1;
                    out[((long)((y0 >> 1) + wy + 1) * (Wo + 2) + ((x0 >> 1) + xo + 1)) * OC + oc] = (f16)v;
                }
            }
        }
        const int px0 = x0 >> 1;
        const int py0 = y0 >> 1;
        if (y0 == 0 || y0 + BROWS == H) {
            int c0 = (x0 == 0) ? 0 : px0 + 1;
            int c1 = (x0 + BX == W) ? (Wo + 1) : (px0 + BX / 2);
            int ncol = c1 - c0 + 1;
            int total = ncol * (OCB / 8);
            for (int pass = 0; pass < 2; ++pass) {
                int row = (pass == 0) ? 0 : Ho + 1;
                if ((pass == 0 && y0 == 0) || (pass == 1 && y0 + BROWS == H)) {
                    for (int s = tid; s < total; s += 256) {
                        int col = c0 + s / (OCB / 8);
                        int gg = s - (col - c0) * (OCB / 8);
                        *(f16x8*)&out[((long)row * (Wo + 2) + col) * OC + ocbase + gg * 8] = z8;
                    }
                }
            }
        }
        if (x0 == 0 || x0 + BX == W) {
            constexpr int PROWS = BROWS / 2;
            int total = PROWS * (OCB / 8);
            for (int pass = 0; pass < 2; ++pass) {
                int col = (pass == 0) ? 0 : Wo + 1;
                if ((pass == 0 && x0 == 0) || (pass == 1 && x0 + BX == W)) {
                    for (int s = tid; s < total; s += 256) {
                        int row = py0 + 1 + s / (OCB / 8);
                        int gg = s - (row - py0 - 1) * (OCB / 8);
                        *(f16x8*)&out[((long)row * (Wo + 2) + col) * OC + ocbase + gg * 8] = z8;
                    }
                }
            }
        }
    }
}

// ---------------- conv1: IC=2, im2col in LDS, K padded to 32 (r5-proven) ----------------
__global__ __launch_bounds__(256) void convmf1_k(
    const float* __restrict__ x, int itemBase,
    const f16* __restrict__ wt1,  // [64][32] f16, k=2t+ic, zero-padded
    const float* __restrict__ bias, f16* __restrict__ out, long outStride)
{
    __shared__ f16 ldsx[10 * 66 * 2];
    __shared__ f16 ldsa[512 * 40];
    const int tid = threadIdx.x;
    const int lane = tid & 63;
    const int wv = tid >> 6;
    const int lm = lane & 15;
    const int lk = lane >> 4;
    const int x0 = blockIdx.x * 64;
    const int y0 = blockIdx.y * 8;
    const float* xb = x + (long)(itemBase + blockIdx.z) * 2 * 512 * 512;
    out += (long)blockIdx.z * outStride;

    for (int s = tid; s < 660; s += 256) {
        int r = s / 66, xc = s - r * 66;
        int gy = y0 + r - 1, gx = x0 + xc - 1;
        f16 v0 = (f16)0.f, v1 = (f16)0.f;
        if ((unsigned)gy < 512u && (unsigned)gx < 512u) {
            v0 = (f16)xb[(long)gy * 512 + gx];
            v1 = (f16)xb[262144 + (long)gy * 512 + gx];
        }
        ldsx[(r * 66 + xc) * 2]     = v0;
        ldsx[(r * 66 + xc) * 2 + 1] = v1;
    }
    __syncthreads();
    for (int s = tid; s < 2048; s += 256) {
        int pos = s >> 2, g = s & 3;
        int row = pos >> 6, col = pos & 63;
        f16x8 v;
#pragma unroll
        for (int j = 0; j < 8; ++j) {
            int k = g * 8 + j;
            f16 val = (f16)0.f;
            if (k < 18) {
                int t = k >> 1, ic = k & 1;
                int dy = t / 3, dx = t - dy * 3;
                val = ldsx[((row + dy) * 66 + col + dx) * 2 + ic];
            }
            v[j] = val;
        }
        *(f16x8*)&ldsa[pos * 40 + g * 8] = v;
    }
    __syncthreads();

    f32x4 acc[8][4];
#pragma unroll
    for (int mt = 0; mt < 8; ++mt)
#pragma unroll
        for (int nt = 0; nt < 4; ++nt)
            acc[mt][nt] = (f32x4){0.f, 0.f, 0.f, 0.f};

    f16x8 b0 = *(const f16x8*)(wt1 + (0 * 16 + lm) * 32 + lk * 8);
    f16x8 b1 = *(const f16x8*)(wt1 + (1 * 16 + lm) * 32 + lk * 8);
    f16x8 b2 = *(const f16x8*)(wt1 + (2 * 16 + lm) * 32 + lk * 8);
    f16x8 b3 = *(const f16x8*)(wt1 + (3 * 16 + lm) * 32 + lk * 8);
#pragma unroll
    for (int mt = 0; mt < 8; ++mt) {
        int pos = wv * 128 + mt * 16 + lm;
        f16x8 a = *(const f16x8*)&ldsa[pos * 40 + lk * 8];
        acc[mt][0] = mfma16(a, b0, acc[mt][0]);
        acc[mt][1] = mfma16(a, b1, acc[mt][1]);
        acc[mt][2] = mfma16(a, b2, acc[mt][2]);
        acc[mt][3] = mfma16(a, b3, acc[mt][3]);
    }
#pragma unroll
    for (int nt = 0; nt < 4; ++nt) {
        int oc = nt * 16 + lm;
        float bs = bias[oc];
#pragma unroll
        for (int mt = 0; mt < 8; ++mt) {
#pragma unroll
            for (int r = 0; r < 4; ++r) {
                int pos = wv * 128 + mt * 16 + lk * 4 + r;
                int xx = pos & 63, yy = pos >> 6;
                float v = fmaxf(acc[mt][nt][r] + bs, 0.f);
                out[((long)(y0 + yy + 1) * 514 + (x0 + xx + 1)) * 64 + oc] = (f16)v;
            }
        }
    }

    f16x8 z8;
#pragma unroll
    for (int j = 0; j < 8; ++j) z8[j] = (f16)0.f;
    if (y0 == 0 || y0 + 8 == 512) {
        int c0 = (x0 == 0) ? 0 : x0 + 1;
        int c1 = (x0 + 64 == 512) ? 513 : (x0 + 64);
        int ncol = c1 - c0 + 1;
        int total = ncol * 8;
        for (int pass = 0; pass < 2; ++pass) {
            int row = (pass == 0) ? 0 : 513;
            if ((pass == 0 && y0 == 0) || (pass == 1 && y0 + 8 == 512)) {
                for (int s = tid; s < total; s += 256) {
                    int col = c0 + (s >> 3);
                    int gg = s & 7;
                    *(f16x8*)&out[((long)row * 514 + col) * 64 + gg * 8] = z8;
                }
            }
        }
    }
    if (x0 == 0 || x0 + 64 == 512) {
        int total = 8 * 8;
        for (int pass = 0; pass < 2; ++pass) {
            int col = (pass == 0) ? 0 : 513;
            if ((pass == 0 && x0 == 0) || (pass == 1 && x0 + 64 == 512)) {
                for (int s = tid; s < total; s += 256) {
                    int row = y0 + 1 + (s >> 3);
                    int gg = s & 7;
                    *(f16x8*)&out[((long)row * 514 + col) * 64 + gg * 8] = z8;
                }
            }
        }
    }
}

// ---------------- fused heads (loc+conf+regr) as one 16-oc MFMA conv ----------------
template<int BX>
__global__ __launch_bounds__(256) void headconv_k(
    const f16* __restrict__ s, long sStride, const f16* __restrict__ wth,
    const float* __restrict__ lb, const float* __restrict__ cb, const float* __restrict__ rb,
    float* __restrict__ loc, float* __restrict__ conf, float* __restrict__ regr,
    int W, int posoff)
{
    constexpr int BY = (BX == 64) ? 1 : 2;
    constexpr int SR = BY + 2, SC = BX + 2;
    constexpr int LOG = (BX == 64) ? 6 : 5;
    __shared__ f16 lds[SR * SC * 40];
    const int tid = threadIdx.x;
    const int lane = tid & 63;
    const int wv = tid >> 6;
    const int lm = lane & 15;
    const int lk = lane >> 4;
    const int y0 = blockIdx.y * BY;
    const int b = blockIdx.z;
    s += (long)b * sStride;

    f32x4 acc = (f32x4){0.f, 0.f, 0.f, 0.f};
    const int Wp = W + 2;
    for (int ic0 = 0; ic0 < 256; ic0 += 32) {
        if (ic0) __syncthreads();
        const f16* ip = s + (long)y0 * Wp * 256 + ic0;
        constexpr int TASKS = SR * SC * 4;
        for (int t = tid; t < TASKS; t += 256) {
            int r = t / (SC * 4);
            int rem = t - r * (SC * 4);
            int xcol = rem >> 2, g = rem & 3;
            f16x8 v = *(const f16x8*)(ip + ((long)r * Wp + xcol) * 256 + g * 8);
            *(f16x8*)&lds[(r * SC + xcol) * 40 + g * 8] = v;
        }
        __syncthreads();
        for (int t = 0; t < 9; ++t) {
            int dy = t / 3, dx = t - dy * 3;
            f16x8 bf = *(const f16x8*)(wth + ((long)t * 16 + lm) * 256 + ic0 + lk * 8);
            int pos = wv * 16 + lm;
            int xx = pos & (BX - 1), yy = pos >> LOG;
            f16x8 a = *(const f16x8*)&lds[((yy + dy) * SC + xx + dx) * 40 + lk * 8];
            acc = mfma16(a, bf, acc);
        }
    }
#pragma unroll
    for (int r = 0; r < 4; ++r) {
        int pos = wv * 16 + lk * 4 + r;
        int xx = pos & (BX - 1), yy = pos >> LOG;
        int P = posoff + (y0 + yy) * W + xx;
        float v = acc[r];
        if (lm < 2)       loc[((long)b * 5120 + P) * 2 + lm]       = v + lb[lm];
        else if (lm < 5)  conf[((long)b * 5120 + P) * 3 + (lm - 2)] = v + cb[lm - 2];
        else if (lm == 5) regr[(long)b * 5120 + P]                  = v + rb[0];
    }
}

// ---------------- merged weight conversions (one dispatch) ----------------
__global__ __launch_bounds__(256) void cvt_all_k(
    const float* __restrict__ w1, const float* __restrict__ w2, const float* __restrict__ w3,
    const float* __restrict__ w4, const float* __restrict__ w5, const float* __restrict__ w6,
    const float* __restrict__ w7, const float* __restrict__ w8,
    const float* __restrict__ lw1, const float* __restrict__ cw1, const float* __restrict__ rw1,
    const float* __restrict__ lw2, const float* __restrict__ cw2, const float* __restrict__ rw2,
    f16* __restrict__ wsh)
{
    int idx = blockIdx.x * 256 + threadIdx.x;
    f16* wt2  = wsh + 0;
    f16* wt3  = wsh + 36864;
    f16* wt4  = wsh + 110592;
    f16* wt5  = wsh + 258048;
    f16* wt6  = wsh + 552960;
    f16* wt7  = wsh + 1142784;
    f16* wt8  = wsh + 1732608;
    f16* wt1  = wsh + 2322432;
    f16* wth1 = wsh + 2324480;
    f16* wth2 = wsh + 2361344;

    auto cw = [](const float* w, f16* wt, int OC, int IC, int i) {
        int oc = i / IC, ic = i - oc * IC;
#pragma unroll
        for (int t = 0; t < 9; ++t)
            wt[((long)t * OC + oc) * IC + ic] = (f16)w[(long)i * 9 + t];
    };
    auto ch = [](const float* lw, const float* cwp, const float* rw, f16* wth, int i) {
        int t = i / 4096;
        int r = (i >> 8) & 15;
        int ic = i & 255;
        float v = 0.f;
        if (r < 2)       v = lw[((long)r * 256 + ic) * 9 + t];
        else if (r < 5)  v = cwp[((long)(r - 2) * 256 + ic) * 9 + t];
        else if (r == 5) v = rw[(long)ic * 9 + t];
        wth[((long)t * 16 + r) * 256 + ic] = (f16)v;
    };

    if (idx < 4096)        cw(w2, wt2, 64, 64, idx);
    else if (idx < 12288)  cw(w3, wt3, 128, 64, idx - 4096);
    else if (idx < 28672)  cw(w4, wt4, 128, 128, idx - 12288);
    else if (idx < 61440)  cw(w5, wt5, 256, 128, idx - 28672);
    else if (idx < 126976) cw(w6, wt6, 256, 256, idx - 61440);
    else if (idx < 192512) cw(w7, wt7, 256, 256, idx - 126976);
    else if (idx < 258048) cw(w8, wt8, 256, 256, idx - 192512);
    else if (idx < 258112) {
        int oc = idx - 258048;
#pragma unroll
        for (int k = 0; k < 32; ++k) {
            f16 v = (f16)0.f;
            if (k < 18) {
                int t = k >> 1, ic = k & 1;
                v = (f16)w1[((long)oc * 2 + ic) * 9 + t];
            }
            wt1[oc * 32 + k] = v;
        }
    }
    else if (idx < 294976) ch(lw1, cw1, rw1, wth1, idx - 258112);
    else if (idx < 331840) ch(lw2, cw2, rw2, wth2, idx - 294976);
}

// ---------------- small utility kernels ----------------
__global__ __launch_bounds__(256) void halo_k(f16* __restrict__ buf, int W, int H, int C,
                                              long stride, int items)
{
    int per = (2 * (W + 2) + 2 * H) * C;
    long total = (long)per * items;
    long idx = (long)blockIdx.x * 256 + threadIdx.x;
    if (idx >= total) return;
    int n = idx / per;
    int j = idx - (long)n * per;
    int c = j % C, p = j / C;
    int row, col;
    if (p < W + 2) { row = 0; col = p; }
    else if (p < 2 * (W + 2)) { row = H + 1; col = p - (W + 2); }
    else { int q = p - 2 * (W + 2); row = 1 + (q >> 1); col = (q & 1) ? (W + 1) : 0; }
    buf[(long)n * stride + ((long)row * (W + 2) + col) * C + c] = (f16)0.f;
}

__global__ __launch_bounds__(256) void l2n_k(const f16* __restrict__ in, const float* __restrict__ g,
                                             f16* __restrict__ out, int W, long stride, int total)
{
    int i = blockIdx.x * 256 + threadIdx.x;
    if (i >= total) return;
    int b = i / (W * W);
    int rem = i - b * W * W;
    int y = rem / W, x = rem - y * W;
    long off = (long)b * stride + ((long)(y + 1) * (W + 2) + x + 1) * 256;
    const f16* p = in + off;
    f16* q = out + off;
    float s = 0.f;
    for (int gg = 0; gg < 32; ++gg) {
        f16x8 v = *(const f16x8*)(p + gg * 8);
#pragma unroll
        for (int j = 0; j < 8; ++j) { float f = (float)v[j]; s = fmaf(f, f, s); }
    }
    float inv = 1.f / (sqrtf(s) + 1e-10f);
    for (int gg = 0; gg < 32; ++gg) {
        f16x8 v = *(const f16x8*)(p + gg * 8);
        f16x8 o;
#pragma unroll
        for (int j = 0; j < 8; ++j) o[j] = (f16)(g[gg * 8 + j] * ((float)v[j] * inv));
        *(f16x8*)(q + gg * 8) = o;
    }
}

__global__ __launch_bounds__(256) void mp_k(const f16* __restrict__ in, f16* __restrict__ out)
{
    int idx = blockIdx.x * 256 + threadIdx.x;
    if (idx >= 8 * 32 * 32 * 32) return;
    int gg = idx & 31;
    int xo = (idx >> 5) & 31;
    int yo = (idx >> 10) & 31;
    int b = idx >> 15;
    const f16* p = in + (long)b * 1115136 + ((long)(2 * yo + 1) * 66 + 2 * xo + 1) * 256 + gg * 8;
    f16x8 a0 = *(const f16x8*)p;
    f16x8 a1 = *(const f16x8*)(p + 256);
    f16x8 a2 = *(const f16x8*)(p + 66 * 256);
    f16x8 a3 = *(const f16x8*)(p + 66 * 256 + 256);
    f16x8 o;
#pragma unroll
    for (int j = 0; j < 8; ++j)
        o[j] = (f16)fmaxf(fmaxf((float)a0[j], (float)a1[j]), fmaxf((float)a2[j], (float)a3[j]));
    *(f16x8*)(out + (long)b * 295936 + ((long)(yo + 1) * 34 + xo + 1) * 256 + gg * 8) = o;
}

__global__ __launch_bounds__(256) void priors_k(float* __restrict__ out)
{
    int r = blockIdx.x * 256 + threadIdx.x;
    if (r >= 5120) return;
    float cx, cy;
    if (r < 4096) {
        int i = r >> 6, j = r & 63;
        cx = (j + 0.5f) / 64.0f; cy = (i + 0.5f) / 64.0f;
    } else {
        int rr = r - 4096;
        int i = rr >> 5, j = rr & 31;
        cx = (j + 0.5f) / 32.0f; cy = (i + 0.5f) / 32.0f;
    }
    out[2 * r] = cx;
    out[2 * r + 1] = cy;
}

// ---------------- launch ----------------
extern "C" void kernel_launch(void* const* d_in, const int* in_sizes, int n_in,
                              void* d_out, int out_size, void* d_ws, size_t ws_size,
                              hipStream_t stream)
{
    const float* x  = (const float*)d_in[0];
    const float* w1 = (const float*)d_in[1];  const float* b1 = (const float*)d_in[2];
    const float* w2 = (const float*)d_in[3];  const float* b2 = (const float*)d_in[4];
    const float* w3 = (const float*)d_in[5];  const float* b3 = (const float*)d_in[6];
    const float* w4 = (const float*)d_in[7];  const float* b4 = (const float*)d_in[8];
    const float* w5 = (const float*)d_in[9];  const float* b5 = (const float*)d_in[10];
    const float* w6 = (const float*)d_in[11]; const float* b6 = (const float*)d_in[12];
    const float* w7 = (const float*)d_in[13]; const float* b7 = (const float*)d_in[14];
    const float* w8 = (const float*)d_in[15]; const float* b8 = (const float*)d_in[16];
    const float* g1 = (const float*)d_in[17]; const float* g2 = (const float*)d_in[18];
    const float* lw1 = (const float*)d_in[19]; const float* lb1 = (const float*)d_in[20];
    const float* lw2 = (const float*)d_in[21]; const float* lb2 = (const float*)d_in[22];
    const float* cw1 = (const float*)d_in[23]; const float* cb1 = (const float*)d_in[24];
    const float* cw2 = (const float*)d_in[25]; const float* cb2 = (const float*)d_in[26];
    const float* rw1 = (const float*)d_in[27]; const float* rb1 = (const float*)d_in[28];
    const float* rw2 = (const float*)d_in[29]; const float* rb2 = (const float*)d_in[30];

    f16* wsh = (f16*)d_ws;
    f16* wt2  = wsh + 0;
    f16* wt3  = wsh + 36864;
    f16* wt4  = wsh + 110592;
    f16* wt5  = wsh + 258048;
    f16* wt6  = wsh + 552960;
    f16* wt7  = wsh + 1142784;
    f16* wt8  = wsh + 1732608;
    f16* wt1  = wsh + 2322432;
    f16* wth1 = wsh + 2324480;
    f16* wth2 = wsh + 2361344;
    f16* x6p  = wsh + 2398208;   // 8*66*66*256 = 8921088
    const long PI = 11319296;    // group region base

    const long A1S = 16908544;   // 514*514*64
    const long P1S = 4260096;    // 258*258*64
    const long A3S = 8520192;    // 258*258*128 (aliases a1 region)
    const long P2S = 2163200;    // 130*130*128 (aliases p1 region)
    const long A5S = 4326400;    // 130*130*256 (aliases a1 region)
    const long PH2 = 18391040;   // phase-2 footprint (s1..s2)

    int G = 1;
    for (int g = 8; g >= 1; g >>= 1) {
        long ext = (long)g * (A1S + P1S); if (ext < PH2) ext = PH2;
        if (2.0 * (double)(PI + ext) <= (double)ws_size) { G = g; break; }
    }
    const int NGRP = 8 / G;

    f16* a1 = wsh + PI;                    // G x A1S (aliased: a3, a5)
    f16* p1 = wsh + PI + (long)G * A1S;    // G x P1S (aliased: p2)
    f16* a3 = a1;
    f16* p2 = p1;
    f16* a5 = a1;
    // phase-2 (after group loop, group region dead)
    f16* s1 = wsh + PI;
    f16* p4 = wsh + PI + 8921088;
    f16* a7 = wsh + PI + 11288576;
    f16* a8 = wsh + PI + 13656064;
    f16* s2 = wsh + PI + 16023552;

    float* loc  = (float*)d_out;
    float* conf = loc + 81920;
    float* regr = loc + 204800;
    float* pri  = loc + 245760;

    cvt_all_k<<<dim3((331840 + 255) / 256), 256, 0, stream>>>(
        w1, w2, w3, w4, w5, w6, w7, w8, lw1, cw1, rw1, lw2, cw2, rw2, wsh);

    // conv1..conv6, G items per dispatch; every conv self-zeroes its output halo
    for (int grp = 0; grp < NGRP; ++grp) {
        f16* x6g = x6p + (long)grp * G * 1115136;
        convmf1_k<<<dim3(8, 64, G), 256, 0, stream>>>(x, grp * G, wt1, b1, a1, A1S);
        convmf_k<64, 64, 64, 2, 2, 8, 2, true><<<dim3(8, 128, G), 256, 0, stream>>>(
            a1, wt2, b2, p1, 512, 512, 1, A1S, P1S);
        convmf_k<64, 128, 64, 2, 2, 8, 2, false><<<dim3(4, 64, 2 * G), 256, 0, stream>>>(
            p1, wt3, b3, a3, 256, 256, 2, P1S, A3S);
        convmf_k<128, 128, 64, 2, 2, 8, 2, true><<<dim3(4, 64, 2 * G), 256, 0, stream>>>(
            a3, wt4, b4, p2, 256, 256, 2, A3S, P2S);
        convmf_k<128, 256, 64, 2, 2, 8, 2, false><<<dim3(2, 32, 4 * G), 256, 0, stream>>>(
            p2, wt5, b5, a5, 128, 128, 4, P2S, A5S);
        convmf_k<256, 256, 64, 2, 2, 8, 2, true><<<dim3(2, 32, 4 * G), 256, 0, stream>>>(
            a5, wt6, b6, x6g, 128, 128, 4, A5S, 1115136);
    }

    // phase-2 halos: s1, then p4+a7+a8+s2 as one items=32 pass (redundant zeros benign)
    halo_k<<<dim3((8 * (2 * 66 + 2 * 64) * 256 + 255) / 256), 256, 0, stream>>>(s1, 64, 64, 256, 1115136, 8);
    halo_k<<<dim3((32 * (2 * 34 + 2 * 32) * 256 + 255) / 256), 256, 0, stream>>>(p4, 32, 32, 256, 295936, 32);

    l2n_k<<<dim3((32768 + 255) / 256), 256, 0, stream>>>(x6p, g1, s1, 64, 1115136, 32768);
    mp_k<<<dim3((262144 + 255) / 256), 256, 0, stream>>>(x6p, p4);
    // conv7/8: NT=2, ocBlocks=4 -> 256 blocks (2x parallelism vs NT=4/ocBlocks=2)
    convmf_k<256, 256, 32, 2, 2, 4, 2, false><<<dim3(1, 8, 32), 256, 0, stream>>>(
        p4, wt7, b7, a7, 32, 32, 4, 295936, 295936);
    convmf_k<256, 256, 32, 2, 2, 4, 2, false><<<dim3(1, 8, 32), 256, 0, stream>>>(
        a7, wt8, b8, a8, 32, 32, 4, 295936, 295936);
    l2n_k<<<dim3((8192 + 255) / 256), 256, 0, stream>>>(a8, g2, s2, 32, 295936, 8192);

    headconv_k<64><<<dim3(1, 64, 8), 256, 0, stream>>>(
        s1, 1115136, wth1, lb1, cb1, rb1, loc, conf, regr, 64, 0);
    headconv_k<32><<<dim3(1, 16, 8), 256, 0, stream>>>(
        s2, 295936, wth2, lb2, cb2, rb2, loc, conf, regr, 32, 4096);
    priors_k<<<dim3(20), 256, 0, stream>>>(pri);

    (void)in_sizes; (void)n_in; (void)out_size; (void)ws_size;
}

// Round 21
// 1098.481 us; speedup vs baseline: 1.4103x; 1.0078x over previous
//
#include <hip/hip_runtime.h>

typedef _Float16 f16;
typedef _Float16 f16x8 __attribute__((ext_vector_type(8)));
typedef float f32x4 __attribute__((ext_vector_type(4)));

__device__ __forceinline__ f32x4 mfma16(f16x8 a, f16x8 b, f32x4 c) {
    return __builtin_amdgcn_mfma_f32_16x16x32_f16(a, b, c, 0, 0, 0);
}

// ---------------- main implicit-GEMM 3x3 conv, f16 MFMA (r10-proven core) ----------------
// Epilogue SELF-ZEROES the output halo (edge blocks only, own oc-slice).
template<int IC, int OC, int BX, int WY, int WO, int MT, int NT, bool POOL>
__global__ __launch_bounds__(256) void convmf_k(
    const f16* __restrict__ in, const f16* __restrict__ wt,
    const float* __restrict__ bias, f16* __restrict__ out,
    int H, int W, int ocBlocks, long inStride, long outStride)
{
    constexpr int WROWS = MT * 16 / BX;
    constexpr int BROWS = WROWS * WY;
    constexpr int SR = BROWS + 2;
    constexpr int SC = BX + 2;
    constexpr int LOG = (BX == 64) ? 6 : 5;
    constexpr int OCB = 16 * NT * WO;     // channels covered per block
    static_assert(!POOL || (BX == 64 && MT == 8), "pool path assumes BX==64, MT==8");
    __shared__ f16 lds[SR * SC * 40];

    const int tid  = threadIdx.x;
    const int lane = tid & 63;
    const int wv   = tid >> 6;
    const int wy   = wv / WO;
    const int wo   = wv % WO;
    const int lm   = lane & 15;
    const int lk   = lane >> 4;
    const int x0   = blockIdx.x * BX;
    const int y0   = blockIdx.y * BROWS;
    const int zb   = blockIdx.z;
    const int n    = zb / ocBlocks;
    const int ocbase = (zb - n * ocBlocks) * OCB;
    const int oc0  = ocbase + wo * (16 * NT);
    in  += (long)n * inStride;
    out += (long)n * outStride;

    f32x4 acc[MT][NT];
#pragma unroll
    for (int mt = 0; mt < MT; ++mt)
#pragma unroll
        for (int nt = 0; nt < NT; ++nt)
            acc[mt][nt] = (f32x4){0.f, 0.f, 0.f, 0.f};

    const int Wp = W + 2;
    for (int ic0 = 0; ic0 < IC; ic0 += 32) {
        if (ic0) __syncthreads();
        const f16* ip = in + ((long)y0 * Wp + x0) * IC + ic0;
        constexpr int TASKS = SR * SC * 4;
        for (int s = tid; s < TASKS; s += 256) {
            int r    = s / (SC * 4);
            int rem  = s - r * (SC * 4);
            int xcol = rem >> 2;
            int g    = rem & 3;
            f16x8 v = *(const f16x8*)(ip + ((long)r * Wp + xcol) * IC + g * 8);
            *(f16x8*)&lds[(r * SC + xcol) * 40 + g * 8] = v;
        }
        __syncthreads();

        for (int t = 0; t < 9; ++t) {
            int dy = t / 3, dx = t - dy * 3;
            const f16* wp = wt + ((long)t * OC + oc0) * IC + ic0 + lk * 8;
            f16x8 bfr[NT];
#pragma unroll
            for (int nt = 0; nt < NT; ++nt)
                bfr[nt] = *(const f16x8*)(wp + (nt * 16 + lm) * IC);
#pragma unroll
            for (int mt = 0; mt < MT; ++mt) {
                int pos = mt * 16 + lm;
                int xx = pos & (BX - 1);
                int yy = wy * WROWS + (pos >> LOG);
                f16x8 a = *(const f16x8*)&lds[((yy + dy) * SC + xx + dx) * 40 + lk * 8];
#pragma unroll
                for (int nt = 0; nt < NT; ++nt)
                    acc[mt][nt] = mfma16(a, bfr[nt], acc[mt][nt]);
            }
        }
    }

    f16x8 z8;
#pragma unroll
    for (int j = 0; j < 8; ++j) z8[j] = (f16)0.f;

    if constexpr (!POOL) {
#pragma unroll
        for (int nt = 0; nt < NT; ++nt) {
            int oc = oc0 + nt * 16 + lm;
            float bs = bias[oc];
#pragma unroll
            for (int mt = 0; mt < MT; ++mt) {
#pragma unroll
                for (int r = 0; r < 4; ++r) {
                    int pos = mt * 16 + lk * 4 + r;
                    int xx = pos & (BX - 1);
                    int yy = wy * WROWS + (pos >> LOG);
                    float v = fmaxf(acc[mt][nt][r] + bs, 0.f);
                    out[((long)(y0 + yy + 1) * (W + 2) + (x0 + xx + 1)) * OC + oc] = (f16)v;
                }
            }
        }
        if (y0 == 0 || y0 + BROWS == H) {
            int c0 = (x0 == 0) ? 0 : x0 + 1;
            int c1 = (x0 + BX == W) ? (W + 1) : (x0 + BX);
            int ncol = c1 - c0 + 1;
            int total = ncol * (OCB / 8);
            for (int pass = 0; pass < 2; ++pass) {
                int row = (pass == 0) ? 0 : H + 1;
                if ((pass == 0 && y0 == 0) || (pass == 1 && y0 + BROWS == H)) {
                    for (int s = tid; s < total; s += 256) {
                        int col = c0 + s / (OCB / 8);
                        int gg = s - (col - c0) * (OCB / 8);
                        *(f16x8*)&out[((long)row * (W + 2) + col) * OC + ocbase + gg * 8] = z8;
                    }
                }
            }
        }
        if (x0 == 0 || x0 + BX == W) {
            int total = BROWS * (OCB / 8);
            for (int pass = 0; pass < 2; ++pass) {
                int col = (pass == 0) ? 0 : W + 1;
                if ((pass == 0 && x0 == 0) || (pass == 1 && x0 + BX == W)) {
                    for (int s = tid; s < total; s += 256) {
                        int row = y0 + 1 + s / (OCB / 8);
                        int gg = s - (row - y0 - 1) * (OCB / 8);
                        *(f16x8*)&out[((long)row * (W + 2) + col) * OC + ocbase + gg * 8] = z8;
                    }
                }
            }
        }
    } else {
        const int Wo = W >> 1;
        const int Ho = H >> 1;
#pragma unroll
        for (int nt = 0; nt < NT; ++nt) {
            int oc = oc0 + nt * 16 + lm;
            float bs = bias[oc];
#pragma unroll
            for (int mt = 0; mt < 4; ++mt) {
#pragma unroll
                for (int r = 0; r < 4; r += 2) {
                    float v = fmaxf(fmaxf(acc[mt][nt][r], acc[mt][nt][r + 1]),
                                    fmaxf(acc[mt + 4][nt][r], acc[mt + 4][nt][r + 1]));
                    v = fmaxf(v + bs, 0.f);
                    int pos = mt * 16 + lk * 4 + r;
                    int xo = pos >> 1;
                    out[((long)((y0 >> 1) + wy + 1) * (Wo + 2) + ((x0 >> 1) + xo + 1)) * OC + oc] = (f16)v;
                }
            }
        }
        const int px0 = x0 >> 1;
        const int py0 = y0 >> 1;
        if (y0 == 0 || y0 + BROWS == H) {
            int c0 = (x0 == 0) ? 0 : px0 + 1;
            int c1 = (x0 + BX == W) ? (Wo + 1) : (px0 + BX / 2);
            int ncol = c1 - c0 + 1;
            int total = ncol * (OCB / 8);
            for (int pass = 0; pass < 2; ++pass) {
                int row = (pass == 0) ? 0 : Ho + 1;
                if ((pass == 0 && y0 == 0) || (pass == 1 && y0 + BROWS == H)) {
                    for (int s = tid; s < total; s += 256) {
                        int col = c0 + s / (OCB / 8);
                        int gg = s - (col - c0) * (OCB / 8);
                        *(f16x8*)&out[((long)row * (Wo + 2) + col) * OC + ocbase + gg * 8] = z8;
                    }
                }
            }
        }
        if (x0 == 0 || x0 + BX == W) {
            constexpr int PROWS = BROWS / 2;
            int total = PROWS * (OCB / 8);
            for (int pass = 0; pass < 2; ++pass) {
                int col = (pass == 0) ? 0 : Wo + 1;
                if ((pass == 0 && x0 == 0) || (pass == 1 && x0 + BX == W)) {
                    for (int s = tid; s < total; s += 256) {
                        int row = py0 + 1 + s / (OCB / 8);
                        int gg = s - (row - py0 - 1) * (OCB / 8);
                        *(f16x8*)&out[((long)row * (Wo + 2) + col) * OC + ocbase + gg * 8] = z8;
                    }
                }
            }
        }
    }
}

// ---------------- conv1: IC=2, im2col in LDS, K padded to 32 (r5-proven) ----------------
__global__ __launch_bounds__(256) void convmf1_k(
    const float* __restrict__ x, int itemBase,
    const f16* __restrict__ wt1,  // [64][32] f16, k=2t+ic, zero-padded
    const float* __restrict__ bias, f16* __restrict__ out, long outStride)
{
    __shared__ f16 ldsx[10 * 66 * 2];
    __shared__ f16 ldsa[512 * 40];
    const int tid = threadIdx.x;
    const int lane = tid & 63;
    const int wv = tid >> 6;
    const int lm = lane & 15;
    const int lk = lane >> 4;
    const int x0 = blockIdx.x * 64;
    const int y0 = blockIdx.y * 8;
    const float* xb = x + (long)(itemBase + blockIdx.z) * 2 * 512 * 512;
    out += (long)blockIdx.z * outStride;

    for (int s = tid; s < 660; s += 256) {
        int r = s / 66, xc = s - r * 66;
        int gy = y0 + r - 1, gx = x0 + xc - 1;
        f16 v0 = (f16)0.f, v1 = (f16)0.f;
        if ((unsigned)gy < 512u && (unsigned)gx < 512u) {
            v0 = (f16)xb[(long)gy * 512 + gx];
            v1 = (f16)xb[262144 + (long)gy * 512 + gx];
        }
        ldsx[(r * 66 + xc) * 2]     = v0;
        ldsx[(r * 66 + xc) * 2 + 1] = v1;
    }
    __syncthreads();
    for (int s = tid; s < 2048; s += 256) {
        int pos = s >> 2, g = s & 3;
        int row = pos >> 6, col = pos & 63;
        f16x8 v;
#pragma unroll
        for (int j = 0; j < 8; ++j) {
            int k = g * 8 + j;
            f16 val = (f16)0.f;
            if (k < 18) {
                int t = k >> 1, ic = k & 1;
                int dy = t / 3, dx = t - dy * 3;
                val = ldsx[((row + dy) * 66 + col + dx) * 2 + ic];
            }
            v[j] = val;
        }
        *(f16x8*)&ldsa[pos * 40 + g * 8] = v;
    }
    __syncthreads();

    f32x4 acc[8][4];
#pragma unroll
    for (int mt = 0; mt < 8; ++mt)
#pragma unroll
        for (int nt = 0; nt < 4; ++nt)
            acc[mt][nt] = (f32x4){0.f, 0.f, 0.f, 0.f};

    f16x8 b0 = *(const f16x8*)(wt1 + (0 * 16 + lm) * 32 + lk * 8);
    f16x8 b1 = *(const f16x8*)(wt1 + (1 * 16 + lm) * 32 + lk * 8);
    f16x8 b2 = *(const f16x8*)(wt1 + (2 * 16 + lm) * 32 + lk * 8);
    f16x8 b3 = *(const f16x8*)(wt1 + (3 * 16 + lm) * 32 + lk * 8);
#pragma unroll
    for (int mt = 0; mt < 8; ++mt) {
        int pos = wv * 128 + mt * 16 + lm;
        f16x8 a = *(const f16x8*)&ldsa[pos * 40 + lk * 8];
        acc[mt][0] = mfma16(a, b0, acc[mt][0]);
        acc[mt][1] = mfma16(a, b1, acc[mt][1]);
        acc[mt][2] = mfma16(a, b2, acc[mt][2]);
        acc[mt][3] = mfma16(a, b3, acc[mt][3]);
    }
#pragma unroll
    for (int nt = 0; nt < 4; ++nt) {
        int oc = nt * 16 + lm;
        float bs = bias[oc];
#pragma unroll
        for (int mt = 0; mt < 8; ++mt) {
#pragma unroll
            for (int r = 0; r < 4; ++r) {
                int pos = wv * 128 + mt * 16 + lk * 4 + r;
                int xx = pos & 63, yy = pos >> 6;
                float v = fmaxf(acc[mt][nt][r] + bs, 0.f);
                out[((long)(y0 + yy + 1) * 514 + (x0 + xx + 1)) * 64 + oc] = (f16)v;
            }
        }
    }

    f16x8 z8;
#pragma unroll
    for (int j = 0; j < 8; ++j) z8[j] = (f16)0.f;
    if (y0 == 0 || y0 + 8 == 512) {
        int c0 = (x0 == 0) ? 0 : x0 + 1;
        int c1 = (x0 + 64 == 512) ? 513 : (x0 + 64);
        int ncol = c1 - c0 + 1;
        int total = ncol * 8;
        for (int pass = 0; pass < 2; ++pass) {
            int row = (pass == 0) ? 0 : 513;
            if ((pass == 0 && y0 == 0) || (pass == 1 && y0 + 8 == 512)) {
                for (int s = tid; s < total; s += 256) {
                    int col = c0 + (s >> 3);
                    int gg = s & 7;
                    *(f16x8*)&out[((long)row * 514 + col) * 64 + gg * 8] = z8;
                }
            }
        }
    }
    if (x0 == 0 || x0 + 64 == 512) {
        int total = 8 * 8;
        for (int pass = 0; pass < 2; ++pass) {
            int col = (pass == 0) ? 0 : 513;
            if ((pass == 0 && x0 == 0) || (pass == 1 && x0 + 64 == 512)) {
                for (int s = tid; s < total; s += 256) {
                    int row = y0 + 1 + (s >> 3);
                    int gg = s & 7;
                    *(f16x8*)&out[((long)row * 514 + col) * 64 + gg * 8] = z8;
                }
            }
        }
    }
}

// ---------------- fused heads (loc+conf+regr) as one 16-oc MFMA conv ----------------
template<int BX>
__global__ __launch_bounds__(256) void headconv_k(
    const f16* __restrict__ s, long sStride, const f16* __restrict__ wth,
    const float* __restrict__ lb, const float* __restrict__ cb, const float* __restrict__ rb,
    float* __restrict__ loc, float* __restrict__ conf, float* __restrict__ regr,
    int W, int posoff)
{
    constexpr int BY = (BX == 64) ? 1 : 2;
    constexpr int SR = BY + 2, SC = BX + 2;
    constexpr int LOG = (BX == 64) ? 6 : 5;
    __shared__ f16 lds[SR * SC * 40];
    const int tid = threadIdx.x;
    const int lane = tid & 63;
    const int wv = tid >> 6;
    const int lm = lane & 15;
    const int lk = lane >> 4;
    const int y0 = blockIdx.y * BY;
    const int b = blockIdx.z;
    s += (long)b * sStride;

    f32x4 acc = (f32x4){0.f, 0.f, 0.f, 0.f};
    const int Wp = W + 2;
    for (int ic0 = 0; ic0 < 256; ic0 += 32) {
        if (ic0) __syncthreads();
        const f16* ip = s + (long)y0 * Wp * 256 + ic0;
        constexpr int TASKS = SR * SC * 4;
        for (int t = tid; t < TASKS; t += 256) {
            int r = t / (SC * 4);
            int rem = t - r * (SC * 4);
            int xcol = rem >> 2, g = rem & 3;
            f16x8 v = *(const f16x8*)(ip + ((long)r * Wp + xcol) * 256 + g * 8);
            *(f16x8*)&lds[(r * SC + xcol) * 40 + g * 8] = v;
        }
        __syncthreads();
        for (int t = 0; t < 9; ++t) {
            int dy = t / 3, dx = t - dy * 3;
            f16x8 bf = *(const f16x8*)(wth + ((long)t * 16 + lm) * 256 + ic0 + lk * 8);
            int pos = wv * 16 + lm;
            int xx = pos & (BX - 1), yy = pos >> LOG;
            f16x8 a = *(const f16x8*)&lds[((yy + dy) * SC + xx + dx) * 40 + lk * 8];
            acc = mfma16(a, bf, acc);
        }
    }
#pragma unroll
    for (int r = 0; r < 4; ++r) {
        int pos = wv * 16 + lk * 4 + r;
        int xx = pos & (BX - 1), yy = pos >> LOG;
        int P = posoff + (y0 + yy) * W + xx;
        float v = acc[r];
        if (lm < 2)       loc[((long)b * 5120 + P) * 2 + lm]       = v + lb[lm];
        else if (lm < 5)  conf[((long)b * 5120 + P) * 3 + (lm - 2)] = v + cb[lm - 2];
        else if (lm == 5) regr[(long)b * 5120 + P]                  = v + rb[0];
    }
}

// ---------------- merged weight conversions (one dispatch) ----------------
__global__ __launch_bounds__(256) void cvt_all_k(
    const float* __restrict__ w1, const float* __restrict__ w2, const float* __restrict__ w3,
    const float* __restrict__ w4, const float* __restrict__ w5, const float* __restrict__ w6,
    const float* __restrict__ w7, const float* __restrict__ w8,
    const float* __restrict__ lw1, const float* __restrict__ cw1, const float* __restrict__ rw1,
    const float* __restrict__ lw2, const float* __restrict__ cw2, const float* __restrict__ rw2,
    f16* __restrict__ wsh)
{
    int idx = blockIdx.x * 256 + threadIdx.x;
    f16* wt2  = wsh + 0;
    f16* wt3  = wsh + 36864;
    f16* wt4  = wsh + 110592;
    f16* wt5  = wsh + 258048;
    f16* wt6  = wsh + 552960;
    f16* wt7  = wsh + 1142784;
    f16* wt8  = wsh + 1732608;
    f16* wt1  = wsh + 2322432;
    f16* wth1 = wsh + 2324480;
    f16* wth2 = wsh + 2361344;

    auto cw = [](const float* w, f16* wt, int OC, int IC, int i) {
        int oc = i / IC, ic = i - oc * IC;
#pragma unroll
        for (int t = 0; t < 9; ++t)
            wt[((long)t * OC + oc) * IC + ic] = (f16)w[(long)i * 9 + t];
    };
    auto ch = [](const float* lw, const float* cwp, const float* rw, f16* wth, int i) {
        int t = i / 4096;
        int r = (i >> 8) & 15;
        int ic = i & 255;
        float v = 0.f;
        if (r < 2)       v = lw[((long)r * 256 + ic) * 9 + t];
        else if (r < 5)  v = cwp[((long)(r - 2) * 256 + ic) * 9 + t];
        else if (r == 5) v = rw[(long)ic * 9 + t];
        wth[((long)t * 16 + r) * 256 + ic] = (f16)v;
    };

    if (idx < 4096)        cw(w2, wt2, 64, 64, idx);
    else if (idx < 12288)  cw(w3, wt3, 128, 64, idx - 4096);
    else if (idx < 28672)  cw(w4, wt4, 128, 128, idx - 12288);
    else if (idx < 61440)  cw(w5, wt5, 256, 128, idx - 28672);
    else if (idx < 126976) cw(w6, wt6, 256, 256, idx - 61440);
    else if (idx < 192512) cw(w7, wt7, 256, 256, idx - 126976);
    else if (idx < 258048) cw(w8, wt8, 256, 256, idx - 192512);
    else if (idx < 258112) {
        int oc = idx - 258048;
#pragma unroll
        for (int k = 0; k < 32; ++k) {
            f16 v = (f16)0.f;
            if (k < 18) {
                int t = k >> 1, ic = k & 1;
                v = (f16)w1[((long)oc * 2 + ic) * 9 + t];
            }
            wt1[oc * 32 + k] = v;
        }
    }
    else if (idx < 294976) ch(lw1, cw1, rw1, wth1, idx - 258112);
    else if (idx < 331840) ch(lw2, cw2, rw2, wth2, idx - 294976);
}

// ---------------- l2norm + fused output-halo zero (f16x8 vectorized) ----------------
// Interior threads [0,total): per-pixel channel L2 normalize.
// Halo threads [total, total + items*per): zero out's padded border, where
// per = (2*(W+2) + 2*W) * 32 f16x8-groups (H == W for both uses).
__global__ __launch_bounds__(256) void l2nh_k(const f16* __restrict__ in, const float* __restrict__ g,
                                              f16* __restrict__ out, int W, long stride,
                                              int total, int items)
{
    int i = blockIdx.x * 256 + threadIdx.x;
    const int Wp = W + 2;
    if (i < total) {
        int b = i / (W * W);
        int rem = i - b * W * W;
        int y = rem / W, x = rem - y * W;
        long off = (long)b * stride + ((long)(y + 1) * Wp + x + 1) * 256;
        const f16* p = in + off;
        f16* q = out + off;
        float s = 0.f;
        for (int gg = 0; gg < 32; ++gg) {
            f16x8 v = *(const f16x8*)(p + gg * 8);
#pragma unroll
            for (int j = 0; j < 8; ++j) { float f = (float)v[j]; s = fmaf(f, f, s); }
        }
        float inv = 1.f / (sqrtf(s) + 1e-10f);
        for (int gg = 0; gg < 32; ++gg) {
            f16x8 v = *(const f16x8*)(p + gg * 8);
            f16x8 o;
#pragma unroll
            for (int j = 0; j < 8; ++j) o[j] = (f16)(g[gg * 8 + j] * ((float)v[j] * inv));
            *(f16x8*)(q + gg * 8) = o;
        }
        return;
    }
    int j = i - total;
    const int perPos = 2 * Wp + 2 * W;
    const int per = perPos * 32;
    if (j >= items * per) return;
    int n = j / per;
    int k = j - n * per;
    int p = k >> 5;
    int gg = k & 31;
    int row, col;
    if (p < Wp)            { row = 0;     col = p; }
    else if (p < 2 * Wp)   { row = W + 1; col = p - Wp; }
    else { int q = p - 2 * Wp; row = 1 + (q >> 1); col = (q & 1) ? (W + 1) : 0; }
    f16x8 z8;
#pragma unroll
    for (int jj = 0; jj < 8; ++jj) z8[jj] = (f16)0.f;
    *(f16x8*)&out[(long)n * stride + ((long)row * Wp + col) * 256 + gg * 8] = z8;
}

// ---------------- maxpool x6p->p4 + fused p4-halo zero ----------------
__global__ __launch_bounds__(256) void mph_k(const f16* __restrict__ in, f16* __restrict__ out)
{
    const int TOT = 8 * 32 * 32 * 32;
    int idx = blockIdx.x * 256 + threadIdx.x;
    if (idx < TOT) {
        int gg = idx & 31;
        int xo = (idx >> 5) & 31;
        int yo = (idx >> 10) & 31;
        int b = idx >> 15;
        const f16* p = in + (long)b * 1115136 + ((long)(2 * yo + 1) * 66 + 2 * xo + 1) * 256 + gg * 8;
        f16x8 a0 = *(const f16x8*)p;
        f16x8 a1 = *(const f16x8*)(p + 256);
        f16x8 a2 = *(const f16x8*)(p + 66 * 256);
        f16x8 a3 = *(const f16x8*)(p + 66 * 256 + 256);
        f16x8 o;
#pragma unroll
        for (int j = 0; j < 8; ++j)
            o[j] = (f16)fmaxf(fmaxf((float)a0[j], (float)a1[j]), fmaxf((float)a2[j], (float)a3[j]));
        *(f16x8*)(out + (long)b * 295936 + ((long)(yo + 1) * 34 + xo + 1) * 256 + gg * 8) = o;
        return;
    }
    int j = idx - TOT;
    const int per = (2 * 34 + 2 * 32) * 32;   // 4224 f16x8-groups per item
    if (j >= 8 * per) return;
    int n = j / per;
    int k = j - n * per;
    int p = k >> 5;
    int gg = k & 31;
    int row, col;
    if (p < 34)       { row = 0;  col = p; }
    else if (p < 68)  { row = 33; col = p - 34; }
    else { int q = p - 68; row = 1 + (q >> 1); col = (q & 1) ? 33 : 0; }
    f16x8 z8;
#pragma unroll
    for (int jj = 0; jj < 8; ++jj) z8[jj] = (f16)0.f;
    *(f16x8*)&out[(long)n * 295936 + ((long)row * 34 + col) * 256 + gg * 8] = z8;
}

__global__ __launch_bounds__(256) void priors_k(float* __restrict__ out)
{
    int r = blockIdx.x * 256 + threadIdx.x;
    if (r >= 5120) return;
    float cx, cy;
    if (r < 4096) {
        int i = r >> 6, j = r & 63;
        cx = (j + 0.5f) / 64.0f; cy = (i + 0.5f) / 64.0f;
    } else {
        int rr = r - 4096;
        int i = rr >> 5, j = rr & 31;
        cx = (j + 0.5f) / 32.0f; cy = (i + 0.5f) / 32.0f;
    }
    out[2 * r] = cx;
    out[2 * r + 1] = cy;
}

// ---------------- launch ----------------
extern "C" void kernel_launch(void* const* d_in, const int* in_sizes, int n_in,
                              void* d_out, int out_size, void* d_ws, size_t ws_size,
                              hipStream_t stream)
{
    const float* x  = (const float*)d_in[0];
    const float* w1 = (const float*)d_in[1];  const float* b1 = (const float*)d_in[2];
    const float* w2 = (const float*)d_in[3];  const float* b2 = (const float*)d_in[4];
    const float* w3 = (const float*)d_in[5];  const float* b3 = (const float*)d_in[6];
    const float* w4 = (const float*)d_in[7];  const float* b4 = (const float*)d_in[8];
    const float* w5 = (const float*)d_in[9];  const float* b5 = (const float*)d_in[10];
    const float* w6 = (const float*)d_in[11]; const float* b6 = (const float*)d_in[12];
    const float* w7 = (const float*)d_in[13]; const float* b7 = (const float*)d_in[14];
    const float* w8 = (const float*)d_in[15]; const float* b8 = (const float*)d_in[16];
    const float* g1 = (const float*)d_in[17]; const float* g2 = (const float*)d_in[18];
    const float* lw1 = (const float*)d_in[19]; const float* lb1 = (const float*)d_in[20];
    const float* lw2 = (const float*)d_in[21]; const float* lb2 = (const float*)d_in[22];
    const float* cw1 = (const float*)d_in[23]; const float* cb1 = (const float*)d_in[24];
    const float* cw2 = (const float*)d_in[25]; const float* cb2 = (const float*)d_in[26];
    const float* rw1 = (const float*)d_in[27]; const float* rb1 = (const float*)d_in[28];
    const float* rw2 = (const float*)d_in[29]; const float* rb2 = (const float*)d_in[30];

    f16* wsh = (f16*)d_ws;
    f16* wt2  = wsh + 0;
    f16* wt3  = wsh + 36864;
    f16* wt4  = wsh + 110592;
    f16* wt5  = wsh + 258048;
    f16* wt6  = wsh + 552960;
    f16* wt7  = wsh + 1142784;
    f16* wt8  = wsh + 1732608;
    f16* wt1  = wsh + 2322432;
    f16* wth1 = wsh + 2324480;
    f16* wth2 = wsh + 2361344;
    f16* x6p  = wsh + 2398208;   // 8*66*66*256 = 8921088
    const long PI = 11319296;    // group region base

    const long A1S = 16908544;   // 514*514*64
    const long P1S = 4260096;    // 258*258*64
    const long A3S = 8520192;    // 258*258*128 (aliases a1 region)
    const long P2S = 2163200;    // 130*130*128 (aliases p1 region)
    const long A5S = 4326400;    // 130*130*256 (aliases a1 region)
    const long PH2 = 18391040;   // phase-2 footprint (s1..s2)

    int G = 1;
    for (int g = 8; g >= 1; g >>= 1) {
        long ext = (long)g * (A1S + P1S); if (ext < PH2) ext = PH2;
        if (2.0 * (double)(PI + ext) <= (double)ws_size) { G = g; break; }
    }
    const int NGRP = 8 / G;

    f16* a1 = wsh + PI;                    // G x A1S (aliased: a3, a5)
    f16* p1 = wsh + PI + (long)G * A1S;    // G x P1S (aliased: p2)
    f16* a3 = a1;
    f16* p2 = p1;
    f16* a5 = a1;
    // phase-2 (after group loop, group region dead)
    f16* s1 = wsh + PI;
    f16* p4 = wsh + PI + 8921088;
    f16* a7 = wsh + PI + 11288576;
    f16* a8 = wsh + PI + 13656064;
    f16* s2 = wsh + PI + 16023552;

    float* loc  = (float*)d_out;
    float* conf = loc + 81920;
    float* regr = loc + 204800;
    float* pri  = loc + 245760;

    cvt_all_k<<<dim3((331840 + 255) / 256), 256, 0, stream>>>(
        w1, w2, w3, w4, w5, w6, w7, w8, lw1, cw1, rw1, lw2, cw2, rw2, wsh);

    // conv1..conv6, G items per dispatch; every conv self-zeroes its output halo
    for (int grp = 0; grp < NGRP; ++grp) {
        f16* x6g = x6p + (long)grp * G * 1115136;
        convmf1_k<<<dim3(8, 64, G), 256, 0, stream>>>(x, grp * G, wt1, b1, a1, A1S);
        convmf_k<64, 64, 64, 2, 2, 8, 2, true><<<dim3(8, 128, G), 256, 0, stream>>>(
            a1, wt2, b2, p1, 512, 512, 1, A1S, P1S);
        convmf_k<64, 128, 64, 2, 2, 8, 2, false><<<dim3(4, 64, 2 * G), 256, 0, stream>>>(
            p1, wt3, b3, a3, 256, 256, 2, P1S, A3S);
        convmf_k<128, 128, 64, 2, 2, 8, 2, true><<<dim3(4, 64, 2 * G), 256, 0, stream>>>(
            a3, wt4, b4, p2, 256, 256, 2, A3S, P2S);
        convmf_k<128, 256, 64, 2, 2, 8, 2, false><<<dim3(2, 32, 4 * G), 256, 0, stream>>>(
            p2, wt5, b5, a5, 128, 128, 4, P2S, A5S);
        convmf_k<256, 256, 64, 2, 2, 8, 2, true><<<dim3(2, 32, 4 * G), 256, 0, stream>>>(
            a5, wt6, b6, x6g, 128, 128, 4, A5S, 1115136);
    }

    // s1 = l2norm(x6p) + s1-halo zero (one dispatch)
    {
        const int total = 8 * 4096;
        const int halo = 8 * (2 * 66 + 2 * 64) * 32;   // 66560
        l2nh_k<<<dim3((total + halo + 255) / 256), 256, 0, stream>>>(
            x6p, g1, s1, 64, 1115136, total, 8);
    }
    // p4 = maxpool(x6p) + p4-halo zero (one dispatch)
    mph_k<<<dim3((262144 + 8 * 4224 + 255) / 256), 256, 0, stream>>>(x6p, p4);

    // conv7/8 self-zero a7/a8 halos in their epilogues
    convmf_k<256, 256, 32, 2, 2, 4, 2, false><<<dim3(1, 8, 32), 256, 0, stream>>>(
        p4, wt7, b7, a7, 32, 32, 4, 295936, 295936);
    convmf_k<256, 256, 32, 2, 2, 4, 2, false><<<dim3(1, 8, 32), 256, 0, stream>>>(
        a7, wt8, b8, a8, 32, 32, 4, 295936, 295936);

    // s2 = l2norm(a8) + s2-halo zero (one dispatch)
    {
        const int total = 8 * 1024;
        const int halo = 8 * (2 * 34 + 2 * 32) * 32;   // 33792
        l2nh_k<<<dim3((total + halo + 255) / 256), 256, 0, stream>>>(
            a8, g2, s2, 32, 295936, total, 8);
    }

    headconv_k<64><<<dim3(1, 64, 8), 256, 0, stream>>>(
        s1, 1115136, wth1, lb1, cb1, rb1, loc, conf, regr, 64, 0);
    headconv_k<32><<<dim3(1, 16, 8), 256, 0, stream>>>(
        s2, 295936, wth2, lb2, cb2, rb2, loc, conf, regr, 32, 4096);
    priors_k<<<dim3(20), 256, 0, stream>>>(pri);

    (void)in_sizes; (void)n_in; (void)out_size; (void)ws_size;
}

// Round 22
// 1085.432 us; speedup vs baseline: 1.4273x; 1.0120x over previous
//
#include <hip/hip_runtime.h>

typedef _Float16 f16;
typedef _Float16 f16x8 __attribute__((ext_vector_type(8)));
typedef float f32x4 __attribute__((ext_vector_type(4)));

__device__ __forceinline__ f32x4 mfma16(f16x8 a, f16x8 b, f32x4 c) {
    return __builtin_amdgcn_mfma_f32_16x16x32_f16(a, b, c, 0, 0, 0);
}

// ---------------- main implicit-GEMM 3x3 conv, f16 MFMA (r10-proven core) ----------------
// Epilogue SELF-ZEROES the output halo (edge blocks only, own oc-slice).
template<int IC, int OC, int BX, int WY, int WO, int MT, int NT, bool POOL>
__global__ __launch_bounds__(256) void convmf_k(
    const f16* __restrict__ in, const f16* __restrict__ wt,
    const float* __restrict__ bias, f16* __restrict__ out,
    int H, int W, int ocBlocks, long inStride, long outStride)
{
    constexpr int WROWS = MT * 16 / BX;
    constexpr int BROWS = WROWS * WY;
    constexpr int SR = BROWS + 2;
    constexpr int SC = BX + 2;
    constexpr int LOG = (BX == 64) ? 6 : 5;
    constexpr int OCB = 16 * NT * WO;     // channels covered per block
    static_assert(!POOL || (BX == 64 && MT == 8), "pool path assumes BX==64, MT==8");
    __shared__ f16 lds[SR * SC * 40];

    const int tid  = threadIdx.x;
    const int lane = tid & 63;
    const int wv   = tid >> 6;
    const int wy   = wv / WO;
    const int wo   = wv % WO;
    const int lm   = lane & 15;
    const int lk   = lane >> 4;
    const int x0   = blockIdx.x * BX;
    const int y0   = blockIdx.y * BROWS;
    const int zb   = blockIdx.z;
    const int n    = zb / ocBlocks;
    const int ocbase = (zb - n * ocBlocks) * OCB;
    const int oc0  = ocbase + wo * (16 * NT);
    in  += (long)n * inStride;
    out += (long)n * outStride;

    f32x4 acc[MT][NT];
#pragma unroll
    for (int mt = 0; mt < MT; ++mt)
#pragma unroll
        for (int nt = 0; nt < NT; ++nt)
            acc[mt][nt] = (f32x4){0.f, 0.f, 0.f, 0.f};

    const int Wp = W + 2;
    for (int ic0 = 0; ic0 < IC; ic0 += 32) {
        if (ic0) __syncthreads();
        const f16* ip = in + ((long)y0 * Wp + x0) * IC + ic0;
        constexpr int TASKS = SR * SC * 4;
        for (int s = tid; s < TASKS; s += 256) {
            int r    = s / (SC * 4);
            int rem  = s - r * (SC * 4);
            int xcol = rem >> 2;
            int g    = rem & 3;
            f16x8 v = *(const f16x8*)(ip + ((long)r * Wp + xcol) * IC + g * 8);
            *(f16x8*)&lds[(r * SC + xcol) * 40 + g * 8] = v;
        }
        __syncthreads();

        for (int t = 0; t < 9; ++t) {
            int dy = t / 3, dx = t - dy * 3;
            const f16* wp = wt + ((long)t * OC + oc0) * IC + ic0 + lk * 8;
            f16x8 bfr[NT];
#pragma unroll
            for (int nt = 0; nt < NT; ++nt)
                bfr[nt] = *(const f16x8*)(wp + (nt * 16 + lm) * IC);
#pragma unroll
            for (int mt = 0; mt < MT; ++mt) {
                int pos = mt * 16 + lm;
                int xx = pos & (BX - 1);
                int yy = wy * WROWS + (pos >> LOG);
                f16x8 a = *(const f16x8*)&lds[((yy + dy) * SC + xx + dx) * 40 + lk * 8];
#pragma unroll
                for (int nt = 0; nt < NT; ++nt)
                    acc[mt][nt] = mfma16(a, bfr[nt], acc[mt][nt]);
            }
        }
    }

    f16x8 z8;
#pragma unroll
    for (int j = 0; j < 8; ++j) z8[j] = (f16)0.f;

    if constexpr (!POOL) {
#pragma unroll
        for (int nt = 0; nt < NT; ++nt) {
            int oc = oc0 + nt * 16 + lm;
            float bs = bias[oc];
#pragma unroll
            for (int mt = 0; mt < MT; ++mt) {
#pragma unroll
                for (int r = 0; r < 4; ++r) {
                    int pos = mt * 16 + lk * 4 + r;
                    int xx = pos & (BX - 1);
                    int yy = wy * WROWS + (pos >> LOG);
                    float v = fmaxf(acc[mt][nt][r] + bs, 0.f);
                    out[((long)(y0 + yy + 1) * (W + 2) + (x0 + xx + 1)) * OC + oc] = (f16)v;
                }
            }
        }
        if (y0 == 0 || y0 + BROWS == H) {
            int c0 = (x0 == 0) ? 0 : x0 + 1;
            int c1 = (x0 + BX == W) ? (W + 1) : (x0 + BX);
            int ncol = c1 - c0 + 1;
            int total = ncol * (OCB / 8);
            for (int pass = 0; pass < 2; ++pass) {
                int row = (pass == 0) ? 0 : H + 1;
                if ((pass == 0 && y0 == 0) || (pass == 1 && y0 + BROWS == H)) {
                    for (int s = tid; s < total; s += 256) {
                        int col = c0 + s / (OCB / 8);
                        int gg = s - (col - c0) * (OCB / 8);
                        *(f16x8*)&out[((long)row * (W + 2) + col) * OC + ocbase + gg * 8] = z8;
                    }
                }
            }
        }
        if (x0 == 0 || x0 + BX == W) {
            int total = BROWS * (OCB / 8);
            for (int pass = 0; pass < 2; ++pass) {
                int col = (pass == 0) ? 0 : W + 1;
                if ((pass == 0 && x0 == 0) || (pass == 1 && x0 + BX == W)) {
                    for (int s = tid; s < total; s += 256) {
                        int row = y0 + 1 + s / (OCB / 8);
                        int gg = s - (row - y0 - 1) * (OCB / 8);
                        *(f16x8*)&out[((long)row * (W + 2) + col) * OC + ocbase + gg * 8] = z8;
                    }
                }
            }
        }
    } else {
        const int Wo = W >> 1;
        const int Ho = H >> 1;
#pragma unroll
        for (int nt = 0; nt < NT; ++nt) {
            int oc = oc0 + nt * 16 + lm;
            float bs = bias[oc];
#pragma unroll
            for (int mt = 0; mt < 4; ++mt) {
#pragma unroll
                for (int r = 0; r < 4; r += 2) {
                    float v = fmaxf(fmaxf(acc[mt][nt][r], acc[mt][nt][r + 1]),
                                    fmaxf(acc[mt + 4][nt][r], acc[mt + 4][nt][r + 1]));
                    v = fmaxf(v + bs, 0.f);
                    int pos = mt * 16 + lk * 4 + r;
                    int xo = pos >> 1;
                    out[((long)((y0 >> 1) + wy + 1) * (Wo + 2) + ((x0 >> 1) + xo + 1)) * OC + oc] = (f16)v;
                }
            }
        }
        const int px0 = x0 >> 1;
        const int py0 = y0 >> 1;
        if (y0 == 0 || y0 + BROWS == H) {
            int c0 = (x0 == 0) ? 0 : px0 + 1;
            int c1 = (x0 + BX == W) ? (Wo + 1) : (px0 + BX / 2);
            int ncol = c1 - c0 + 1;
            int total = ncol * (OCB / 8);
            for (int pass = 0; pass < 2; ++pass) {
                int row = (pass == 0) ? 0 : Ho + 1;
                if ((pass == 0 && y0 == 0) || (pass == 1 && y0 + BROWS == H)) {
                    for (int s = tid; s < total; s += 256) {
                        int col = c0 + s / (OCB / 8);
                        int gg = s - (col - c0) * (OCB / 8);
                        *(f16x8*)&out[((long)row * (Wo + 2) + col) * OC + ocbase + gg * 8] = z8;
                    }
                }
            }
        }
        if (x0 == 0 || x0 + BX == W) {
            constexpr int PROWS = BROWS / 2;
            int total = PROWS * (OCB / 8);
            for (int pass = 0; pass < 2; ++pass) {
                int col = (pass == 0) ? 0 : Wo + 1;
                if ((pass == 0 && x0 == 0) || (pass == 1 && x0 + BX == W)) {
                    for (int s = tid; s < total; s += 256) {
                        int row = py0 + 1 + s / (OCB / 8);
                        int gg = s - (row - py0 - 1) * (OCB / 8);
                        *(f16x8*)&out[((long)row * (Wo + 2) + col) * OC + ocbase + gg * 8] = z8;
                    }
                }
            }
        }
    }
}

// ---------------- conv1: IC=2, im2col in LDS, K padded to 32 (r5-proven) ----------------
__global__ __launch_bounds__(256) void convmf1_k(
    const float* __restrict__ x, int itemBase,
    const f16* __restrict__ wt1,  // [64][32] f16, k=2t+ic, zero-padded
    const float* __restrict__ bias, f16* __restrict__ out, long outStride)
{
    __shared__ f16 ldsx[10 * 66 * 2];
    __shared__ f16 ldsa[512 * 40];
    const int tid = threadIdx.x;
    const int lane = tid & 63;
    const int wv = tid >> 6;
    const int lm = lane & 15;
    const int lk = lane >> 4;
    const int x0 = blockIdx.x * 64;
    const int y0 = blockIdx.y * 8;
    const float* xb = x + (long)(itemBase + blockIdx.z) * 2 * 512 * 512;
    out += (long)blockIdx.z * outStride;

    for (int s = tid; s < 660; s += 256) {
        int r = s / 66, xc = s - r * 66;
        int gy = y0 + r - 1, gx = x0 + xc - 1;
        f16 v0 = (f16)0.f, v1 = (f16)0.f;
        if ((unsigned)gy < 512u && (unsigned)gx < 512u) {
            v0 = (f16)xb[(long)gy * 512 + gx];
            v1 = (f16)xb[262144 + (long)gy * 512 + gx];
        }
        ldsx[(r * 66 + xc) * 2]     = v0;
        ldsx[(r * 66 + xc) * 2 + 1] = v1;
    }
    __syncthreads();
    for (int s = tid; s < 2048; s += 256) {
        int pos = s >> 2, g = s & 3;
        int row = pos >> 6, col = pos & 63;
        f16x8 v;
#pragma unroll
        for (int j = 0; j < 8; ++j) {
            int k = g * 8 + j;
            f16 val = (f16)0.f;
            if (k < 18) {
                int t = k >> 1, ic = k & 1;
                int dy = t / 3, dx = t - dy * 3;
                val = ldsx[((row + dy) * 66 + col + dx) * 2 + ic];
            }
            v[j] = val;
        }
        *(f16x8*)&ldsa[pos * 40 + g * 8] = v;
    }
    __syncthreads();

    f32x4 acc[8][4];
#pragma unroll
    for (int mt = 0; mt < 8; ++mt)
#pragma unroll
        for (int nt = 0; nt < 4; ++nt)
            acc[mt][nt] = (f32x4){0.f, 0.f, 0.f, 0.f};

    f16x8 b0 = *(const f16x8*)(wt1 + (0 * 16 + lm) * 32 + lk * 8);
    f16x8 b1 = *(const f16x8*)(wt1 + (1 * 16 + lm) * 32 + lk * 8);
    f16x8 b2 = *(const f16x8*)(wt1 + (2 * 16 + lm) * 32 + lk * 8);
    f16x8 b3 = *(const f16x8*)(wt1 + (3 * 16 + lm) * 32 + lk * 8);
#pragma unroll
    for (int mt = 0; mt < 8; ++mt) {
        int pos = wv * 128 + mt * 16 + lm;
        f16x8 a = *(const f16x8*)&ldsa[pos * 40 + lk * 8];
        acc[mt][0] = mfma16(a, b0, acc[mt][0]);
        acc[mt][1] = mfma16(a, b1, acc[mt][1]);
        acc[mt][2] = mfma16(a, b2, acc[mt][2]);
        acc[mt][3] = mfma16(a, b3, acc[mt][3]);
    }
#pragma unroll
    for (int nt = 0; nt < 4; ++nt) {
        int oc = nt * 16 + lm;
        float bs = bias[oc];
#pragma unroll
        for (int mt = 0; mt < 8; ++mt) {
#pragma unroll
            for (int r = 0; r < 4; ++r) {
                int pos = wv * 128 + mt * 16 + lk * 4 + r;
                int xx = pos & 63, yy = pos >> 6;
                float v = fmaxf(acc[mt][nt][r] + bs, 0.f);
                out[((long)(y0 + yy + 1) * 514 + (x0 + xx + 1)) * 64 + oc] = (f16)v;
            }
        }
    }

    f16x8 z8;
#pragma unroll
    for (int j = 0; j < 8; ++j) z8[j] = (f16)0.f;
    if (y0 == 0 || y0 + 8 == 512) {
        int c0 = (x0 == 0) ? 0 : x0 + 1;
        int c1 = (x0 + 64 == 512) ? 513 : (x0 + 64);
        int ncol = c1 - c0 + 1;
        int total = ncol * 8;
        for (int pass = 0; pass < 2; ++pass) {
            int row = (pass == 0) ? 0 : 513;
            if ((pass == 0 && y0 == 0) || (pass == 1 && y0 + 8 == 512)) {
                for (int s = tid; s < total; s += 256) {
                    int col = c0 + (s >> 3);
                    int gg = s & 7;
                    *(f16x8*)&out[((long)row * 514 + col) * 64 + gg * 8] = z8;
                }
            }
        }
    }
    if (x0 == 0 || x0 + 64 == 512) {
        int total = 8 * 8;
        for (int pass = 0; pass < 2; ++pass) {
            int col = (pass == 0) ? 0 : 513;
            if ((pass == 0 && x0 == 0) || (pass == 1 && x0 + 64 == 512)) {
                for (int s = tid; s < total; s += 256) {
                    int row = y0 + 1 + (s >> 3);
                    int gg = s & 7;
                    *(f16x8*)&out[((long)row * 514 + col) * 64 + gg * 8] = z8;
                }
            }
        }
    }
}

// ---------------- merged heads: both scales in ONE dispatch ----------------
// grid (1, 64+16, 8): y<64 -> s1 path (W=64, BY=1); y>=64 -> s2 path (W=32, BY=2).
// Per-block uniform branch; logic identical to the proven per-scale kernels.
__global__ __launch_bounds__(256) void headall_k(
    const f16* __restrict__ s1v, const f16* __restrict__ s2v,
    const f16* __restrict__ wth1, const f16* __restrict__ wth2,
    const float* __restrict__ lb1, const float* __restrict__ cb1, const float* __restrict__ rb1,
    const float* __restrict__ lb2, const float* __restrict__ cb2, const float* __restrict__ rb2,
    float* __restrict__ loc, float* __restrict__ conf, float* __restrict__ regr)
{
    __shared__ f16 lds[3 * 66 * 40];   // max(3*66, 4*34) * 40
    const int tid = threadIdx.x;
    const int lane = tid & 63;
    const int wv = tid >> 6;
    const int lm = lane & 15;
    const int lk = lane >> 4;
    const int b = blockIdx.z;

    const bool big = (blockIdx.y < 64);
    const int W   = big ? 64 : 32;
    const int LOG = big ? 6 : 5;
    const int BY  = big ? 1 : 2;
    const int y0  = big ? (int)blockIdx.y : ((int)blockIdx.y - 64) * 2;
    const int posoff = big ? 0 : 4096;
    const f16* s   = big ? (s1v + (long)b * 1115136) : (s2v + (long)b * 295936);
    const f16* wth = big ? wth1 : wth2;
    const float* lb = big ? lb1 : lb2;
    const float* cb = big ? cb1 : cb2;
    const float* rb = big ? rb1 : rb2;

    const int SR = BY + 2, SC = W + 2;
    const int Wp = W + 2;

    f32x4 acc = (f32x4){0.f, 0.f, 0.f, 0.f};
    for (int ic0 = 0; ic0 < 256; ic0 += 32) {
        if (ic0) __syncthreads();
        const f16* ip = s + (long)y0 * Wp * 256 + ic0;
        const int TASKS = SR * SC * 4;
        for (int t = tid; t < TASKS; t += 256) {
            int r = t / (SC * 4);
            int rem = t - r * (SC * 4);
            int xcol = rem >> 2, g = rem & 3;
            f16x8 v = *(const f16x8*)(ip + ((long)r * Wp + xcol) * 256 + g * 8);
            *(f16x8*)&lds[(r * SC + xcol) * 40 + g * 8] = v;
        }
        __syncthreads();
        for (int t = 0; t < 9; ++t) {
            int dy = t / 3, dx = t - dy * 3;
            f16x8 bf = *(const f16x8*)(wth + ((long)t * 16 + lm) * 256 + ic0 + lk * 8);
            int pos = wv * 16 + lm;
            int xx = pos & (W - 1), yy = pos >> LOG;
            f16x8 a = *(const f16x8*)&lds[((yy + dy) * SC + xx + dx) * 40 + lk * 8];
            acc = mfma16(a, bf, acc);
        }
    }
#pragma unroll
    for (int r = 0; r < 4; ++r) {
        int pos = wv * 16 + lk * 4 + r;
        int xx = pos & (W - 1), yy = pos >> LOG;
        int P = posoff + (y0 + yy) * W + xx;
        float v = acc[r];
        if (lm < 2)       loc[((long)b * 5120 + P) * 2 + lm]       = v + lb[lm];
        else if (lm < 5)  conf[((long)b * 5120 + P) * 3 + (lm - 2)] = v + cb[lm - 2];
        else if (lm == 5) regr[(long)b * 5120 + P]                  = v + rb[0];
    }
}

// ---------------- merged weight conversions + priors (one dispatch) ----------------
__global__ __launch_bounds__(256) void cvt_all_k(
    const float* __restrict__ w1, const float* __restrict__ w2, const float* __restrict__ w3,
    const float* __restrict__ w4, const float* __restrict__ w5, const float* __restrict__ w6,
    const float* __restrict__ w7, const float* __restrict__ w8,
    const float* __restrict__ lw1, const float* __restrict__ cw1, const float* __restrict__ rw1,
    const float* __restrict__ lw2, const float* __restrict__ cw2, const float* __restrict__ rw2,
    f16* __restrict__ wsh, float* __restrict__ pri)
{
    int idx = blockIdx.x * 256 + threadIdx.x;
    f16* wt2  = wsh + 0;
    f16* wt3  = wsh + 36864;
    f16* wt4  = wsh + 110592;
    f16* wt5  = wsh + 258048;
    f16* wt6  = wsh + 552960;
    f16* wt7  = wsh + 1142784;
    f16* wt8  = wsh + 1732608;
    f16* wt1  = wsh + 2322432;
    f16* wth1 = wsh + 2324480;
    f16* wth2 = wsh + 2361344;

    auto cw = [](const float* w, f16* wt, int OC, int IC, int i) {
        int oc = i / IC, ic = i - oc * IC;
#pragma unroll
        for (int t = 0; t < 9; ++t)
            wt[((long)t * OC + oc) * IC + ic] = (f16)w[(long)i * 9 + t];
    };
    auto ch = [](const float* lw, const float* cwp, const float* rw, f16* wth, int i) {
        int t = i / 4096;
        int r = (i >> 8) & 15;
        int ic = i & 255;
        float v = 0.f;
        if (r < 2)       v = lw[((long)r * 256 + ic) * 9 + t];
        else if (r < 5)  v = cwp[((long)(r - 2) * 256 + ic) * 9 + t];
        else if (r == 5) v = rw[(long)ic * 9 + t];
        wth[((long)t * 16 + r) * 256 + ic] = (f16)v;
    };

    if (idx < 4096)        cw(w2, wt2, 64, 64, idx);
    else if (idx < 12288)  cw(w3, wt3, 128, 64, idx - 4096);
    else if (idx < 28672)  cw(w4, wt4, 128, 128, idx - 12288);
    else if (idx < 61440)  cw(w5, wt5, 256, 128, idx - 28672);
    else if (idx < 126976) cw(w6, wt6, 256, 256, idx - 61440);
    else if (idx < 192512) cw(w7, wt7, 256, 256, idx - 126976);
    else if (idx < 258048) cw(w8, wt8, 256, 256, idx - 192512);
    else if (idx < 258112) {
        int oc = idx - 258048;
#pragma unroll
        for (int k = 0; k < 32; ++k) {
            f16 v = (f16)0.f;
            if (k < 18) {
                int t = k >> 1, ic = k & 1;
                v = (f16)w1[((long)oc * 2 + ic) * 9 + t];
            }
            wt1[oc * 32 + k] = v;
        }
    }
    else if (idx < 294976) ch(lw1, cw1, rw1, wth1, idx - 258112);
    else if (idx < 331840) ch(lw2, cw2, rw2, wth2, idx - 294976);
    else if (idx < 336960) {
        int r = idx - 331840;
        float cx, cy;
        if (r < 4096) {
            int i = r >> 6, j = r & 63;
            cx = (j + 0.5f) / 64.0f; cy = (i + 0.5f) / 64.0f;
        } else {
            int rr = r - 4096;
            int i = rr >> 5, j = rr & 31;
            cx = (j + 0.5f) / 32.0f; cy = (i + 0.5f) / 32.0f;
        }
        pri[2 * r]     = cx;
        pri[2 * r + 1] = cy;
    }
}

// ---------------- l2norm + fused output-halo zero (f16x8 vectorized) ----------------
__global__ __launch_bounds__(256) void l2nh_k(const f16* __restrict__ in, const float* __restrict__ g,
                                              f16* __restrict__ out, int W, long stride,
                                              int total, int items)
{
    int i = blockIdx.x * 256 + threadIdx.x;
    const int Wp = W + 2;
    if (i < total) {
        int b = i / (W * W);
        int rem = i - b * W * W;
        int y = rem / W, x = rem - y * W;
        long off = (long)b * stride + ((long)(y + 1) * Wp + x + 1) * 256;
        const f16* p = in + off;
        f16* q = out + off;
        float s = 0.f;
        for (int gg = 0; gg < 32; ++gg) {
            f16x8 v = *(const f16x8*)(p + gg * 8);
#pragma unroll
            for (int j = 0; j < 8; ++j) { float f = (float)v[j]; s = fmaf(f, f, s); }
        }
        float inv = 1.f / (sqrtf(s) + 1e-10f);
        for (int gg = 0; gg < 32; ++gg) {
            f16x8 v = *(const f16x8*)(p + gg * 8);
            f16x8 o;
#pragma unroll
            for (int j = 0; j < 8; ++j) o[j] = (f16)(g[gg * 8 + j] * ((float)v[j] * inv));
            *(f16x8*)(q + gg * 8) = o;
        }
        return;
    }
    int j = i - total;
    const int perPos = 2 * Wp + 2 * W;
    const int per = perPos * 32;
    if (j >= items * per) return;
    int n = j / per;
    int k = j - n * per;
    int p = k >> 5;
    int gg = k & 31;
    int row, col;
    if (p < Wp)            { row = 0;     col = p; }
    else if (p < 2 * Wp)   { row = W + 1; col = p - Wp; }
    else { int q = p - 2 * Wp; row = 1 + (q >> 1); col = (q & 1) ? (W + 1) : 0; }
    f16x8 z8;
#pragma unroll
    for (int jj = 0; jj < 8; ++jj) z8[jj] = (f16)0.f;
    *(f16x8*)&out[(long)n * stride + ((long)row * Wp + col) * 256 + gg * 8] = z8;
}

// ---------------- maxpool x6p->p4 + fused p4-halo zero ----------------
__global__ __launch_bounds__(256) void mph_k(const f16* __restrict__ in, f16* __restrict__ out)
{
    const int TOT = 8 * 32 * 32 * 32;
    int idx = blockIdx.x * 256 + threadIdx.x;
    if (idx < TOT) {
        int gg = idx & 31;
        int xo = (idx >> 5) & 31;
        int yo = (idx >> 10) & 31;
        int b = idx >> 15;
        const f16* p = in + (long)b * 1115136 + ((long)(2 * yo + 1) * 66 + 2 * xo + 1) * 256 + gg * 8;
        f16x8 a0 = *(const f16x8*)p;
        f16x8 a1 = *(const f16x8*)(p + 256);
        f16x8 a2 = *(const f16x8*)(p + 66 * 256);
        f16x8 a3 = *(const f16x8*)(p + 66 * 256 + 256);
        f16x8 o;
#pragma unroll
        for (int j = 0; j < 8; ++j)
            o[j] = (f16)fmaxf(fmaxf((float)a0[j], (float)a1[j]), fmaxf((float)a2[j], (float)a3[j]));
        *(f16x8*)(out + (long)b * 295936 + ((long)(yo + 1) * 34 + xo + 1) * 256 + gg * 8) = o;
        return;
    }
    int j = idx - TOT;
    const int per = (2 * 34 + 2 * 32) * 32;
    if (j >= 8 * per) return;
    int n = j / per;
    int k = j - n * per;
    int p = k >> 5;
    int gg = k & 31;
    int row, col;
    if (p < 34)       { row = 0;  col = p; }
    else if (p < 68)  { row = 33; col = p - 34; }
    else { int q = p - 68; row = 1 + (q >> 1); col = (q & 1) ? 33 : 0; }
    f16x8 z8;
#pragma unroll
    for (int jj = 0; jj < 8; ++jj) z8[jj] = (f16)0.f;
    *(f16x8*)&out[(long)n * 295936 + ((long)row * 34 + col) * 256 + gg * 8] = z8;
}

// ---------------- launch ----------------
extern "C" void kernel_launch(void* const* d_in, const int* in_sizes, int n_in,
                              void* d_out, int out_size, void* d_ws, size_t ws_size,
                              hipStream_t stream)
{
    const float* x  = (const float*)d_in[0];
    const float* w1 = (const float*)d_in[1];  const float* b1 = (const float*)d_in[2];
    const float* w2 = (const float*)d_in[3];  const float* b2 = (const float*)d_in[4];
    const float* w3 = (const float*)d_in[5];  const float* b3 = (const float*)d_in[6];
    const float* w4 = (const float*)d_in[7];  const float* b4 = (const float*)d_in[8];
    const float* w5 = (const float*)d_in[9];  const float* b5 = (const float*)d_in[10];
    const float* w6 = (const float*)d_in[11]; const float* b6 = (const float*)d_in[12];
    const float* w7 = (const float*)d_in[13]; const float* b7 = (const float*)d_in[14];
    const float* w8 = (const float*)d_in[15]; const float* b8 = (const float*)d_in[16];
    const float* g1 = (const float*)d_in[17]; const float* g2 = (const float*)d_in[18];
    const float* lw1 = (const float*)d_in[19]; const float* lb1 = (const float*)d_in[20];
    const float* lw2 = (const float*)d_in[21]; const float* lb2 = (const float*)d_in[22];
    const float* cw1 = (const float*)d_in[23]; const float* cb1 = (const float*)d_in[24];
    const float* cw2 = (const float*)d_in[25]; const float* cb2 = (const float*)d_in[26];
    const float* rw1 = (const float*)d_in[27]; const float* rb1 = (const float*)d_in[28];
    const float* rw2 = (const float*)d_in[29]; const float* rb2 = (const float*)d_in[30];

    f16* wsh = (f16*)d_ws;
    f16* wt2  = wsh + 0;
    f16* wt3  = wsh + 36864;
    f16* wt4  = wsh + 110592;
    f16* wt5  = wsh + 258048;
    f16* wt6  = wsh + 552960;
    f16* wt7  = wsh + 1142784;
    f16* wt8  = wsh + 1732608;
    f16* wt1  = wsh + 2322432;
    f16* wth1 = wsh + 2324480;
    f16* wth2 = wsh + 2361344;
    f16* x6p  = wsh + 2398208;   // 8*66*66*256 = 8921088
    const long PI = 11319296;    // group region base

    const long A1S = 16908544;   // 514*514*64
    const long P1S = 4260096;    // 258*258*64
    const long A3S = 8520192;    // 258*258*128 (aliases a1 region)
    const long P2S = 2163200;    // 130*130*128 (aliases p1 region)
    const long A5S = 4326400;    // 130*130*256 (aliases a1 region)
    const long PH2 = 18391040;   // phase-2 footprint (s1..s2)

    int G = 1;
    for (int g = 8; g >= 1; g >>= 1) {
        long ext = (long)g * (A1S + P1S); if (ext < PH2) ext = PH2;
        if (2.0 * (double)(PI + ext) <= (double)ws_size) { G = g; break; }
    }
    const int NGRP = 8 / G;

    f16* a1 = wsh + PI;                    // G x A1S (aliased: a3, a5)
    f16* p1 = wsh + PI + (long)G * A1S;    // G x P1S (aliased: p2)
    f16* a3 = a1;
    f16* p2 = p1;
    f16* a5 = a1;
    // phase-2 (after group loop, group region dead)
    f16* s1 = wsh + PI;
    f16* p4 = wsh + PI + 8921088;
    f16* a7 = wsh + PI + 11288576;
    f16* a8 = wsh + PI + 13656064;
    f16* s2 = wsh + PI + 16023552;

    float* loc  = (float*)d_out;
    float* conf = loc + 81920;
    float* regr = loc + 204800;
    float* pri  = loc + 245760;

    // weights + head-weights + priors in one dispatch
    cvt_all_k<<<dim3((336960 + 255) / 256), 256, 0, stream>>>(
        w1, w2, w3, w4, w5, w6, w7, w8, lw1, cw1, rw1, lw2, cw2, rw2, wsh, pri);

    // conv1..conv6, G items per dispatch; every conv self-zeroes its output halo
    for (int grp = 0; grp < NGRP; ++grp) {
        f16* x6g = x6p + (long)grp * G * 1115136;
        convmf1_k<<<dim3(8, 64, G), 256, 0, stream>>>(x, grp * G, wt1, b1, a1, A1S);
        convmf_k<64, 64, 64, 2, 2, 8, 2, true><<<dim3(8, 128, G), 256, 0, stream>>>(
            a1, wt2, b2, p1, 512, 512, 1, A1S, P1S);
        convmf_k<64, 128, 64, 2, 2, 8, 2, false><<<dim3(4, 64, 2 * G), 256, 0, stream>>>(
            p1, wt3, b3, a3, 256, 256, 2, P1S, A3S);
        convmf_k<128, 128, 64, 2, 2, 8, 2, true><<<dim3(4, 64, 2 * G), 256, 0, stream>>>(
            a3, wt4, b4, p2, 256, 256, 2, A3S, P2S);
        convmf_k<128, 256, 64, 2, 2, 8, 2, false><<<dim3(2, 32, 4 * G), 256, 0, stream>>>(
            p2, wt5, b5, a5, 128, 128, 4, P2S, A5S);
        convmf_k<256, 256, 64, 2, 2, 8, 2, true><<<dim3(2, 32, 4 * G), 256, 0, stream>>>(
            a5, wt6, b6, x6g, 128, 128, 4, A5S, 1115136);
    }

    // s1 = l2norm(x6p) + s1-halo zero (one dispatch)
    {
        const int total = 8 * 4096;
        const int halo = 8 * (2 * 66 + 2 * 64) * 32;
        l2nh_k<<<dim3((total + halo + 255) / 256), 256, 0, stream>>>(
            x6p, g1, s1, 64, 1115136, total, 8);
    }
    // p4 = maxpool(x6p) + p4-halo zero (one dispatch)
    mph_k<<<dim3((262144 + 8 * 4224 + 255) / 256), 256, 0, stream>>>(x6p, p4);

    // conv7/8 self-zero a7/a8 halos in their epilogues
    convmf_k<256, 256, 32, 2, 2, 4, 2, false><<<dim3(1, 8, 32), 256, 0, stream>>>(
        p4, wt7, b7, a7, 32, 32, 4, 295936, 295936);
    convmf_k<256, 256, 32, 2, 2, 4, 2, false><<<dim3(1, 8, 32), 256, 0, stream>>>(
        a7, wt8, b8, a8, 32, 32, 4, 295936, 295936);

    // s2 = l2norm(a8) + s2-halo zero (one dispatch)
    {
        const int total = 8 * 1024;
        const int halo = 8 * (2 * 34 + 2 * 32) * 32;
        l2nh_k<<<dim3((total + halo + 255) / 256), 256, 0, stream>>>(
            a8, g2, s2, 32, 295936, total, 8);
    }

    // both head scales in one dispatch
    headall_k<<<dim3(1, 80, 8), 256, 0, stream>>>(
        s1, s2, wth1, wth2, lb1, cb1, rb1, lb2, cb2, rb2, loc, conf, regr);

    (void)in_sizes; (void)n_in; (void)out_size; (void)ws_size;
}